// Round 1
// baseline (414.864 us; speedup 1.0000x reference)
//
#include <hip/hip_runtime.h>
#include <hip/hip_bf16.h>
#include <math.h>

#define WORDC 30000
#define F_TOT 80000
#define NTOK  2048
#define DMODEL 256
#define FFDIM 512
#define NHEAD 8
#define HDIM  32
#define SEQL  64

// ---------------------------------------------------------------------------
// Fused sparse embed: dedupe(word+6 ngrams) -> fc1 gather+relu -> fc2
// block = 8 tokens, 256 threads
// ---------------------------------------------------------------------------
__global__ __launch_bounds__(256) void embed_kernel(
    const int* __restrict__ word_idx,    // [NTOK]
    const int* __restrict__ ngram_idx,   // [NTOK][6]
    const float* __restrict__ fc1_w,     // [FFDIM][F_TOT]
    const float* __restrict__ fc1_b,     // [FFDIM]
    const float* __restrict__ fc2_w,     // [DMODEL][FFDIM]
    const float* __restrict__ fc2_b,     // [DMODEL]
    float* __restrict__ x)               // [NTOK][DMODEL]
{
    __shared__ int   feats[8][8];
    __shared__ int   nf[8];
    __shared__ float x1[8][FFDIM];

    const int t0  = blockIdx.x * 8;
    const int tid = threadIdx.x;

    if (tid < 8) {
        int t = t0 + tid;
        int cnt = 0;
        feats[tid][cnt++] = word_idx[t];
        for (int k = 0; k < 6; ++k) {
            int f = WORDC + ngram_idx[t * 6 + k];
            bool dup = false;
            for (int s = 1; s < cnt; ++s)
                if (feats[tid][s] == f) dup = true;
            if (!dup) feats[tid][cnt++] = f;
        }
        nf[tid] = cnt;
    }
    __syncthreads();

    // x1 = relu(sv @ fc1_w.T + fc1_b): 8 tokens x 512 outputs = 4096 items
    for (int it = 0; it < 16; ++it) {
        int item = it * 256 + tid;
        int tt = item >> 9;          // /512
        int j  = item & 511;
        float acc = fc1_b[j];
        int n = nf[tt];
        const float* rowbase = fc1_w + (long)j * F_TOT;
        for (int s = 0; s < n; ++s)
            acc += rowbase[feats[tt][s]];
        x1[tt][j] = fmaxf(acc, 0.f);
    }
    __syncthreads();

    // fc2: thread d computes 8 token outputs
    const int d = tid;
    float acc[8];
    float bb = fc2_b[d];
    #pragma unroll
    for (int tt = 0; tt < 8; ++tt) acc[tt] = bb;
    const float* wrow = fc2_w + d * FFDIM;
    for (int k = 0; k < FFDIM; ++k) {
        float w = wrow[k];
        #pragma unroll
        for (int tt = 0; tt < 8; ++tt) acc[tt] += w * x1[tt][k];
    }
    #pragma unroll
    for (int tt = 0; tt < 8; ++tt)
        x[(t0 + tt) * DMODEL + d] = acc[tt];
}

// ---------------------------------------------------------------------------
// fp32 tiled GEMM:  C[M][N] = A[M][K] @ W[N][K]^T + bias[N]  (optional relu)
// 64x64 tile, BK=16, 256 threads, 4x4 micro-tile
// ---------------------------------------------------------------------------
template<bool RELU>
__global__ __launch_bounds__(256) void gemm_bias(
    const float* __restrict__ A,
    const float* __restrict__ W,
    const float* __restrict__ bias,
    float* __restrict__ C,
    int M, int N, int K)
{
    __shared__ float sA[16][64];   // [k][m]
    __shared__ float sW[16][64];   // [k][n]

    const int tid = threadIdx.x;
    const int tx = tid & 15;       // n-dir
    const int ty = tid >> 4;       // m-dir
    const int m0 = blockIdx.y * 64;
    const int n0 = blockIdx.x * 64;

    const int lr = tid >> 2;       // 0..63 row within tile
    const int lc = tid & 3;        // float4 column group

    float acc[4][4] = {};

    for (int k0 = 0; k0 < K; k0 += 16) {
        float4 av = *(const float4*)&A[(long)(m0 + lr) * K + k0 + lc * 4];
        float4 wv = *(const float4*)&W[(long)(n0 + lr) * K + k0 + lc * 4];
        __syncthreads();
        sA[lc * 4 + 0][lr] = av.x; sA[lc * 4 + 1][lr] = av.y;
        sA[lc * 4 + 2][lr] = av.z; sA[lc * 4 + 3][lr] = av.w;
        sW[lc * 4 + 0][lr] = wv.x; sW[lc * 4 + 1][lr] = wv.y;
        sW[lc * 4 + 2][lr] = wv.z; sW[lc * 4 + 3][lr] = wv.w;
        __syncthreads();
        #pragma unroll
        for (int k = 0; k < 16; ++k) {
            float4 a4 = *(const float4*)&sA[k][ty * 4];
            float4 b4 = *(const float4*)&sW[k][tx * 4];
            float am[4] = {a4.x, a4.y, a4.z, a4.w};
            float bn[4] = {b4.x, b4.y, b4.z, b4.w};
            #pragma unroll
            for (int i = 0; i < 4; ++i)
                #pragma unroll
                for (int j = 0; j < 4; ++j)
                    acc[i][j] += am[i] * bn[j];
        }
    }

    float4 bv = *(const float4*)&bias[n0 + tx * 4];
    #pragma unroll
    for (int i = 0; i < 4; ++i) {
        int m = m0 + ty * 4 + i;
        float4 o;
        o.x = acc[i][0] + bv.x;
        o.y = acc[i][1] + bv.y;
        o.z = acc[i][2] + bv.z;
        o.w = acc[i][3] + bv.w;
        if (RELU) {
            o.x = fmaxf(o.x, 0.f); o.y = fmaxf(o.y, 0.f);
            o.z = fmaxf(o.z, 0.f); o.w = fmaxf(o.w, 0.f);
        }
        *(float4*)&C[(long)m * N + n0 + tx * 4] = o;
    }
}

// ---------------------------------------------------------------------------
// Attention: one block per (batch, head), 64 threads (thread = query row)
// ---------------------------------------------------------------------------
__global__ __launch_bounds__(64) void attn_kernel(
    const float* __restrict__ qkv,   // [NTOK][3*DMODEL]
    float* __restrict__ o)           // [NTOK][DMODEL]
{
    const int b = blockIdx.x >> 3;
    const int h = blockIdx.x & 7;
    const int j = threadIdx.x;       // query row
    const int t = b * SEQL + j;

    __shared__ float Kt[SEQL][HDIM];
    __shared__ float Vt[SEQL][HDIM];
    __shared__ float S[SEQL][SEQL + 1];

    const float scale = 0.17677669529663687f;  // 1/sqrt(32)
    const float* base = qkv + (long)t * 768 + h * HDIM;

    #pragma unroll
    for (int c = 0; c < HDIM / 4; ++c) {
        *(float4*)&Kt[j][c * 4] = *(const float4*)&base[256 + c * 4];
        *(float4*)&Vt[j][c * 4] = *(const float4*)&base[512 + c * 4];
    }
    float q[HDIM];
    #pragma unroll
    for (int d = 0; d < HDIM; ++d) q[d] = base[d] * scale;
    __syncthreads();

    float mx = -1e30f;
    for (int jj = 0; jj < SEQL; ++jj) {
        float s = 0.f;
        #pragma unroll
        for (int d = 0; d < HDIM; ++d) s += q[d] * Kt[jj][d];
        S[j][jj] = s;
        mx = fmaxf(mx, s);
    }
    float sum = 0.f;
    for (int jj = 0; jj < SEQL; ++jj) {
        float e = __expf(S[j][jj] - mx);
        S[j][jj] = e;
        sum += e;
    }
    const float inv = 1.f / sum;

    float acc[HDIM] = {};
    for (int jj = 0; jj < SEQL; ++jj) {
        float p = S[j][jj];
        #pragma unroll
        for (int d = 0; d < HDIM; ++d) acc[d] += p * Vt[jj][d];
    }
    float* orow = o + (long)t * DMODEL + h * HDIM;
    #pragma unroll
    for (int d = 0; d < HDIM; ++d) orow[d] = acc[d] * inv;
}

// ---------------------------------------------------------------------------
// x = LayerNorm(xin + f) * g + b ; one wave per token, 4 tokens/block
// ---------------------------------------------------------------------------
__global__ __launch_bounds__(256) void add_ln_kernel(
    const float* __restrict__ xin,
    const float* __restrict__ f,
    const float* __restrict__ g,
    const float* __restrict__ bta,
    float* __restrict__ xout)
{
    const int w = threadIdx.x >> 6;
    const int lane = threadIdx.x & 63;
    const int t = blockIdx.x * 4 + w;

    float4 xv = *(const float4*)&xin[(long)t * DMODEL + lane * 4];
    float4 fv = *(const float4*)&f[(long)t * DMODEL + lane * 4];
    float v0 = xv.x + fv.x, v1 = xv.y + fv.y, v2 = xv.z + fv.z, v3 = xv.w + fv.w;

    float s  = v0 + v1 + v2 + v3;
    float sq = v0 * v0 + v1 * v1 + v2 * v2 + v3 * v3;
    #pragma unroll
    for (int off = 1; off < 64; off <<= 1) {
        s  += __shfl_xor(s, off);
        sq += __shfl_xor(sq, off);
    }
    float mean = s * (1.f / 256.f);
    float var  = sq * (1.f / 256.f) - mean * mean;
    float rs   = rsqrtf(var + 1e-5f);

    float4 gv = *(const float4*)&g[lane * 4];
    float4 bv = *(const float4*)&bta[lane * 4];
    float4 o;
    o.x = (v0 - mean) * rs * gv.x + bv.x;
    o.y = (v1 - mean) * rs * gv.y + bv.y;
    o.z = (v2 - mean) * rs * gv.z + bv.z;
    o.w = (v3 - mean) * rs * gv.w + bv.w;
    *(float4*)&xout[(long)t * DMODEL + lane * 4] = o;
}

// ---------------------------------------------------------------------------
extern "C" void kernel_launch(void* const* d_in, const int* in_sizes, int n_in,
                              void* d_out, int out_size, void* d_ws, size_t ws_size,
                              hipStream_t stream) {
    const int*   word_idx  = (const int*)d_in[0];
    const int*   ngram_idx = (const int*)d_in[1];
    const float* fc1_w = (const float*)d_in[2];
    const float* fc1_b = (const float*)d_in[3];
    const float* fc2_w = (const float*)d_in[4];
    const float* fc2_b = (const float*)d_in[5];
    const float* qkv_w = (const float*)d_in[6];
    const float* qkv_b = (const float*)d_in[7];
    const float* out_w = (const float*)d_in[8];
    const float* out_b = (const float*)d_in[9];
    const float* ln1_g = (const float*)d_in[10];
    const float* ln1_b = (const float*)d_in[11];
    const float* ff1_w = (const float*)d_in[12];
    const float* ff1_b = (const float*)d_in[13];
    const float* ff2_w = (const float*)d_in[14];
    const float* ff2_b = (const float*)d_in[15];
    const float* ln2_g = (const float*)d_in[16];
    const float* ln2_b = (const float*)d_in[17];

    float* x = (float*)d_out;                    // [2048][256] — final answer lives here
    float* wsf      = (float*)d_ws;
    float* qkvbuf   = wsf;                       // 2048*768
    float* attn_raw = qkvbuf + 2048 * 768;       // 2048*256
    float* obuf     = attn_raw + 2048 * 256;     // 2048*256
    float* ffbuf    = obuf + 2048 * 256;         // 2048*1024

    embed_kernel<<<NTOK / 8, 256, 0, stream>>>(word_idx, ngram_idx, fc1_w, fc1_b,
                                               fc2_w, fc2_b, x);

    for (int i = 0; i < 2; ++i) {
        gemm_bias<false><<<dim3(768 / 64, NTOK / 64), 256, 0, stream>>>(
            x, qkv_w + (long)i * 768 * 256, qkv_b + i * 768, qkvbuf, NTOK, 768, 256);

        attn_kernel<<<32 * NHEAD, 64, 0, stream>>>(qkvbuf, attn_raw);

        gemm_bias<false><<<dim3(256 / 64, NTOK / 64), 256, 0, stream>>>(
            attn_raw, out_w + (long)i * 256 * 256, out_b + i * 256, obuf, NTOK, 256, 256);

        add_ln_kernel<<<NTOK / 4, 256, 0, stream>>>(x, obuf, ln1_g + i * 256,
                                                    ln1_b + i * 256, x);

        gemm_bias<true><<<dim3(1024 / 64, NTOK / 64), 256, 0, stream>>>(
            x, ff1_w + (long)i * 1024 * 256, ff1_b + i * 1024, ffbuf, NTOK, 1024, 256);

        gemm_bias<false><<<dim3(256 / 64, NTOK / 64), 256, 0, stream>>>(
            ffbuf, ff2_w + (long)i * 256 * 1024, ff2_b + i * 256, obuf, NTOK, 256, 1024);

        add_ln_kernel<<<NTOK / 4, 256, 0, stream>>>(x, obuf, ln2_g + i * 256,
                                                    ln2_b + i * 256, x);
    }
}

// Round 2
// 340.707 us; speedup vs baseline: 1.2177x; 1.2177x over previous
//
#include <hip/hip_runtime.h>
#include <hip/hip_bf16.h>
#include <math.h>

#define WORDC 30000
#define F_TOT 80000
#define NTOK  2048
#define DMODEL 256
#define FFDIM 512
#define NHEAD 8
#define HDIM  32
#define SEQL  64

__device__ __forceinline__ unsigned short f32_to_bf16_rne(float x) {
    unsigned int u = __float_as_uint(x);
    unsigned int r = (u + 0x7FFFu + ((u >> 16) & 1u)) >> 16;
    return (unsigned short)r;
}

// ---------------------------------------------------------------------------
// Transpose fc1_w [512][80000] f32  ->  fc1_wT [80000][512] bf16
// 64x64 tiles, 256 threads
// ---------------------------------------------------------------------------
__global__ __launch_bounds__(256) void transpose_fc1(
    const float* __restrict__ in,            // [512][80000]
    unsigned short* __restrict__ out)        // [80000][512] bf16 bits
{
    __shared__ float tile[64][65];
    const int f0  = blockIdx.x * 64;
    const int j0  = blockIdx.y * 64;
    const int tid = threadIdx.x;

    const int fr = (tid & 15) * 4;   // f offset in tile (load phase)
    const int jr = tid >> 4;         // 0..15
    #pragma unroll
    for (int p = 0; p < 4; ++p) {
        int j = j0 + p * 16 + jr;
        float4 v = *(const float4*)&in[(long)j * F_TOT + f0 + fr];
        tile[fr + 0][p * 16 + jr] = v.x;
        tile[fr + 1][p * 16 + jr] = v.y;
        tile[fr + 2][p * 16 + jr] = v.z;
        tile[fr + 3][p * 16 + jr] = v.w;
    }
    __syncthreads();

    const int jc  = (tid & 15) * 4;  // j offset in tile (store phase)
    const int fr2 = tid >> 4;        // 0..15
    #pragma unroll
    for (int p = 0; p < 4; ++p) {
        int fi = p * 16 + fr2;
        ushort4 o;
        o.x = f32_to_bf16_rne(tile[fi][jc + 0]);
        o.y = f32_to_bf16_rne(tile[fi][jc + 1]);
        o.z = f32_to_bf16_rne(tile[fi][jc + 2]);
        o.w = f32_to_bf16_rne(tile[fi][jc + 3]);
        *(ushort4*)&out[(long)(f0 + fi) * FFDIM + j0 + jc] = o;
    }
}

// ---------------------------------------------------------------------------
// Gather path using transposed fc1: dedupe -> sum bf16 rows -> relu -> fc2
// block = 8 tokens, 256 threads
// ---------------------------------------------------------------------------
__global__ __launch_bounds__(256) void embed_gather(
    const int* __restrict__ word_idx,
    const int* __restrict__ ngram_idx,
    const unsigned short* __restrict__ fc1_wT,  // [80000][512] bf16
    const float* __restrict__ fc1_b,
    const float* __restrict__ fc2_w,            // [256][512]
    const float* __restrict__ fc2_b,
    float* __restrict__ x)                      // [NTOK][DMODEL]
{
    __shared__ int   feats[8][8];
    __shared__ int   nf[8];
    __shared__ float x1[8][FFDIM];

    const int t0  = blockIdx.x * 8;
    const int tid = threadIdx.x;

    if (tid < 8) {
        int t = t0 + tid;
        int cnt = 0;
        feats[tid][cnt++] = word_idx[t];
        for (int k = 0; k < 6; ++k) {
            int f = WORDC + ngram_idx[t * 6 + k];
            bool dup = false;
            for (int s = 1; s < cnt; ++s)
                if (feats[tid][s] == f) dup = true;
            if (!dup) feats[tid][cnt++] = f;
        }
        nf[tid] = cnt;
    }
    __syncthreads();

    // thread owns j-pair (2*tid, 2*tid+1) for all 8 tokens
    const float2 bb = *(const float2*)&fc1_b[tid * 2];
    #pragma unroll
    for (int tt = 0; tt < 8; ++tt) {
        float a0 = bb.x, a1 = bb.y;
        int n = nf[tt];
        for (int s = 0; s < n; ++s) {
            unsigned int w = *(const unsigned int*)
                &fc1_wT[(long)feats[tt][s] * FFDIM + tid * 2];
            a0 += __uint_as_float((w & 0xFFFFu) << 16);
            a1 += __uint_as_float(w & 0xFFFF0000u);
        }
        x1[tt][tid * 2 + 0] = fmaxf(a0, 0.f);
        x1[tt][tid * 2 + 1] = fmaxf(a1, 0.f);
    }
    __syncthreads();

    // fc2: thread d computes 8 token outputs
    const int d = tid;
    float acc[8];
    float cb = fc2_b[d];
    #pragma unroll
    for (int tt = 0; tt < 8; ++tt) acc[tt] = cb;
    const float* wrow = fc2_w + d * FFDIM;
    for (int k = 0; k < FFDIM; ++k) {
        float w = wrow[k];
        #pragma unroll
        for (int tt = 0; tt < 8; ++tt) acc[tt] += w * x1[tt][k];
    }
    #pragma unroll
    for (int tt = 0; tt < 8; ++tt)
        x[(t0 + tt) * DMODEL + d] = acc[tt];
}

// ---------------------------------------------------------------------------
// Fallback fused sparse embed (original scattered-column path)
// ---------------------------------------------------------------------------
__global__ __launch_bounds__(256) void embed_kernel(
    const int* __restrict__ word_idx,
    const int* __restrict__ ngram_idx,
    const float* __restrict__ fc1_w,
    const float* __restrict__ fc1_b,
    const float* __restrict__ fc2_w,
    const float* __restrict__ fc2_b,
    float* __restrict__ x)
{
    __shared__ int   feats[8][8];
    __shared__ int   nf[8];
    __shared__ float x1[8][FFDIM];

    const int t0  = blockIdx.x * 8;
    const int tid = threadIdx.x;

    if (tid < 8) {
        int t = t0 + tid;
        int cnt = 0;
        feats[tid][cnt++] = word_idx[t];
        for (int k = 0; k < 6; ++k) {
            int f = WORDC + ngram_idx[t * 6 + k];
            bool dup = false;
            for (int s = 1; s < cnt; ++s)
                if (feats[tid][s] == f) dup = true;
            if (!dup) feats[tid][cnt++] = f;
        }
        nf[tid] = cnt;
    }
    __syncthreads();

    for (int it = 0; it < 16; ++it) {
        int item = it * 256 + tid;
        int tt = item >> 9;
        int j  = item & 511;
        float acc = fc1_b[j];
        int n = nf[tt];
        const float* rowbase = fc1_w + (long)j * F_TOT;
        for (int s = 0; s < n; ++s)
            acc += rowbase[feats[tt][s]];
        x1[tt][j] = fmaxf(acc, 0.f);
    }
    __syncthreads();

    const int d = tid;
    float acc[8];
    float bb = fc2_b[d];
    #pragma unroll
    for (int tt = 0; tt < 8; ++tt) acc[tt] = bb;
    const float* wrow = fc2_w + d * FFDIM;
    for (int k = 0; k < FFDIM; ++k) {
        float w = wrow[k];
        #pragma unroll
        for (int tt = 0; tt < 8; ++tt) acc[tt] += w * x1[tt][k];
    }
    #pragma unroll
    for (int tt = 0; tt < 8; ++tt)
        x[(t0 + tt) * DMODEL + d] = acc[tt];
}

// ---------------------------------------------------------------------------
// fp32 tiled GEMM:  C[M][N] = A[M][K] @ W[N][K]^T + bias[N]  (optional relu)
// ---------------------------------------------------------------------------
template<bool RELU>
__global__ __launch_bounds__(256) void gemm_bias(
    const float* __restrict__ A,
    const float* __restrict__ W,
    const float* __restrict__ bias,
    float* __restrict__ C,
    int M, int N, int K)
{
    __shared__ float sA[16][64];
    __shared__ float sW[16][64];

    const int tid = threadIdx.x;
    const int tx = tid & 15;
    const int ty = tid >> 4;
    const int m0 = blockIdx.y * 64;
    const int n0 = blockIdx.x * 64;

    const int lr = tid >> 2;
    const int lc = tid & 3;

    float acc[4][4] = {};

    for (int k0 = 0; k0 < K; k0 += 16) {
        float4 av = *(const float4*)&A[(long)(m0 + lr) * K + k0 + lc * 4];
        float4 wv = *(const float4*)&W[(long)(n0 + lr) * K + k0 + lc * 4];
        __syncthreads();
        sA[lc * 4 + 0][lr] = av.x; sA[lc * 4 + 1][lr] = av.y;
        sA[lc * 4 + 2][lr] = av.z; sA[lc * 4 + 3][lr] = av.w;
        sW[lc * 4 + 0][lr] = wv.x; sW[lc * 4 + 1][lr] = wv.y;
        sW[lc * 4 + 2][lr] = wv.z; sW[lc * 4 + 3][lr] = wv.w;
        __syncthreads();
        #pragma unroll
        for (int k = 0; k < 16; ++k) {
            float4 a4 = *(const float4*)&sA[k][ty * 4];
            float4 b4 = *(const float4*)&sW[k][tx * 4];
            float am[4] = {a4.x, a4.y, a4.z, a4.w};
            float bn[4] = {b4.x, b4.y, b4.z, b4.w};
            #pragma unroll
            for (int i = 0; i < 4; ++i)
                #pragma unroll
                for (int j = 0; j < 4; ++j)
                    acc[i][j] += am[i] * bn[j];
        }
    }

    float4 bv = *(const float4*)&bias[n0 + tx * 4];
    #pragma unroll
    for (int i = 0; i < 4; ++i) {
        int m = m0 + ty * 4 + i;
        float4 o;
        o.x = acc[i][0] + bv.x;
        o.y = acc[i][1] + bv.y;
        o.z = acc[i][2] + bv.z;
        o.w = acc[i][3] + bv.w;
        if (RELU) {
            o.x = fmaxf(o.x, 0.f); o.y = fmaxf(o.y, 0.f);
            o.z = fmaxf(o.z, 0.f); o.w = fmaxf(o.w, 0.f);
        }
        *(float4*)&C[(long)m * N + n0 + tx * 4] = o;
    }
}

// ---------------------------------------------------------------------------
// Attention: one block per (batch, head), 64 threads (thread = query row)
// ---------------------------------------------------------------------------
__global__ __launch_bounds__(64) void attn_kernel(
    const float* __restrict__ qkv,
    float* __restrict__ o)
{
    const int b = blockIdx.x >> 3;
    const int h = blockIdx.x & 7;
    const int j = threadIdx.x;
    const int t = b * SEQL + j;

    __shared__ float Kt[SEQL][HDIM];
    __shared__ float Vt[SEQL][HDIM];
    __shared__ float S[SEQL][SEQL + 1];

    const float scale = 0.17677669529663687f;
    const float* base = qkv + (long)t * 768 + h * HDIM;

    #pragma unroll
    for (int c = 0; c < HDIM / 4; ++c) {
        *(float4*)&Kt[j][c * 4] = *(const float4*)&base[256 + c * 4];
        *(float4*)&Vt[j][c * 4] = *(const float4*)&base[512 + c * 4];
    }
    float q[HDIM];
    #pragma unroll
    for (int d = 0; d < HDIM; ++d) q[d] = base[d] * scale;
    __syncthreads();

    float mx = -1e30f;
    for (int jj = 0; jj < SEQL; ++jj) {
        float s = 0.f;
        #pragma unroll
        for (int d = 0; d < HDIM; ++d) s += q[d] * Kt[jj][d];
        S[j][jj] = s;
        mx = fmaxf(mx, s);
    }
    float sum = 0.f;
    for (int jj = 0; jj < SEQL; ++jj) {
        float e = __expf(S[j][jj] - mx);
        S[j][jj] = e;
        sum += e;
    }
    const float inv = 1.f / sum;

    float acc[HDIM] = {};
    for (int jj = 0; jj < SEQL; ++jj) {
        float p = S[j][jj];
        #pragma unroll
        for (int d = 0; d < HDIM; ++d) acc[d] += p * Vt[jj][d];
    }
    float* orow = o + (long)t * DMODEL + h * HDIM;
    #pragma unroll
    for (int d = 0; d < HDIM; ++d) orow[d] = acc[d] * inv;
}

// ---------------------------------------------------------------------------
// x = LayerNorm(xin + f) * g + b
// ---------------------------------------------------------------------------
__global__ __launch_bounds__(256) void add_ln_kernel(
    const float* __restrict__ xin,
    const float* __restrict__ f,
    const float* __restrict__ g,
    const float* __restrict__ bta,
    float* __restrict__ xout)
{
    const int w = threadIdx.x >> 6;
    const int lane = threadIdx.x & 63;
    const int t = blockIdx.x * 4 + w;

    float4 xv = *(const float4*)&xin[(long)t * DMODEL + lane * 4];
    float4 fv = *(const float4*)&f[(long)t * DMODEL + lane * 4];
    float v0 = xv.x + fv.x, v1 = xv.y + fv.y, v2 = xv.z + fv.z, v3 = xv.w + fv.w;

    float s  = v0 + v1 + v2 + v3;
    float sq = v0 * v0 + v1 * v1 + v2 * v2 + v3 * v3;
    #pragma unroll
    for (int off = 1; off < 64; off <<= 1) {
        s  += __shfl_xor(s, off);
        sq += __shfl_xor(sq, off);
    }
    float mean = s * (1.f / 256.f);
    float var  = sq * (1.f / 256.f) - mean * mean;
    float rs   = rsqrtf(var + 1e-5f);

    float4 gv = *(const float4*)&g[lane * 4];
    float4 bv = *(const float4*)&bta[lane * 4];
    float4 o;
    o.x = (v0 - mean) * rs * gv.x + bv.x;
    o.y = (v1 - mean) * rs * gv.y + bv.y;
    o.z = (v2 - mean) * rs * gv.z + bv.z;
    o.w = (v3 - mean) * rs * gv.w + bv.w;
    *(float4*)&xout[(long)t * DMODEL + lane * 4] = o;
}

// ---------------------------------------------------------------------------
extern "C" void kernel_launch(void* const* d_in, const int* in_sizes, int n_in,
                              void* d_out, int out_size, void* d_ws, size_t ws_size,
                              hipStream_t stream) {
    const int*   word_idx  = (const int*)d_in[0];
    const int*   ngram_idx = (const int*)d_in[1];
    const float* fc1_w = (const float*)d_in[2];
    const float* fc1_b = (const float*)d_in[3];
    const float* fc2_w = (const float*)d_in[4];
    const float* fc2_b = (const float*)d_in[5];
    const float* qkv_w = (const float*)d_in[6];
    const float* qkv_b = (const float*)d_in[7];
    const float* out_w = (const float*)d_in[8];
    const float* out_b = (const float*)d_in[9];
    const float* ln1_g = (const float*)d_in[10];
    const float* ln1_b = (const float*)d_in[11];
    const float* ff1_w = (const float*)d_in[12];
    const float* ff1_b = (const float*)d_in[13];
    const float* ff2_w = (const float*)d_in[14];
    const float* ff2_b = (const float*)d_in[15];
    const float* ln2_g = (const float*)d_in[16];
    const float* ln2_b = (const float*)d_in[17];

    float* x = (float*)d_out;  // [2048][256]

    const size_t FC1T_BYTES = (size_t)F_TOT * FFDIM * 2;            // 81,920,000
    const size_t FLOAT_BYTES = (size_t)2048 * 2304 * 4;             // 18,874,368
    const bool use_transpose = ws_size >= FC1T_BYTES + FLOAT_BYTES;

    unsigned short* fc1T = (unsigned short*)d_ws;
    float* wsf = use_transpose
        ? (float*)((char*)d_ws + FC1T_BYTES)
        : (float*)d_ws;
    float* qkvbuf   = wsf;                       // 2048*768
    float* attn_raw = qkvbuf + 2048 * 768;       // 2048*256
    float* obuf     = attn_raw + 2048 * 256;     // 2048*256
    float* ffbuf    = obuf + 2048 * 256;         // 2048*1024

    if (use_transpose) {
        transpose_fc1<<<dim3(F_TOT / 64, 8), 256, 0, stream>>>(fc1_w, fc1T);
        embed_gather<<<NTOK / 8, 256, 0, stream>>>(word_idx, ngram_idx, fc1T,
                                                   fc1_b, fc2_w, fc2_b, x);
    } else {
        embed_kernel<<<NTOK / 8, 256, 0, stream>>>(word_idx, ngram_idx, fc1_w,
                                                   fc1_b, fc2_w, fc2_b, x);
    }

    for (int i = 0; i < 2; ++i) {
        gemm_bias<false><<<dim3(768 / 64, NTOK / 64), 256, 0, stream>>>(
            x, qkv_w + (long)i * 768 * 256, qkv_b + i * 768, qkvbuf, NTOK, 768, 256);

        attn_kernel<<<32 * NHEAD, 64, 0, stream>>>(qkvbuf, attn_raw);

        gemm_bias<false><<<dim3(256 / 64, NTOK / 64), 256, 0, stream>>>(
            attn_raw, out_w + (long)i * 256 * 256, out_b + i * 256, obuf, NTOK, 256, 256);

        add_ln_kernel<<<NTOK / 4, 256, 0, stream>>>(x, obuf, ln1_g + i * 256,
                                                    ln1_b + i * 256, x);

        gemm_bias<true><<<dim3(1024 / 64, NTOK / 64), 256, 0, stream>>>(
            x, ff1_w + (long)i * 1024 * 256, ff1_b + i * 1024, ffbuf, NTOK, 1024, 256);

        gemm_bias<false><<<dim3(256 / 64, NTOK / 64), 256, 0, stream>>>(
            ffbuf, ff2_w + (long)i * 256 * 1024, ff2_b + i * 256, obuf, NTOK, 256, 1024);

        add_ln_kernel<<<NTOK / 4, 256, 0, stream>>>(x, obuf, ln2_g + i * 256,
                                                    ln2_b + i * 256, x);
    }
}

// Round 3
// 218.226 us; speedup vs baseline: 1.9011x; 1.5613x over previous
//
#include <hip/hip_runtime.h>
#include <hip/hip_bf16.h>
#include <math.h>

#define WORDC 30000
#define F_TOT 80000
#define NTOK  2048
#define DMODEL 256
#define FFDIM 512
#define NHEAD 8
#define HDIM  32
#define SEQL  64

typedef __attribute__((ext_vector_type(8))) short bf16x8;
typedef __attribute__((ext_vector_type(8))) unsigned short u16x8;
typedef __attribute__((ext_vector_type(4))) float f32x4;

__device__ __forceinline__ unsigned short f32_to_bf16_rne(float x) {
    unsigned int u = __float_as_uint(x);
    unsigned int r = (u + 0x7FFFu + ((u >> 16) & 1u)) >> 16;
    return (unsigned short)r;
}

// ---------------------------------------------------------------------------
// Transpose fc1_w [512][80000] f32  ->  fc1_wT [80000][512] bf16
// ---------------------------------------------------------------------------
__global__ __launch_bounds__(256) void transpose_fc1(
    const float* __restrict__ in,
    unsigned short* __restrict__ out)
{
    __shared__ float tile[64][65];
    const int f0  = blockIdx.x * 64;
    const int j0  = blockIdx.y * 64;
    const int tid = threadIdx.x;

    const int fr = (tid & 15) * 4;
    const int jr = tid >> 4;
    #pragma unroll
    for (int p = 0; p < 4; ++p) {
        int j = j0 + p * 16 + jr;
        float4 v = *(const float4*)&in[(long)j * F_TOT + f0 + fr];
        tile[fr + 0][p * 16 + jr] = v.x;
        tile[fr + 1][p * 16 + jr] = v.y;
        tile[fr + 2][p * 16 + jr] = v.z;
        tile[fr + 3][p * 16 + jr] = v.w;
    }
    __syncthreads();

    const int jc  = (tid & 15) * 4;
    const int fr2 = tid >> 4;
    #pragma unroll
    for (int p = 0; p < 4; ++p) {
        int fi = p * 16 + fr2;
        ushort4 o;
        o.x = f32_to_bf16_rne(tile[fi][jc + 0]);
        o.y = f32_to_bf16_rne(tile[fi][jc + 1]);
        o.z = f32_to_bf16_rne(tile[fi][jc + 2]);
        o.w = f32_to_bf16_rne(tile[fi][jc + 3]);
        *(ushort4*)&out[(long)(f0 + fi) * FFDIM + j0 + jc] = o;
    }
}

// ---------------------------------------------------------------------------
// Convert the 4 transformer weight tensors (both layers) fp32 -> bf16
// blockIdx.y selects tensor
// ---------------------------------------------------------------------------
__global__ __launch_bounds__(256) void cvt_weights(
    const float* __restrict__ s0, const float* __restrict__ s1,
    const float* __restrict__ s2, const float* __restrict__ s3,
    unsigned short* __restrict__ d0, unsigned short* __restrict__ d1,
    unsigned short* __restrict__ d2, unsigned short* __restrict__ d3)
{
    const float* s; unsigned short* d; int n4;
    switch (blockIdx.y) {
        case 0: s = s0; d = d0; n4 = 2 * 768 * 256 / 4;  break;
        case 1: s = s1; d = d1; n4 = 2 * 256 * 256 / 4;  break;
        case 2: s = s2; d = d2; n4 = 2 * 1024 * 256 / 4; break;
        default: s = s3; d = d3; n4 = 2 * 256 * 1024 / 4; break;
    }
    for (int i = blockIdx.x * 256 + threadIdx.x; i < n4; i += gridDim.x * 256) {
        float4 v = ((const float4*)s)[i];
        ushort4 o;
        o.x = f32_to_bf16_rne(v.x);
        o.y = f32_to_bf16_rne(v.y);
        o.z = f32_to_bf16_rne(v.z);
        o.w = f32_to_bf16_rne(v.w);
        ((ushort4*)d)[i] = o;
    }
}

// ---------------------------------------------------------------------------
// MFMA GEMM: C[M][N] = A[M][K](f32, cvt->bf16) @ Wb[N][K](bf16)^T + bias
// 64x64 tile, BK=32, 256 threads = 4 waves (2x2), wave = 32x32 (2x2 frags)
// LDS rows padded to 40 bf16 (80B) -> 2-way bank aliasing only (free)
// ---------------------------------------------------------------------------
template<bool RELU>
__global__ __launch_bounds__(256) void gemm_mfma(
    const float* __restrict__ A,
    const unsigned short* __restrict__ Wb,
    const float* __restrict__ bias,
    float* __restrict__ C,
    int M, int N, int K)
{
    __shared__ unsigned short sA[64 * 40];
    __shared__ unsigned short sW[64 * 40];

    const int tid  = threadIdx.x;
    const int lane = tid & 63;
    const int w    = tid >> 6;
    const int wr   = w >> 1;          // wave m (0..1)
    const int wc   = w & 1;           // wave n (0..1)
    const int m0   = blockIdx.y * 64;
    const int n0   = blockIdx.x * 64;

    const int srow = tid >> 2;        // staging row 0..63
    const int ssub = tid & 3;         // 8-elem chunk 0..3

    const int fr   = lane & 15;       // frag row/col
    const int ksub = lane >> 4;       // 0..3, k-chunk of 8

    f32x4 acc[2][2] = {};

    for (int k0 = 0; k0 < K; k0 += 32) {
        // issue global loads early
        const float* ap = &A[(long)(m0 + srow) * K + k0 + ssub * 8];
        float4 a0 = *(const float4*)ap;
        float4 a1 = *(const float4*)(ap + 4);
        u16x8 wv = *(const u16x8*)&Wb[(long)(n0 + srow) * K + k0 + ssub * 8];

        __syncthreads();   // previous compute done before overwrite

        u16x8 av;
        av[0] = f32_to_bf16_rne(a0.x); av[1] = f32_to_bf16_rne(a0.y);
        av[2] = f32_to_bf16_rne(a0.z); av[3] = f32_to_bf16_rne(a0.w);
        av[4] = f32_to_bf16_rne(a1.x); av[5] = f32_to_bf16_rne(a1.y);
        av[6] = f32_to_bf16_rne(a1.z); av[7] = f32_to_bf16_rne(a1.w);
        *(u16x8*)&sA[srow * 40 + ssub * 8] = av;
        *(u16x8*)&sW[srow * 40 + ssub * 8] = wv;

        __syncthreads();   // tile ready

        #pragma unroll
        for (int mi = 0; mi < 2; ++mi) {
            bf16x8 af = *(bf16x8*)&sA[(wr * 32 + mi * 16 + fr) * 40 + ksub * 8];
            #pragma unroll
            for (int ni = 0; ni < 2; ++ni) {
                bf16x8 bf = *(bf16x8*)&sW[(wc * 32 + ni * 16 + fr) * 40 + ksub * 8];
                acc[mi][ni] = __builtin_amdgcn_mfma_f32_16x16x32_bf16(
                    af, bf, acc[mi][ni], 0, 0, 0);
            }
        }
    }

    // epilogue: C/D layout col=lane&15, row=(lane>>4)*4+r
    #pragma unroll
    for (int mi = 0; mi < 2; ++mi) {
        #pragma unroll
        for (int ni = 0; ni < 2; ++ni) {
            int col = n0 + wc * 32 + ni * 16 + fr;
            float bv = bias[col];
            #pragma unroll
            for (int r = 0; r < 4; ++r) {
                int row = m0 + wr * 32 + mi * 16 + ksub * 4 + r;
                float v = acc[mi][ni][r] + bv;
                if (RELU) v = fmaxf(v, 0.f);
                C[(long)row * N + col] = v;
            }
        }
    }
}

// ---------------------------------------------------------------------------
// Gather path: dedupe -> sum bf16 rows of fc1T -> relu -> fc2
// ---------------------------------------------------------------------------
__global__ __launch_bounds__(256) void embed_gather(
    const int* __restrict__ word_idx,
    const int* __restrict__ ngram_idx,
    const unsigned short* __restrict__ fc1_wT,
    const float* __restrict__ fc1_b,
    const float* __restrict__ fc2_w,
    const float* __restrict__ fc2_b,
    float* __restrict__ x)
{
    __shared__ int   feats[8][8];
    __shared__ int   nf[8];
    __shared__ float x1[8][FFDIM];

    const int t0  = blockIdx.x * 8;
    const int tid = threadIdx.x;

    if (tid < 8) {
        int t = t0 + tid;
        int cnt = 0;
        feats[tid][cnt++] = word_idx[t];
        for (int k = 0; k < 6; ++k) {
            int f = WORDC + ngram_idx[t * 6 + k];
            bool dup = false;
            for (int s = 1; s < cnt; ++s)
                if (feats[tid][s] == f) dup = true;
            if (!dup) feats[tid][cnt++] = f;
        }
        nf[tid] = cnt;
    }
    __syncthreads();

    const float2 bb = *(const float2*)&fc1_b[tid * 2];
    #pragma unroll
    for (int tt = 0; tt < 8; ++tt) {
        float a0 = bb.x, a1 = bb.y;
        int n = nf[tt];
        for (int s = 0; s < n; ++s) {
            unsigned int wrd = *(const unsigned int*)
                &fc1_wT[(long)feats[tt][s] * FFDIM + tid * 2];
            a0 += __uint_as_float((wrd & 0xFFFFu) << 16);
            a1 += __uint_as_float(wrd & 0xFFFF0000u);
        }
        x1[tt][tid * 2 + 0] = fmaxf(a0, 0.f);
        x1[tt][tid * 2 + 1] = fmaxf(a1, 0.f);
    }
    __syncthreads();

    const int d = tid;
    float acc[8];
    float cb = fc2_b[d];
    #pragma unroll
    for (int tt = 0; tt < 8; ++tt) acc[tt] = cb;
    const float* wrow = fc2_w + d * FFDIM;
    for (int k = 0; k < FFDIM; ++k) {
        float wv = wrow[k];
        #pragma unroll
        for (int tt = 0; tt < 8; ++tt) acc[tt] += wv * x1[tt][k];
    }
    #pragma unroll
    for (int tt = 0; tt < 8; ++tt)
        x[(t0 + tt) * DMODEL + d] = acc[tt];
}

// ---------------------------------------------------------------------------
// Fallback fused sparse embed (scattered-column path, fp32)
// ---------------------------------------------------------------------------
__global__ __launch_bounds__(256) void embed_kernel(
    const int* __restrict__ word_idx,
    const int* __restrict__ ngram_idx,
    const float* __restrict__ fc1_w,
    const float* __restrict__ fc1_b,
    const float* __restrict__ fc2_w,
    const float* __restrict__ fc2_b,
    float* __restrict__ x)
{
    __shared__ int   feats[8][8];
    __shared__ int   nf[8];
    __shared__ float x1[8][FFDIM];

    const int t0  = blockIdx.x * 8;
    const int tid = threadIdx.x;

    if (tid < 8) {
        int t = t0 + tid;
        int cnt = 0;
        feats[tid][cnt++] = word_idx[t];
        for (int k = 0; k < 6; ++k) {
            int f = WORDC + ngram_idx[t * 6 + k];
            bool dup = false;
            for (int s = 1; s < cnt; ++s)
                if (feats[tid][s] == f) dup = true;
            if (!dup) feats[tid][cnt++] = f;
        }
        nf[tid] = cnt;
    }
    __syncthreads();

    for (int it = 0; it < 16; ++it) {
        int item = it * 256 + tid;
        int tt = item >> 9;
        int j  = item & 511;
        float acc = fc1_b[j];
        int n = nf[tt];
        const float* rowbase = fc1_w + (long)j * F_TOT;
        for (int s = 0; s < n; ++s)
            acc += rowbase[feats[tt][s]];
        x1[tt][j] = fmaxf(acc, 0.f);
    }
    __syncthreads();

    const int d = tid;
    float acc[8];
    float bb = fc2_b[d];
    #pragma unroll
    for (int tt = 0; tt < 8; ++tt) acc[tt] = bb;
    const float* wrow = fc2_w + d * FFDIM;
    for (int k = 0; k < FFDIM; ++k) {
        float wv = wrow[k];
        #pragma unroll
        for (int tt = 0; tt < 8; ++tt) acc[tt] += wv * x1[tt][k];
    }
    #pragma unroll
    for (int tt = 0; tt < 8; ++tt)
        x[(t0 + tt) * DMODEL + d] = acc[tt];
}

// ---------------------------------------------------------------------------
// fp32 tiled GEMM (fallback path only)
// ---------------------------------------------------------------------------
template<bool RELU>
__global__ __launch_bounds__(256) void gemm_bias(
    const float* __restrict__ A,
    const float* __restrict__ W,
    const float* __restrict__ bias,
    float* __restrict__ C,
    int M, int N, int K)
{
    __shared__ float sA[16][64];
    __shared__ float sW[16][64];

    const int tid = threadIdx.x;
    const int tx = tid & 15;
    const int ty = tid >> 4;
    const int m0 = blockIdx.y * 64;
    const int n0 = blockIdx.x * 64;

    const int lr = tid >> 2;
    const int lc = tid & 3;

    float acc[4][4] = {};

    for (int k0 = 0; k0 < K; k0 += 16) {
        float4 av = *(const float4*)&A[(long)(m0 + lr) * K + k0 + lc * 4];
        float4 wv = *(const float4*)&W[(long)(n0 + lr) * K + k0 + lc * 4];
        __syncthreads();
        sA[lc * 4 + 0][lr] = av.x; sA[lc * 4 + 1][lr] = av.y;
        sA[lc * 4 + 2][lr] = av.z; sA[lc * 4 + 3][lr] = av.w;
        sW[lc * 4 + 0][lr] = wv.x; sW[lc * 4 + 1][lr] = wv.y;
        sW[lc * 4 + 2][lr] = wv.z; sW[lc * 4 + 3][lr] = wv.w;
        __syncthreads();
        #pragma unroll
        for (int k = 0; k < 16; ++k) {
            float4 a4 = *(const float4*)&sA[k][ty * 4];
            float4 b4 = *(const float4*)&sW[k][tx * 4];
            float am[4] = {a4.x, a4.y, a4.z, a4.w};
            float bn[4] = {b4.x, b4.y, b4.z, b4.w};
            #pragma unroll
            for (int i = 0; i < 4; ++i)
                #pragma unroll
                for (int j = 0; j < 4; ++j)
                    acc[i][j] += am[i] * bn[j];
        }
    }

    float4 bv = *(const float4*)&bias[n0 + tx * 4];
    #pragma unroll
    for (int i = 0; i < 4; ++i) {
        int m = m0 + ty * 4 + i;
        float4 o;
        o.x = acc[i][0] + bv.x;
        o.y = acc[i][1] + bv.y;
        o.z = acc[i][2] + bv.z;
        o.w = acc[i][3] + bv.w;
        if (RELU) {
            o.x = fmaxf(o.x, 0.f); o.y = fmaxf(o.y, 0.f);
            o.z = fmaxf(o.z, 0.f); o.w = fmaxf(o.w, 0.f);
        }
        *(float4*)&C[(long)m * N + n0 + tx * 4] = o;
    }
}

// ---------------------------------------------------------------------------
// Attention: one block per (batch, head), 64 threads (thread = query row)
// ---------------------------------------------------------------------------
__global__ __launch_bounds__(64) void attn_kernel(
    const float* __restrict__ qkv,
    float* __restrict__ o)
{
    const int b = blockIdx.x >> 3;
    const int h = blockIdx.x & 7;
    const int j = threadIdx.x;
    const int t = b * SEQL + j;

    __shared__ float Kt[SEQL][HDIM];
    __shared__ float Vt[SEQL][HDIM];
    __shared__ float S[SEQL][SEQL + 1];

    const float scale = 0.17677669529663687f;
    const float* base = qkv + (long)t * 768 + h * HDIM;

    #pragma unroll
    for (int c = 0; c < HDIM / 4; ++c) {
        *(float4*)&Kt[j][c * 4] = *(const float4*)&base[256 + c * 4];
        *(float4*)&Vt[j][c * 4] = *(const float4*)&base[512 + c * 4];
    }
    float q[HDIM];
    #pragma unroll
    for (int d = 0; d < HDIM; ++d) q[d] = base[d] * scale;
    __syncthreads();

    float mx = -1e30f;
    for (int jj = 0; jj < SEQL; ++jj) {
        float s = 0.f;
        #pragma unroll
        for (int d = 0; d < HDIM; ++d) s += q[d] * Kt[jj][d];
        S[j][jj] = s;
        mx = fmaxf(mx, s);
    }
    float sum = 0.f;
    for (int jj = 0; jj < SEQL; ++jj) {
        float e = __expf(S[j][jj] - mx);
        S[j][jj] = e;
        sum += e;
    }
    const float inv = 1.f / sum;

    float acc[HDIM] = {};
    for (int jj = 0; jj < SEQL; ++jj) {
        float p = S[j][jj];
        #pragma unroll
        for (int d = 0; d < HDIM; ++d) acc[d] += p * Vt[jj][d];
    }
    float* orow = o + (long)t * DMODEL + h * HDIM;
    #pragma unroll
    for (int d = 0; d < HDIM; ++d) orow[d] = acc[d] * inv;
}

// ---------------------------------------------------------------------------
// x = LayerNorm(xin + f) * g + b
// ---------------------------------------------------------------------------
__global__ __launch_bounds__(256) void add_ln_kernel(
    const float* __restrict__ xin,
    const float* __restrict__ f,
    const float* __restrict__ g,
    const float* __restrict__ bta,
    float* __restrict__ xout)
{
    const int w = threadIdx.x >> 6;
    const int lane = threadIdx.x & 63;
    const int t = blockIdx.x * 4 + w;

    float4 xv = *(const float4*)&xin[(long)t * DMODEL + lane * 4];
    float4 fv = *(const float4*)&f[(long)t * DMODEL + lane * 4];
    float v0 = xv.x + fv.x, v1 = xv.y + fv.y, v2 = xv.z + fv.z, v3 = xv.w + fv.w;

    float s  = v0 + v1 + v2 + v3;
    float sq = v0 * v0 + v1 * v1 + v2 * v2 + v3 * v3;
    #pragma unroll
    for (int off = 1; off < 64; off <<= 1) {
        s  += __shfl_xor(s, off);
        sq += __shfl_xor(sq, off);
    }
    float mean = s * (1.f / 256.f);
    float var  = sq * (1.f / 256.f) - mean * mean;
    float rs   = rsqrtf(var + 1e-5f);

    float4 gv = *(const float4*)&g[lane * 4];
    float4 bv = *(const float4*)&bta[lane * 4];
    float4 o;
    o.x = (v0 - mean) * rs * gv.x + bv.x;
    o.y = (v1 - mean) * rs * gv.y + bv.y;
    o.z = (v2 - mean) * rs * gv.z + bv.z;
    o.w = (v3 - mean) * rs * gv.w + bv.w;
    *(float4*)&xout[(long)t * DMODEL + lane * 4] = o;
}

// ---------------------------------------------------------------------------
extern "C" void kernel_launch(void* const* d_in, const int* in_sizes, int n_in,
                              void* d_out, int out_size, void* d_ws, size_t ws_size,
                              hipStream_t stream) {
    const int*   word_idx  = (const int*)d_in[0];
    const int*   ngram_idx = (const int*)d_in[1];
    const float* fc1_w = (const float*)d_in[2];
    const float* fc1_b = (const float*)d_in[3];
    const float* fc2_w = (const float*)d_in[4];
    const float* fc2_b = (const float*)d_in[5];
    const float* qkv_w = (const float*)d_in[6];
    const float* qkv_b = (const float*)d_in[7];
    const float* out_w = (const float*)d_in[8];
    const float* out_b = (const float*)d_in[9];
    const float* ln1_g = (const float*)d_in[10];
    const float* ln1_b = (const float*)d_in[11];
    const float* ff1_w = (const float*)d_in[12];
    const float* ff1_b = (const float*)d_in[13];
    const float* ff2_w = (const float*)d_in[14];
    const float* ff2_b = (const float*)d_in[15];
    const float* ln2_g = (const float*)d_in[16];
    const float* ln2_b = (const float*)d_in[17];

    float* x = (float*)d_out;  // [2048][256]

    const size_t FC1T_ELEMS = (size_t)F_TOT * FFDIM;          // ushort
    const size_t WQKV_ELEMS = 2 * 768 * 256;
    const size_t WOUT_ELEMS = 2 * 256 * 256;
    const size_t WFF1_ELEMS = 2 * 1024 * 256;
    const size_t WFF2_ELEMS = 2 * 256 * 1024;
    const size_t BF16_BYTES = (FC1T_ELEMS + WQKV_ELEMS + WOUT_ELEMS +
                               WFF1_ELEMS + WFF2_ELEMS) * 2;
    const size_t FLOAT_BYTES = (size_t)2048 * 2304 * 4;
    const bool fast = ws_size >= BF16_BYTES + FLOAT_BYTES;

    if (fast) {
        unsigned short* fc1T  = (unsigned short*)d_ws;
        unsigned short* qkvT  = fc1T + FC1T_ELEMS;
        unsigned short* outT  = qkvT + WQKV_ELEMS;
        unsigned short* ff1T  = outT + WOUT_ELEMS;
        unsigned short* ff2T  = ff1T + WFF1_ELEMS;
        float* wsf      = (float*)((char*)d_ws + BF16_BYTES);
        float* qkvbuf   = wsf;
        float* attn_raw = qkvbuf + 2048 * 768;
        float* obuf     = attn_raw + 2048 * 256;
        float* ffbuf    = obuf + 2048 * 256;

        transpose_fc1<<<dim3(F_TOT / 64, 8), 256, 0, stream>>>(fc1_w, fc1T);
        cvt_weights<<<dim3(192, 4), 256, 0, stream>>>(
            qkv_w, out_w, ff1_w, ff2_w, qkvT, outT, ff1T, ff2T);
        embed_gather<<<NTOK / 8, 256, 0, stream>>>(word_idx, ngram_idx, fc1T,
                                                   fc1_b, fc2_w, fc2_b, x);

        for (int i = 0; i < 2; ++i) {
            gemm_mfma<false><<<dim3(768 / 64, NTOK / 64), 256, 0, stream>>>(
                x, qkvT + (long)i * 768 * 256, qkv_b + i * 768, qkvbuf,
                NTOK, 768, 256);

            attn_kernel<<<32 * NHEAD, 64, 0, stream>>>(qkvbuf, attn_raw);

            gemm_mfma<false><<<dim3(256 / 64, NTOK / 64), 256, 0, stream>>>(
                attn_raw, outT + (long)i * 256 * 256, out_b + i * 256, obuf,
                NTOK, 256, 256);

            add_ln_kernel<<<NTOK / 4, 256, 0, stream>>>(x, obuf, ln1_g + i * 256,
                                                        ln1_b + i * 256, x);

            gemm_mfma<true><<<dim3(1024 / 64, NTOK / 64), 256, 0, stream>>>(
                x, ff1T + (long)i * 1024 * 256, ff1_b + i * 1024, ffbuf,
                NTOK, 1024, 256);

            gemm_mfma<false><<<dim3(256 / 64, NTOK / 64), 256, 0, stream>>>(
                ffbuf, ff2T + (long)i * 256 * 1024, ff2_b + i * 256, obuf,
                NTOK, 256, 1024);

            add_ln_kernel<<<NTOK / 4, 256, 0, stream>>>(x, obuf, ln2_g + i * 256,
                                                        ln2_b + i * 256, x);
        }
    } else {
        float* wsf      = (float*)d_ws;
        float* qkvbuf   = wsf;
        float* attn_raw = qkvbuf + 2048 * 768;
        float* obuf     = attn_raw + 2048 * 256;
        float* ffbuf    = obuf + 2048 * 256;

        embed_kernel<<<NTOK / 8, 256, 0, stream>>>(word_idx, ngram_idx, fc1_w,
                                                   fc1_b, fc2_w, fc2_b, x);
        for (int i = 0; i < 2; ++i) {
            gemm_bias<false><<<dim3(768 / 64, NTOK / 64), 256, 0, stream>>>(
                x, qkv_w + (long)i * 768 * 256, qkv_b + i * 768, qkvbuf,
                NTOK, 768, 256);
            attn_kernel<<<32 * NHEAD, 64, 0, stream>>>(qkvbuf, attn_raw);
            gemm_bias<false><<<dim3(256 / 64, NTOK / 64), 256, 0, stream>>>(
                attn_raw, out_w + (long)i * 256 * 256, out_b + i * 256, obuf,
                NTOK, 256, 256);
            add_ln_kernel<<<NTOK / 4, 256, 0, stream>>>(x, obuf, ln1_g + i * 256,
                                                        ln1_b + i * 256, x);
            gemm_bias<true><<<dim3(1024 / 64, NTOK / 64), 256, 0, stream>>>(
                x, ff1_w + (long)i * 1024 * 256, ff1_b + i * 1024, ffbuf,
                NTOK, 1024, 256);
            gemm_bias<false><<<dim3(256 / 64, NTOK / 64), 256, 0, stream>>>(
                ffbuf, ff2_w + (long)i * 256 * 1024, ff2_b + i * 256, obuf,
                NTOK, 256, 1024);
            add_ln_kernel<<<NTOK / 4, 256, 0, stream>>>(x, obuf, ln2_g + i * 256,
                                                        ln2_b + i * 256, x);
        }
    }
}

// Round 4
// 216.930 us; speedup vs baseline: 1.9124x; 1.0060x over previous
//
#include <hip/hip_runtime.h>
#include <hip/hip_bf16.h>
#include <math.h>

#define WORDC 30000
#define F_TOT 80000
#define NTOK  2048
#define DMODEL 256
#define FFDIM 512
#define NHEAD 8
#define HDIM  32
#define SEQL  64

typedef __attribute__((ext_vector_type(8))) short bf16x8;
typedef __attribute__((ext_vector_type(8))) unsigned short u16x8;
typedef __attribute__((ext_vector_type(4))) float f32x4;

__device__ __forceinline__ unsigned short f32_to_bf16_rne(float x) {
    unsigned int u = __float_as_uint(x);
    unsigned int r = (u + 0x7FFFu + ((u >> 16) & 1u)) >> 16;
    return (unsigned short)r;
}

// ---------------------------------------------------------------------------
// Transpose fc1_w [512][80000] f32  ->  fc1_wT [80000][512] bf16
// ---------------------------------------------------------------------------
__global__ __launch_bounds__(256) void transpose_fc1(
    const float* __restrict__ in,
    unsigned short* __restrict__ out)
{
    __shared__ float tile[64][65];
    const int f0  = blockIdx.x * 64;
    const int j0  = blockIdx.y * 64;
    const int tid = threadIdx.x;

    const int fr = (tid & 15) * 4;
    const int jr = tid >> 4;
    #pragma unroll
    for (int p = 0; p < 4; ++p) {
        int j = j0 + p * 16 + jr;
        float4 v = *(const float4*)&in[(long)j * F_TOT + f0 + fr];
        tile[fr + 0][p * 16 + jr] = v.x;
        tile[fr + 1][p * 16 + jr] = v.y;
        tile[fr + 2][p * 16 + jr] = v.z;
        tile[fr + 3][p * 16 + jr] = v.w;
    }
    __syncthreads();

    const int jc  = (tid & 15) * 4;
    const int fr2 = tid >> 4;
    #pragma unroll
    for (int p = 0; p < 4; ++p) {
        int fi = p * 16 + fr2;
        ushort4 o;
        o.x = f32_to_bf16_rne(tile[fi][jc + 0]);
        o.y = f32_to_bf16_rne(tile[fi][jc + 1]);
        o.z = f32_to_bf16_rne(tile[fi][jc + 2]);
        o.w = f32_to_bf16_rne(tile[fi][jc + 3]);
        *(ushort4*)&out[(long)(f0 + fi) * FFDIM + j0 + jc] = o;
    }
}

// ---------------------------------------------------------------------------
// Convert the 4 transformer weight tensors fp32 -> bf16
// ---------------------------------------------------------------------------
__global__ __launch_bounds__(256) void cvt_weights(
    const float* __restrict__ s0, const float* __restrict__ s1,
    const float* __restrict__ s2, const float* __restrict__ s3,
    unsigned short* __restrict__ d0, unsigned short* __restrict__ d1,
    unsigned short* __restrict__ d2, unsigned short* __restrict__ d3)
{
    const float* s; unsigned short* d; int n4;
    switch (blockIdx.y) {
        case 0: s = s0; d = d0; n4 = 2 * 768 * 256 / 4;  break;
        case 1: s = s1; d = d1; n4 = 2 * 256 * 256 / 4;  break;
        case 2: s = s2; d = d2; n4 = 2 * 1024 * 256 / 4; break;
        default: s = s3; d = d3; n4 = 2 * 256 * 1024 / 4; break;
    }
    for (int i = blockIdx.x * 256 + threadIdx.x; i < n4; i += gridDim.x * 256) {
        float4 v = ((const float4*)s)[i];
        ushort4 o;
        o.x = f32_to_bf16_rne(v.x);
        o.y = f32_to_bf16_rne(v.y);
        o.z = f32_to_bf16_rne(v.z);
        o.w = f32_to_bf16_rne(v.w);
        ((ushort4*)d)[i] = o;
    }
}

// ---------------------------------------------------------------------------
// MFMA GEMM: C = A[M][K](f32->bf16) @ Wb[N][K]^T + bias ; optional relu,
// optional bf16 output. 64x64 tile, BK=32, 4 waves (2x2), wave 32x32.
// ---------------------------------------------------------------------------
template<bool RELU, bool OUT16>
__global__ __launch_bounds__(256) void gemm_mfma(
    const float* __restrict__ A,
    const unsigned short* __restrict__ Wb,
    const float* __restrict__ bias,
    void* __restrict__ Cout,
    int M, int N, int K)
{
    __shared__ unsigned short sA[64 * 40];
    __shared__ unsigned short sW[64 * 40];

    const int tid  = threadIdx.x;
    const int lane = tid & 63;
    const int w    = tid >> 6;
    const int wr   = w >> 1;
    const int wc   = w & 1;
    const int m0   = blockIdx.y * 64;
    const int n0   = blockIdx.x * 64;

    const int srow = tid >> 2;
    const int ssub = tid & 3;

    const int fr   = lane & 15;
    const int ksub = lane >> 4;

    f32x4 acc[2][2] = {};

    for (int k0 = 0; k0 < K; k0 += 32) {
        const float* ap = &A[(long)(m0 + srow) * K + k0 + ssub * 8];
        float4 a0 = *(const float4*)ap;
        float4 a1 = *(const float4*)(ap + 4);
        u16x8 wv = *(const u16x8*)&Wb[(long)(n0 + srow) * K + k0 + ssub * 8];

        __syncthreads();

        u16x8 av;
        av[0] = f32_to_bf16_rne(a0.x); av[1] = f32_to_bf16_rne(a0.y);
        av[2] = f32_to_bf16_rne(a0.z); av[3] = f32_to_bf16_rne(a0.w);
        av[4] = f32_to_bf16_rne(a1.x); av[5] = f32_to_bf16_rne(a1.y);
        av[6] = f32_to_bf16_rne(a1.z); av[7] = f32_to_bf16_rne(a1.w);
        *(u16x8*)&sA[srow * 40 + ssub * 8] = av;
        *(u16x8*)&sW[srow * 40 + ssub * 8] = wv;

        __syncthreads();

        #pragma unroll
        for (int mi = 0; mi < 2; ++mi) {
            bf16x8 af = *(bf16x8*)&sA[(wr * 32 + mi * 16 + fr) * 40 + ksub * 8];
            #pragma unroll
            for (int ni = 0; ni < 2; ++ni) {
                bf16x8 bf = *(bf16x8*)&sW[(wc * 32 + ni * 16 + fr) * 40 + ksub * 8];
                acc[mi][ni] = __builtin_amdgcn_mfma_f32_16x16x32_bf16(
                    af, bf, acc[mi][ni], 0, 0, 0);
            }
        }
    }

    #pragma unroll
    for (int mi = 0; mi < 2; ++mi) {
        #pragma unroll
        for (int ni = 0; ni < 2; ++ni) {
            int col = n0 + wc * 32 + ni * 16 + fr;
            float bv = bias[col];
            #pragma unroll
            for (int r = 0; r < 4; ++r) {
                int row = m0 + wr * 32 + mi * 16 + ksub * 4 + r;
                float v = acc[mi][ni][r] + bv;
                if (RELU) v = fmaxf(v, 0.f);
                if (OUT16)
                    ((unsigned short*)Cout)[(long)row * N + col] = f32_to_bf16_rne(v);
                else
                    ((float*)Cout)[(long)row * N + col] = v;
            }
        }
    }
}

// ---------------------------------------------------------------------------
// Fused GEMM + residual + LayerNorm:
//   xout = LN(xres + A@W^T + bias) * g + beta
// BM=16 rows, BN=256 (full width), BK=32, 256 threads = 4 waves (1x4).
// ---------------------------------------------------------------------------
template<int K, bool A_BF16>
__global__ __launch_bounds__(256) void gemm_ln(
    const void* __restrict__ Aptr,
    const unsigned short* __restrict__ Wb,
    const float* __restrict__ bias,
    const float* __restrict__ xres,
    const float* __restrict__ g,
    const float* __restrict__ beta,
    float* __restrict__ xout)
{
    __shared__ unsigned short sA[16 * 40];
    __shared__ unsigned short sW[256 * 40];
    __shared__ float redS[4][16];
    __shared__ float redQ[4][16];

    const int tid  = threadIdx.x;
    const int lane = tid & 63;
    const int w    = tid >> 6;           // wave -> col block w*64
    const int fr   = lane & 15;
    const int ksub = lane >> 4;
    const int m0   = blockIdx.x * 16;

    f32x4 acc[4] = {};

    for (int k0 = 0; k0 < K; k0 += 32) {
        // global loads to regs
        float4 a4;
        u16x8 a8;
        if (A_BF16) {
            if (tid < 64) {
                int row = tid >> 2, c8 = tid & 3;
                a8 = *(const u16x8*)&((const unsigned short*)Aptr)
                        [(long)(m0 + row) * K + k0 + c8 * 8];
            }
        } else {
            if (tid < 128) {
                int row = tid >> 3, c4 = tid & 7;
                a4 = *(const float4*)&((const float*)Aptr)
                        [(long)(m0 + row) * K + k0 + c4 * 4];
            }
        }
        u16x8 wv[4];
        #pragma unroll
        for (int c = 0; c < 4; ++c)
            wv[c] = *(const u16x8*)&Wb[(long)tid * K + k0 + c * 8];

        __syncthreads();

        if (A_BF16) {
            if (tid < 64) {
                int row = tid >> 2, c8 = tid & 3;
                *(u16x8*)&sA[row * 40 + c8 * 8] = a8;
            }
        } else {
            if (tid < 128) {
                int row = tid >> 3, c4 = tid & 7;
                ushort4 o;
                o.x = f32_to_bf16_rne(a4.x);
                o.y = f32_to_bf16_rne(a4.y);
                o.z = f32_to_bf16_rne(a4.z);
                o.w = f32_to_bf16_rne(a4.w);
                *(ushort4*)&sA[row * 40 + c4 * 4] = o;
            }
        }
        #pragma unroll
        for (int c = 0; c < 4; ++c)
            *(u16x8*)&sW[tid * 40 + c * 8] = wv[c];

        __syncthreads();

        bf16x8 af = *(bf16x8*)&sA[fr * 40 + ksub * 8];
        #pragma unroll
        for (int ni = 0; ni < 4; ++ni) {
            bf16x8 bf = *(bf16x8*)&sW[(w * 64 + ni * 16 + fr) * 40 + ksub * 8];
            acc[ni] = __builtin_amdgcn_mfma_f32_16x16x32_bf16(af, bf, acc[ni], 0, 0, 0);
        }
    }

    // epilogue: v = acc + bias + residual
    float vres[4][4];
    #pragma unroll
    for (int ni = 0; ni < 4; ++ni) {
        int col = w * 64 + ni * 16 + fr;
        float bv = bias[col];
        #pragma unroll
        for (int r = 0; r < 4; ++r) {
            int row = m0 + ksub * 4 + r;
            vres[ni][r] = acc[ni][r] + bv + xres[(long)row * DMODEL + col];
        }
    }

    // per-row partial sums over this wave's 64 cols, reduce across fr lanes
    #pragma unroll
    for (int r = 0; r < 4; ++r) {
        float s = 0.f, q = 0.f;
        #pragma unroll
        for (int ni = 0; ni < 4; ++ni) {
            s += vres[ni][r];
            q += vres[ni][r] * vres[ni][r];
        }
        #pragma unroll
        for (int mask = 1; mask < 16; mask <<= 1) {
            s += __shfl_xor(s, mask);
            q += __shfl_xor(q, mask);
        }
        if (fr == 0) {
            redS[w][ksub * 4 + r] = s;
            redQ[w][ksub * 4 + r] = q;
        }
    }
    __syncthreads();

    #pragma unroll
    for (int r = 0; r < 4; ++r) {
        int rl = ksub * 4 + r;
        float sum  = redS[0][rl] + redS[1][rl] + redS[2][rl] + redS[3][rl];
        float sumq = redQ[0][rl] + redQ[1][rl] + redQ[2][rl] + redQ[3][rl];
        float mean = sum * (1.f / 256.f);
        float var  = sumq * (1.f / 256.f) - mean * mean;
        float rstd = rsqrtf(var + 1e-5f);
        int row = m0 + rl;
        #pragma unroll
        for (int ni = 0; ni < 4; ++ni) {
            int col = w * 64 + ni * 16 + fr;
            xout[(long)row * DMODEL + col] =
                (vres[ni][r] - mean) * rstd * g[col] + beta[col];
        }
    }
}

// ---------------------------------------------------------------------------
// Gather path: dedupe -> sum bf16 rows of fc1T -> relu -> fc2
// ---------------------------------------------------------------------------
__global__ __launch_bounds__(256) void embed_gather(
    const int* __restrict__ word_idx,
    const int* __restrict__ ngram_idx,
    const unsigned short* __restrict__ fc1_wT,
    const float* __restrict__ fc1_b,
    const float* __restrict__ fc2_w,
    const float* __restrict__ fc2_b,
    float* __restrict__ x)
{
    __shared__ int   feats[8][8];
    __shared__ int   nf[8];
    __shared__ float x1[8][FFDIM];

    const int t0  = blockIdx.x * 8;
    const int tid = threadIdx.x;

    if (tid < 8) {
        int t = t0 + tid;
        int cnt = 0;
        feats[tid][cnt++] = word_idx[t];
        for (int k = 0; k < 6; ++k) {
            int f = WORDC + ngram_idx[t * 6 + k];
            bool dup = false;
            for (int s = 1; s < cnt; ++s)
                if (feats[tid][s] == f) dup = true;
            if (!dup) feats[tid][cnt++] = f;
        }
        nf[tid] = cnt;
    }
    __syncthreads();

    const float2 bb = *(const float2*)&fc1_b[tid * 2];
    #pragma unroll
    for (int tt = 0; tt < 8; ++tt) {
        float a0 = bb.x, a1 = bb.y;
        int n = nf[tt];
        for (int s = 0; s < n; ++s) {
            unsigned int wrd = *(const unsigned int*)
                &fc1_wT[(long)feats[tt][s] * FFDIM + tid * 2];
            a0 += __uint_as_float((wrd & 0xFFFFu) << 16);
            a1 += __uint_as_float(wrd & 0xFFFF0000u);
        }
        x1[tt][tid * 2 + 0] = fmaxf(a0, 0.f);
        x1[tt][tid * 2 + 1] = fmaxf(a1, 0.f);
    }
    __syncthreads();

    const int d = tid;
    float acc[8];
    float cb = fc2_b[d];
    #pragma unroll
    for (int tt = 0; tt < 8; ++tt) acc[tt] = cb;
    const float* wrow = fc2_w + d * FFDIM;
    for (int k = 0; k < FFDIM; ++k) {
        float wv = wrow[k];
        #pragma unroll
        for (int tt = 0; tt < 8; ++tt) acc[tt] += wv * x1[tt][k];
    }
    #pragma unroll
    for (int tt = 0; tt < 8; ++tt)
        x[(t0 + tt) * DMODEL + d] = acc[tt];
}

// ---------------------------------------------------------------------------
// Fallback fused sparse embed (scattered-column path, fp32)
// ---------------------------------------------------------------------------
__global__ __launch_bounds__(256) void embed_kernel(
    const int* __restrict__ word_idx,
    const int* __restrict__ ngram_idx,
    const float* __restrict__ fc1_w,
    const float* __restrict__ fc1_b,
    const float* __restrict__ fc2_w,
    const float* __restrict__ fc2_b,
    float* __restrict__ x)
{
    __shared__ int   feats[8][8];
    __shared__ int   nf[8];
    __shared__ float x1[8][FFDIM];

    const int t0  = blockIdx.x * 8;
    const int tid = threadIdx.x;

    if (tid < 8) {
        int t = t0 + tid;
        int cnt = 0;
        feats[tid][cnt++] = word_idx[t];
        for (int k = 0; k < 6; ++k) {
            int f = WORDC + ngram_idx[t * 6 + k];
            bool dup = false;
            for (int s = 1; s < cnt; ++s)
                if (feats[tid][s] == f) dup = true;
            if (!dup) feats[tid][cnt++] = f;
        }
        nf[tid] = cnt;
    }
    __syncthreads();

    for (int it = 0; it < 16; ++it) {
        int item = it * 256 + tid;
        int tt = item >> 9;
        int j  = item & 511;
        float acc = fc1_b[j];
        int n = nf[tt];
        const float* rowbase = fc1_w + (long)j * F_TOT;
        for (int s = 0; s < n; ++s)
            acc += rowbase[feats[tt][s]];
        x1[tt][j] = fmaxf(acc, 0.f);
    }
    __syncthreads();

    const int d = tid;
    float acc[8];
    float bb = fc2_b[d];
    #pragma unroll
    for (int tt = 0; tt < 8; ++tt) acc[tt] = bb;
    const float* wrow = fc2_w + d * FFDIM;
    for (int k = 0; k < FFDIM; ++k) {
        float wv = wrow[k];
        #pragma unroll
        for (int tt = 0; tt < 8; ++tt) acc[tt] += wv * x1[tt][k];
    }
    #pragma unroll
    for (int tt = 0; tt < 8; ++tt)
        x[(t0 + tt) * DMODEL + d] = acc[tt];
}

// ---------------------------------------------------------------------------
// fp32 tiled GEMM (fallback path only)
// ---------------------------------------------------------------------------
template<bool RELU>
__global__ __launch_bounds__(256) void gemm_bias(
    const float* __restrict__ A,
    const float* __restrict__ W,
    const float* __restrict__ bias,
    float* __restrict__ C,
    int M, int N, int K)
{
    __shared__ float sA[16][64];
    __shared__ float sW[16][64];

    const int tid = threadIdx.x;
    const int tx = tid & 15;
    const int ty = tid >> 4;
    const int m0 = blockIdx.y * 64;
    const int n0 = blockIdx.x * 64;

    const int lr = tid >> 2;
    const int lc = tid & 3;

    float acc[4][4] = {};

    for (int k0 = 0; k0 < K; k0 += 16) {
        float4 av = *(const float4*)&A[(long)(m0 + lr) * K + k0 + lc * 4];
        float4 wv = *(const float4*)&W[(long)(n0 + lr) * K + k0 + lc * 4];
        __syncthreads();
        sA[lc * 4 + 0][lr] = av.x; sA[lc * 4 + 1][lr] = av.y;
        sA[lc * 4 + 2][lr] = av.z; sA[lc * 4 + 3][lr] = av.w;
        sW[lc * 4 + 0][lr] = wv.x; sW[lc * 4 + 1][lr] = wv.y;
        sW[lc * 4 + 2][lr] = wv.z; sW[lc * 4 + 3][lr] = wv.w;
        __syncthreads();
        #pragma unroll
        for (int k = 0; k < 16; ++k) {
            float4 a4 = *(const float4*)&sA[k][ty * 4];
            float4 b4 = *(const float4*)&sW[k][tx * 4];
            float am[4] = {a4.x, a4.y, a4.z, a4.w};
            float bn[4] = {b4.x, b4.y, b4.z, b4.w};
            #pragma unroll
            for (int i = 0; i < 4; ++i)
                #pragma unroll
                for (int j = 0; j < 4; ++j)
                    acc[i][j] += am[i] * bn[j];
        }
    }

    float4 bv = *(const float4*)&bias[n0 + tx * 4];
    #pragma unroll
    for (int i = 0; i < 4; ++i) {
        int m = m0 + ty * 4 + i;
        float4 o;
        o.x = acc[i][0] + bv.x;
        o.y = acc[i][1] + bv.y;
        o.z = acc[i][2] + bv.z;
        o.w = acc[i][3] + bv.w;
        if (RELU) {
            o.x = fmaxf(o.x, 0.f); o.y = fmaxf(o.y, 0.f);
            o.z = fmaxf(o.z, 0.f); o.w = fmaxf(o.w, 0.f);
        }
        *(float4*)&C[(long)m * N + n0 + tx * 4] = o;
    }
}

// ---------------------------------------------------------------------------
// Attention: one block per (b,h), 256 threads: thread = (query q, quarter p)
// ---------------------------------------------------------------------------
__global__ __launch_bounds__(256) void attn_kernel(
    const float* __restrict__ qkv,
    float* __restrict__ o)
{
    const int b = blockIdx.x >> 3;
    const int h = blockIdx.x & 7;
    const int tid = threadIdx.x;
    const int q = tid >> 2;
    const int p = tid & 3;

    __shared__ float Kt[SEQL][HDIM + 1];
    __shared__ float Vt[SEQL][HDIM + 1];
    __shared__ float S[SEQL][SEQL + 1];

    const float scale = 0.17677669529663687f;

    // load K,V: thread loads 8 consecutive floats of one row per matrix
    {
        int fidx = tid * 2;               // even float4 index
        int row  = fidx >> 3;
        int c    = (fidx & 7) * 4;        // 0,8,16,24
        const float* kb = qkv + (long)(b * SEQL + row) * 768 + 256 + h * HDIM + c;
        float4 k0 = *(const float4*)kb;
        float4 k1 = *(const float4*)(kb + 4);
        float4 v0 = *(const float4*)(kb + 256);
        float4 v1 = *(const float4*)(kb + 260);
        *(float4*)&Kt[row][c]     = k0;
        *(float4*)&Kt[row][c + 4] = k1;
        *(float4*)&Vt[row][c]     = v0;
        *(float4*)&Vt[row][c + 4] = v1;
    }

    // full Q row in regs (scaled)
    float qreg[HDIM];
    {
        const float* qb = qkv + (long)(b * SEQL + q) * 768 + h * HDIM;
        #pragma unroll
        for (int c = 0; c < HDIM / 4; ++c) {
            float4 v = *(const float4*)(qb + c * 4);
            qreg[c * 4 + 0] = v.x * scale;
            qreg[c * 4 + 1] = v.y * scale;
            qreg[c * 4 + 2] = v.z * scale;
            qreg[c * 4 + 3] = v.w * scale;
        }
    }
    __syncthreads();

    // scores for 16 keys: jj = p*16 + i
    float sc[16];
    float mx = -1e30f;
    #pragma unroll
    for (int i = 0; i < 16; ++i) {
        int jj = p * 16 + i;
        float s = 0.f;
        #pragma unroll
        for (int d = 0; d < HDIM; ++d) s += qreg[d] * Kt[jj][d];
        sc[i] = s;
        mx = fmaxf(mx, s);
    }
    mx = fmaxf(mx, __shfl_xor(mx, 1));
    mx = fmaxf(mx, __shfl_xor(mx, 2));

    float sum = 0.f;
    #pragma unroll
    for (int i = 0; i < 16; ++i) {
        float e = __expf(sc[i] - mx);
        S[q][p * 16 + i] = e;
        sum += e;
    }
    sum += __shfl_xor(sum, 1);
    sum += __shfl_xor(sum, 2);
    const float inv = 1.f / sum;
    __syncthreads();

    // PV: thread accumulates dims [p*8, p*8+8)
    float acc[8] = {};
    for (int jj = 0; jj < SEQL; ++jj) {
        float pv = S[q][jj];
        #pragma unroll
        for (int d = 0; d < 8; ++d) acc[d] += pv * Vt[jj][p * 8 + d];
    }
    float* orow = o + (long)(b * SEQL + q) * DMODEL + h * HDIM + p * 8;
    float4 o0, o1;
    o0.x = acc[0] * inv; o0.y = acc[1] * inv; o0.z = acc[2] * inv; o0.w = acc[3] * inv;
    o1.x = acc[4] * inv; o1.y = acc[5] * inv; o1.z = acc[6] * inv; o1.w = acc[7] * inv;
    *(float4*)orow = o0;
    *(float4*)(orow + 4) = o1;
}

// ---------------------------------------------------------------------------
// x = LayerNorm(xin + f) * g + b  (fallback path only)
// ---------------------------------------------------------------------------
__global__ __launch_bounds__(256) void add_ln_kernel(
    const float* __restrict__ xin,
    const float* __restrict__ f,
    const float* __restrict__ g,
    const float* __restrict__ bta,
    float* __restrict__ xout)
{
    const int w = threadIdx.x >> 6;
    const int lane = threadIdx.x & 63;
    const int t = blockIdx.x * 4 + w;

    float4 xv = *(const float4*)&xin[(long)t * DMODEL + lane * 4];
    float4 fv = *(const float4*)&f[(long)t * DMODEL + lane * 4];
    float v0 = xv.x + fv.x, v1 = xv.y + fv.y, v2 = xv.z + fv.z, v3 = xv.w + fv.w;

    float s  = v0 + v1 + v2 + v3;
    float sq = v0 * v0 + v1 * v1 + v2 * v2 + v3 * v3;
    #pragma unroll
    for (int off = 1; off < 64; off <<= 1) {
        s  += __shfl_xor(s, off);
        sq += __shfl_xor(sq, off);
    }
    float mean = s * (1.f / 256.f);
    float var  = sq * (1.f / 256.f) - mean * mean;
    float rs   = rsqrtf(var + 1e-5f);

    float4 gv = *(const float4*)&g[lane * 4];
    float4 bv = *(const float4*)&bta[lane * 4];
    float4 o;
    o.x = (v0 - mean) * rs * gv.x + bv.x;
    o.y = (v1 - mean) * rs * gv.y + bv.y;
    o.z = (v2 - mean) * rs * gv.z + bv.z;
    o.w = (v3 - mean) * rs * gv.w + bv.w;
    *(float4*)&xout[(long)t * DMODEL + lane * 4] = o;
}

// ---------------------------------------------------------------------------
extern "C" void kernel_launch(void* const* d_in, const int* in_sizes, int n_in,
                              void* d_out, int out_size, void* d_ws, size_t ws_size,
                              hipStream_t stream) {
    const int*   word_idx  = (const int*)d_in[0];
    const int*   ngram_idx = (const int*)d_in[1];
    const float* fc1_w = (const float*)d_in[2];
    const float* fc1_b = (const float*)d_in[3];
    const float* fc2_w = (const float*)d_in[4];
    const float* fc2_b = (const float*)d_in[5];
    const float* qkv_w = (const float*)d_in[6];
    const float* qkv_b = (const float*)d_in[7];
    const float* out_w = (const float*)d_in[8];
    const float* out_b = (const float*)d_in[9];
    const float* ln1_g = (const float*)d_in[10];
    const float* ln1_b = (const float*)d_in[11];
    const float* ff1_w = (const float*)d_in[12];
    const float* ff1_b = (const float*)d_in[13];
    const float* ff2_w = (const float*)d_in[14];
    const float* ff2_b = (const float*)d_in[15];
    const float* ln2_g = (const float*)d_in[16];
    const float* ln2_b = (const float*)d_in[17];

    float* x = (float*)d_out;  // [2048][256]

    const size_t FC1T_ELEMS = (size_t)F_TOT * FFDIM;
    const size_t WQKV_ELEMS = 2 * 768 * 256;
    const size_t WOUT_ELEMS = 2 * 256 * 256;
    const size_t WFF1_ELEMS = 2 * 1024 * 256;
    const size_t WFF2_ELEMS = 2 * 256 * 1024;
    const size_t BF16_BYTES = (FC1T_ELEMS + WQKV_ELEMS + WOUT_ELEMS +
                               WFF1_ELEMS + WFF2_ELEMS) * 2;
    const size_t FLOAT_BYTES = (size_t)2048 * 2304 * 4;
    const bool fast = ws_size >= BF16_BYTES + FLOAT_BYTES;

    if (fast) {
        unsigned short* fc1T  = (unsigned short*)d_ws;
        unsigned short* qkvT  = fc1T + FC1T_ELEMS;
        unsigned short* outT  = qkvT + WQKV_ELEMS;
        unsigned short* ff1T  = outT + WOUT_ELEMS;
        unsigned short* ff2T  = ff1T + WFF1_ELEMS;
        float* wsf      = (float*)((char*)d_ws + BF16_BYTES);
        float* qkvbuf   = wsf;                                  // 2048*768 f32
        float* attn_raw = qkvbuf + 2048 * 768;                  // 2048*256 f32
        unsigned short* ffbuf = (unsigned short*)(attn_raw + 2048 * 256); // 2048*1024 bf16

        transpose_fc1<<<dim3(F_TOT / 64, 8), 256, 0, stream>>>(fc1_w, fc1T);
        cvt_weights<<<dim3(192, 4), 256, 0, stream>>>(
            qkv_w, out_w, ff1_w, ff2_w, qkvT, outT, ff1T, ff2T);
        embed_gather<<<NTOK / 8, 256, 0, stream>>>(word_idx, ngram_idx, fc1T,
                                                   fc1_b, fc2_w, fc2_b, x);

        for (int i = 0; i < 2; ++i) {
            gemm_mfma<false, false><<<dim3(768 / 64, NTOK / 64), 256, 0, stream>>>(
                x, qkvT + (long)i * 768 * 256, qkv_b + i * 768, qkvbuf,
                NTOK, 768, 256);

            attn_kernel<<<32 * NHEAD, 256, 0, stream>>>(qkvbuf, attn_raw);

            gemm_ln<256, false><<<NTOK / 16, 256, 0, stream>>>(
                attn_raw, outT + (long)i * 256 * 256, out_b + i * 256,
                x, ln1_g + i * 256, ln1_b + i * 256, x);

            gemm_mfma<true, true><<<dim3(1024 / 64, NTOK / 64), 256, 0, stream>>>(
                x, ff1T + (long)i * 1024 * 256, ff1_b + i * 1024, ffbuf,
                NTOK, 1024, 256);

            gemm_ln<1024, true><<<NTOK / 16, 256, 0, stream>>>(
                ffbuf, ff2T + (long)i * 256 * 1024, ff2_b + i * 256,
                x, ln2_g + i * 256, ln2_b + i * 256, x);
        }
    } else {
        float* wsf      = (float*)d_ws;
        float* qkvbuf   = wsf;
        float* attn_raw = qkvbuf + 2048 * 768;
        float* obuf     = attn_raw + 2048 * 256;
        float* ffbuf    = obuf + 2048 * 256;

        embed_kernel<<<NTOK / 8, 256, 0, stream>>>(word_idx, ngram_idx, fc1_w,
                                                   fc1_b, fc2_w, fc2_b, x);
        for (int i = 0; i < 2; ++i) {
            gemm_bias<false><<<dim3(768 / 64, NTOK / 64), 256, 0, stream>>>(
                x, qkv_w + (long)i * 768 * 256, qkv_b + i * 768, qkvbuf,
                NTOK, 768, 256);
            attn_kernel<<<32 * NHEAD, 256, 0, stream>>>(qkvbuf, attn_raw);
            gemm_bias<false><<<dim3(256 / 64, NTOK / 64), 256, 0, stream>>>(
                attn_raw, out_w + (long)i * 256 * 256, out_b + i * 256, obuf,
                NTOK, 256, 256);
            add_ln_kernel<<<NTOK / 4, 256, 0, stream>>>(x, obuf, ln1_g + i * 256,
                                                        ln1_b + i * 256, x);
            gemm_bias<true><<<dim3(1024 / 64, NTOK / 64), 256, 0, stream>>>(
                x, ff1_w + (long)i * 1024 * 256, ff1_b + i * 1024, ffbuf,
                NTOK, 1024, 256);
            gemm_bias<false><<<dim3(256 / 64, NTOK / 64), 256, 0, stream>>>(
                ffbuf, ff2_w + (long)i * 256 * 1024, ff2_b + i * 256, obuf,
                NTOK, 256, 1024);
            add_ln_kernel<<<NTOK / 4, 256, 0, stream>>>(x, obuf, ln2_g + i * 256,
                                                        ln2_b + i * 256, x);
        }
    }
}

// Round 5
// 198.896 us; speedup vs baseline: 2.0858x; 1.0907x over previous
//
#include <hip/hip_runtime.h>
#include <hip/hip_bf16.h>
#include <math.h>

#define WORDC 30000
#define F_TOT 80000
#define NTOK  2048
#define DMODEL 256
#define FFDIM 512
#define NHEAD 8
#define HDIM  32
#define SEQL  64

typedef __attribute__((ext_vector_type(8))) short bf16x8;
typedef __attribute__((ext_vector_type(8))) unsigned short u16x8;
typedef __attribute__((ext_vector_type(4))) float f32x4;

__device__ __forceinline__ unsigned short f32_to_bf16_rne(float x) {
    unsigned int u = __float_as_uint(x);
    unsigned int r = (u + 0x7FFFu + ((u >> 16) & 1u)) >> 16;
    return (unsigned short)r;
}

// ---------------------------------------------------------------------------
// Build bitmap of used features (word + ngram), one block.
// ---------------------------------------------------------------------------
__global__ __launch_bounds__(256) void mark_feats(
    const int* __restrict__ word_idx,
    const int* __restrict__ ngram_idx,
    unsigned int* __restrict__ bm)          // 2500 u32
{
    __shared__ unsigned int lbm[2500];
    const int tid = threadIdx.x;
    for (int i = tid; i < 2500; i += 256) lbm[i] = 0u;
    __syncthreads();
    for (int j = tid; j < NTOK; j += 256) {
        int f = word_idx[j];
        atomicOr(&lbm[f >> 5], 1u << (f & 31));
    }
    for (int j = tid; j < NTOK * 6; j += 256) {
        int f = WORDC + ngram_idx[j];
        atomicOr(&lbm[f >> 5], 1u << (f & 31));
    }
    __syncthreads();
    for (int i = tid; i < 2500; i += 256) bm[i] = lbm[i];
}

// ---------------------------------------------------------------------------
// Combined: transpose fc1_w [512][80000] -> fc1T [80000][512] bf16
// (skipping stores of unused feature rows) + cvt of transformer weights.
// 1-D grid: blocks [0,10000) transpose, [10000,10192) cvt.
// ---------------------------------------------------------------------------
__global__ __launch_bounds__(256) void transpose_cvt(
    const float* __restrict__ fc1_w,
    unsigned short* __restrict__ fc1T,
    const unsigned int* __restrict__ bm,
    const float* __restrict__ s0, const float* __restrict__ s1,
    const float* __restrict__ s2, const float* __restrict__ s3,
    unsigned short* __restrict__ d0, unsigned short* __restrict__ d1,
    unsigned short* __restrict__ d2, unsigned short* __restrict__ d3)
{
    __shared__ float tile[64][65];
    const int bid = blockIdx.x;
    const int tid = threadIdx.x;

    if (bid < 10000) {
        const int f0 = (bid % 1250) * 64;
        const int j0 = (bid / 1250) * 64;

        const int fr = (tid & 15) * 4;
        const int jr = tid >> 4;
        #pragma unroll
        for (int p = 0; p < 4; ++p) {
            int j = j0 + p * 16 + jr;
            float4 v = *(const float4*)&fc1_w[(long)j * F_TOT + f0 + fr];
            tile[fr + 0][p * 16 + jr] = v.x;
            tile[fr + 1][p * 16 + jr] = v.y;
            tile[fr + 2][p * 16 + jr] = v.z;
            tile[fr + 3][p * 16 + jr] = v.w;
        }
        __syncthreads();

        const int jc  = (tid & 15) * 4;
        const int fr2 = tid >> 4;
        #pragma unroll
        for (int p = 0; p < 4; ++p) {
            int fi = p * 16 + fr2;
            int f  = f0 + fi;
            if ((bm[f >> 5] >> (f & 31)) & 1u) {
                ushort4 o;
                o.x = f32_to_bf16_rne(tile[fi][jc + 0]);
                o.y = f32_to_bf16_rne(tile[fi][jc + 1]);
                o.z = f32_to_bf16_rne(tile[fi][jc + 2]);
                o.w = f32_to_bf16_rne(tile[fi][jc + 3]);
                *(ushort4*)&fc1T[(long)f * FFDIM + j0 + jc] = o;
            }
        }
    } else {
        int s = bid - 10000;
        int ten = s / 48, b48 = s % 48;
        const float* src; unsigned short* dst; int n4;
        switch (ten) {
            case 0:  src = s0; dst = d0; n4 = 2 * 768 * 256 / 4;  break;
            case 1:  src = s1; dst = d1; n4 = 2 * 256 * 256 / 4;  break;
            case 2:  src = s2; dst = d2; n4 = 2 * 1024 * 256 / 4; break;
            default: src = s3; dst = d3; n4 = 2 * 256 * 1024 / 4; break;
        }
        for (int i = b48 * 256 + tid; i < n4; i += 48 * 256) {
            float4 v = ((const float4*)src)[i];
            ushort4 o;
            o.x = f32_to_bf16_rne(v.x);
            o.y = f32_to_bf16_rne(v.y);
            o.z = f32_to_bf16_rne(v.z);
            o.w = f32_to_bf16_rne(v.w);
            ((ushort4*)dst)[i] = o;
        }
    }
}

// ---------------------------------------------------------------------------
// Gather path: dedupe -> sum bf16 rows of fc1T -> relu -> fc2
// ---------------------------------------------------------------------------
__global__ __launch_bounds__(256) void embed_gather(
    const int* __restrict__ word_idx,
    const int* __restrict__ ngram_idx,
    const unsigned short* __restrict__ fc1_wT,
    const float* __restrict__ fc1_b,
    const float* __restrict__ fc2_w,
    const float* __restrict__ fc2_b,
    float* __restrict__ x)
{
    __shared__ int   feats[8][8];
    __shared__ int   nf[8];
    __shared__ float x1[8][FFDIM];

    const int t0  = blockIdx.x * 8;
    const int tid = threadIdx.x;

    if (tid < 8) {
        int t = t0 + tid;
        int cnt = 0;
        feats[tid][cnt++] = word_idx[t];
        for (int k = 0; k < 6; ++k) {
            int f = WORDC + ngram_idx[t * 6 + k];
            bool dup = false;
            for (int s = 1; s < cnt; ++s)
                if (feats[tid][s] == f) dup = true;
            if (!dup) feats[tid][cnt++] = f;
        }
        nf[tid] = cnt;
    }
    __syncthreads();

    const float2 bb = *(const float2*)&fc1_b[tid * 2];
    #pragma unroll
    for (int tt = 0; tt < 8; ++tt) {
        float a0 = bb.x, a1 = bb.y;
        int n = nf[tt];
        for (int s = 0; s < n; ++s) {
            unsigned int wrd = *(const unsigned int*)
                &fc1_wT[(long)feats[tt][s] * FFDIM + tid * 2];
            a0 += __uint_as_float((wrd & 0xFFFFu) << 16);
            a1 += __uint_as_float(wrd & 0xFFFF0000u);
        }
        x1[tt][tid * 2 + 0] = fmaxf(a0, 0.f);
        x1[tt][tid * 2 + 1] = fmaxf(a1, 0.f);
    }
    __syncthreads();

    const int d = tid;
    float acc[8];
    float cb = fc2_b[d];
    #pragma unroll
    for (int tt = 0; tt < 8; ++tt) acc[tt] = cb;
    const float* wrow = fc2_w + d * FFDIM;
    for (int k = 0; k < FFDIM; ++k) {
        float wv = wrow[k];
        #pragma unroll
        for (int tt = 0; tt < 8; ++tt) acc[tt] += wv * x1[tt][k];
    }
    #pragma unroll
    for (int tt = 0; tt < 8; ++tt)
        x[(t0 + tt) * DMODEL + d] = acc[tt];
}

// ---------------------------------------------------------------------------
// Fused per-(b,h) QKV GEMM (MFMA, N=96 head slice) + attention.
// grid 256 = (b,h); 256 threads = 4 waves; wave owns 16 rows x 96 cols.
// ---------------------------------------------------------------------------
__global__ __launch_bounds__(256) void fused_qkv_attn(
    const float* __restrict__ x,            // [2048][256]
    const unsigned short* __restrict__ Wq,  // layer qkvT [768][256]
    const float* __restrict__ bq,           // layer qkv_b [768]
    float* __restrict__ o)                  // attn_raw [2048][256]
{
    __shared__ unsigned short sA[64 * 40];
    __shared__ unsigned short sW[96 * 40];
    __shared__ float Qs[SEQL][HDIM + 1];
    __shared__ float Ks[SEQL][HDIM + 1];
    __shared__ float Vs[SEQL][HDIM + 1];
    __shared__ float S[SEQL][SEQL + 1];

    const int b = blockIdx.x >> 3;
    const int h = blockIdx.x & 7;
    const int tid  = threadIdx.x;
    const int lane = tid & 63;
    const int w    = tid >> 6;
    const int fr   = lane & 15;
    const int ksub = lane >> 4;
    const int row0 = b * SEQL;

    const int srow = tid >> 2;
    const int ssub = tid & 3;

    f32x4 acc[6] = {};

    const int r1 = tid >> 2, c1 = tid & 3;
    const int wrow1 = ((r1 >> 5) << 8) + h * HDIM + (r1 & 31);

    for (int k0 = 0; k0 < DMODEL; k0 += 32) {
        const float* ap = &x[(long)(row0 + srow) * DMODEL + k0 + ssub * 8];
        float4 a0 = *(const float4*)ap;
        float4 a1 = *(const float4*)(ap + 4);
        u16x8 wv1 = *(const u16x8*)&Wq[(long)wrow1 * DMODEL + k0 + c1 * 8];
        u16x8 wv2;
        int r2 = 0, c2 = 0;
        if (tid < 128) {
            int s2 = 256 + tid;
            r2 = s2 >> 2; c2 = s2 & 3;
            int wrow2 = ((r2 >> 5) << 8) + h * HDIM + (r2 & 31);
            wv2 = *(const u16x8*)&Wq[(long)wrow2 * DMODEL + k0 + c2 * 8];
        }
        __syncthreads();
        u16x8 av;
        av[0] = f32_to_bf16_rne(a0.x); av[1] = f32_to_bf16_rne(a0.y);
        av[2] = f32_to_bf16_rne(a0.z); av[3] = f32_to_bf16_rne(a0.w);
        av[4] = f32_to_bf16_rne(a1.x); av[5] = f32_to_bf16_rne(a1.y);
        av[6] = f32_to_bf16_rne(a1.z); av[7] = f32_to_bf16_rne(a1.w);
        *(u16x8*)&sA[srow * 40 + ssub * 8] = av;
        *(u16x8*)&sW[r1 * 40 + c1 * 8] = wv1;
        if (tid < 128) *(u16x8*)&sW[r2 * 40 + c2 * 8] = wv2;
        __syncthreads();

        bf16x8 af = *(bf16x8*)&sA[(w * 16 + fr) * 40 + ksub * 8];
        #pragma unroll
        for (int ni = 0; ni < 6; ++ni) {
            bf16x8 bf = *(bf16x8*)&sW[(ni * 16 + fr) * 40 + ksub * 8];
            acc[ni] = __builtin_amdgcn_mfma_f32_16x16x32_bf16(af, bf, acc[ni], 0, 0, 0);
        }
    }

    const float scale = 0.17677669529663687f;   // 1/sqrt(32)
    #pragma unroll
    for (int ni = 0; ni < 6; ++ni) {
        const int part = ni >> 1;               // 0=Q 1=K 2=V
        const int pc   = ((ni & 1) << 4) + fr;  // col within 32
        float bv = bq[(part << 8) + h * HDIM + pc];
        #pragma unroll
        for (int r = 0; r < 4; ++r) {
            int row = w * 16 + ksub * 4 + r;
            float v = acc[ni][r] + bv;
            if (part == 0)      Qs[row][pc] = v * scale;
            else if (part == 1) Ks[row][pc] = v;
            else                Vs[row][pc] = v;
        }
    }
    __syncthreads();

    // attention: thread = (query q, quarter p)
    const int q = tid >> 2;
    const int p = tid & 3;

    float qreg[HDIM];
    #pragma unroll
    for (int d = 0; d < HDIM; ++d) qreg[d] = Qs[q][d];

    float sc[16];
    float mx = -1e30f;
    #pragma unroll
    for (int i = 0; i < 16; ++i) {
        int jj = p * 16 + i;
        float s = 0.f;
        #pragma unroll
        for (int d = 0; d < HDIM; ++d) s += qreg[d] * Ks[jj][d];
        sc[i] = s;
        mx = fmaxf(mx, s);
    }
    mx = fmaxf(mx, __shfl_xor(mx, 1));
    mx = fmaxf(mx, __shfl_xor(mx, 2));

    float sum = 0.f;
    #pragma unroll
    for (int i = 0; i < 16; ++i) {
        float e = __expf(sc[i] - mx);
        S[q][p * 16 + i] = e;
        sum += e;
    }
    sum += __shfl_xor(sum, 1);
    sum += __shfl_xor(sum, 2);
    const float inv = 1.f / sum;
    __syncthreads();

    float pacc[8] = {};
    for (int jj = 0; jj < SEQL; ++jj) {
        float pv = S[q][jj];
        #pragma unroll
        for (int d = 0; d < 8; ++d) pacc[d] += pv * Vs[jj][p * 8 + d];
    }
    float* orow = o + (long)(row0 + q) * DMODEL + h * HDIM + p * 8;
    float4 o0, o1;
    o0.x = pacc[0] * inv; o0.y = pacc[1] * inv;
    o0.z = pacc[2] * inv; o0.w = pacc[3] * inv;
    o1.x = pacc[4] * inv; o1.y = pacc[5] * inv;
    o1.z = pacc[6] * inv; o1.w = pacc[7] * inv;
    *(float4*)orow = o0;
    *(float4*)(orow + 4) = o1;
}

// ---------------------------------------------------------------------------
// Fused GEMM + residual + LayerNorm (out-projection):
//   xout = LN(xres + A@W^T + bias) * g + beta ; K=256, A fp32
// BM=16, BN=256 full width, 4 waves (1x4).
// ---------------------------------------------------------------------------
__global__ __launch_bounds__(256) void gemm_ln(
    const float* __restrict__ A,
    const unsigned short* __restrict__ Wb,
    const float* __restrict__ bias,
    const float* __restrict__ xres,
    const float* __restrict__ g,
    const float* __restrict__ beta,
    float* __restrict__ xout)
{
    __shared__ unsigned short sA[16 * 40];
    __shared__ unsigned short sW[256 * 40];
    __shared__ float redS[4][16];
    __shared__ float redQ[4][16];

    const int tid  = threadIdx.x;
    const int lane = tid & 63;
    const int w    = tid >> 6;
    const int fr   = lane & 15;
    const int ksub = lane >> 4;
    const int m0   = blockIdx.x * 16;

    f32x4 acc[4] = {};

    for (int k0 = 0; k0 < DMODEL; k0 += 32) {
        float4 a4;
        if (tid < 128) {
            int row = tid >> 3, c4 = tid & 7;
            a4 = *(const float4*)&A[(long)(m0 + row) * DMODEL + k0 + c4 * 4];
        }
        u16x8 wv[4];
        #pragma unroll
        for (int c = 0; c < 4; ++c)
            wv[c] = *(const u16x8*)&Wb[(long)tid * DMODEL + k0 + c * 8];

        __syncthreads();

        if (tid < 128) {
            int row = tid >> 3, c4 = tid & 7;
            ushort4 ov;
            ov.x = f32_to_bf16_rne(a4.x);
            ov.y = f32_to_bf16_rne(a4.y);
            ov.z = f32_to_bf16_rne(a4.z);
            ov.w = f32_to_bf16_rne(a4.w);
            *(ushort4*)&sA[row * 40 + c4 * 4] = ov;
        }
        #pragma unroll
        for (int c = 0; c < 4; ++c)
            *(u16x8*)&sW[tid * 40 + c * 8] = wv[c];

        __syncthreads();

        bf16x8 af = *(bf16x8*)&sA[fr * 40 + ksub * 8];
        #pragma unroll
        for (int ni = 0; ni < 4; ++ni) {
            bf16x8 bf = *(bf16x8*)&sW[(w * 64 + ni * 16 + fr) * 40 + ksub * 8];
            acc[ni] = __builtin_amdgcn_mfma_f32_16x16x32_bf16(af, bf, acc[ni], 0, 0, 0);
        }
    }

    float vres[4][4];
    #pragma unroll
    for (int ni = 0; ni < 4; ++ni) {
        int col = w * 64 + ni * 16 + fr;
        float bv = bias[col];
        #pragma unroll
        for (int r = 0; r < 4; ++r) {
            int row = m0 + ksub * 4 + r;
            vres[ni][r] = acc[ni][r] + bv + xres[(long)row * DMODEL + col];
        }
    }

    #pragma unroll
    for (int r = 0; r < 4; ++r) {
        float s = 0.f, qq = 0.f;
        #pragma unroll
        for (int ni = 0; ni < 4; ++ni) {
            s  += vres[ni][r];
            qq += vres[ni][r] * vres[ni][r];
        }
        #pragma unroll
        for (int mask = 1; mask < 16; mask <<= 1) {
            s  += __shfl_xor(s, mask);
            qq += __shfl_xor(qq, mask);
        }
        if (fr == 0) {
            redS[w][ksub * 4 + r] = s;
            redQ[w][ksub * 4 + r] = qq;
        }
    }
    __syncthreads();

    #pragma unroll
    for (int r = 0; r < 4; ++r) {
        int rl = ksub * 4 + r;
        float sum  = redS[0][rl] + redS[1][rl] + redS[2][rl] + redS[3][rl];
        float sumq = redQ[0][rl] + redQ[1][rl] + redQ[2][rl] + redQ[3][rl];
        float mean = sum * (1.f / 256.f);
        float var  = sumq * (1.f / 256.f) - mean * mean;
        float rstd = rsqrtf(var + 1e-5f);
        int row = m0 + rl;
        #pragma unroll
        for (int ni = 0; ni < 4; ++ni) {
            int col = w * 64 + ni * 16 + fr;
            xout[(long)row * DMODEL + col] =
                (vres[ni][r] - mean) * rstd * g[col] + beta[col];
        }
    }
}

// ---------------------------------------------------------------------------
// Fused FFN: x = LN(x + relu(x@W1^T+b1)@W2^T + b2) * g + beta
// BM=16 tokens, x1 stays in LDS. 4 waves (1x4 col split).
// ---------------------------------------------------------------------------
__global__ __launch_bounds__(256) void fused_ffn(
    const float* __restrict__ x,
    const unsigned short* __restrict__ W1,   // [1024][256] bf16
    const float* __restrict__ b1,
    const unsigned short* __restrict__ W2,   // [256][1024] bf16
    const float* __restrict__ b2,
    const float* __restrict__ g,
    const float* __restrict__ beta,
    float* __restrict__ xout)
{
    __shared__ unsigned short sX[16 * 264];
    __shared__ unsigned short x1[16 * 1032];
    __shared__ unsigned short sW[256 * 40];
    __shared__ float redS[4][16];
    __shared__ float redQ[4][16];

    const int tid  = threadIdx.x;
    const int lane = tid & 63;
    const int w    = tid >> 6;
    const int fr   = lane & 15;
    const int ksub = lane >> 4;
    const int m0   = blockIdx.x * 16;

    // stage x tile (16x256) as bf16, reused by all ff1 chunks
    #pragma unroll
    for (int j = 0; j < 2; ++j) {
        int s = tid + j * 256;
        int row = s >> 5, c8 = s & 31;
        const float* xp = &x[(long)(m0 + row) * DMODEL + c8 * 8];
        float4 a0 = *(const float4*)xp;
        float4 a1 = *(const float4*)(xp + 4);
        u16x8 av;
        av[0] = f32_to_bf16_rne(a0.x); av[1] = f32_to_bf16_rne(a0.y);
        av[2] = f32_to_bf16_rne(a0.z); av[3] = f32_to_bf16_rne(a0.w);
        av[4] = f32_to_bf16_rne(a1.x); av[5] = f32_to_bf16_rne(a1.y);
        av[6] = f32_to_bf16_rne(a1.z); av[7] = f32_to_bf16_rne(a1.w);
        *(u16x8*)&sX[row * 264 + c8 * 8] = av;
    }

    // ---- ff1: 4 chunks of 256 outputs ----
    for (int nc = 0; nc < 4; ++nc) {
        f32x4 acc[4] = {};
        for (int k0 = 0; k0 < DMODEL; k0 += 32) {
            u16x8 wv[4];
            #pragma unroll
            for (int j = 0; j < 4; ++j) {
                int s = tid + j * 256;
                int rr = s >> 2, c = s & 3;
                wv[j] = *(const u16x8*)&W1[(long)(nc * 256 + rr) * DMODEL + k0 + c * 8];
            }
            __syncthreads();
            #pragma unroll
            for (int j = 0; j < 4; ++j) {
                int s = tid + j * 256;
                int rr = s >> 2, c = s & 3;
                *(u16x8*)&sW[rr * 40 + c * 8] = wv[j];
            }
            __syncthreads();
            bf16x8 af = *(bf16x8*)&sX[fr * 264 + k0 + ksub * 8];
            #pragma unroll
            for (int ni = 0; ni < 4; ++ni) {
                bf16x8 bf = *(bf16x8*)&sW[(w * 64 + ni * 16 + fr) * 40 + ksub * 8];
                acc[ni] = __builtin_amdgcn_mfma_f32_16x16x32_bf16(af, bf, acc[ni], 0, 0, 0);
            }
        }
        #pragma unroll
        for (int ni = 0; ni < 4; ++ni) {
            int col = nc * 256 + w * 64 + ni * 16 + fr;
            float bv = b1[col];
            #pragma unroll
            for (int r = 0; r < 4; ++r) {
                int row = ksub * 4 + r;
                x1[row * 1032 + col] = f32_to_bf16_rne(fmaxf(acc[ni][r] + bv, 0.f));
            }
        }
    }

    // ---- ff2: K=1024 from LDS x1 ----
    f32x4 acc2[4] = {};
    for (int k0 = 0; k0 < 4 * DMODEL; k0 += 32) {
        u16x8 wv[4];
        #pragma unroll
        for (int j = 0; j < 4; ++j) {
            int s = tid + j * 256;
            int rr = s >> 2, c = s & 3;
            wv[j] = *(const u16x8*)&W2[(long)rr * 1024 + k0 + c * 8];
        }
        __syncthreads();
        #pragma unroll
        for (int j = 0; j < 4; ++j) {
            int s = tid + j * 256;
            int rr = s >> 2, c = s & 3;
            *(u16x8*)&sW[rr * 40 + c * 8] = wv[j];
        }
        __syncthreads();
        bf16x8 af = *(bf16x8*)&x1[fr * 1032 + k0 + ksub * 8];
        #pragma unroll
        for (int ni = 0; ni < 4; ++ni) {
            bf16x8 bf = *(bf16x8*)&sW[(w * 64 + ni * 16 + fr) * 40 + ksub * 8];
            acc2[ni] = __builtin_amdgcn_mfma_f32_16x16x32_bf16(af, bf, acc2[ni], 0, 0, 0);
        }
    }

    // ---- epilogue: + b2 + residual, LN ----
    float vres[4][4];
    #pragma unroll
    for (int ni = 0; ni < 4; ++ni) {
        int col = w * 64 + ni * 16 + fr;
        float bv = b2[col];
        #pragma unroll
        for (int r = 0; r < 4; ++r) {
            int row = m0 + ksub * 4 + r;
            vres[ni][r] = acc2[ni][r] + bv + x[(long)row * DMODEL + col];
        }
    }

    #pragma unroll
    for (int r = 0; r < 4; ++r) {
        float s = 0.f, qq = 0.f;
        #pragma unroll
        for (int ni = 0; ni < 4; ++ni) {
            s  += vres[ni][r];
            qq += vres[ni][r] * vres[ni][r];
        }
        #pragma unroll
        for (int mask = 1; mask < 16; mask <<= 1) {
            s  += __shfl_xor(s, mask);
            qq += __shfl_xor(qq, mask);
        }
        if (fr == 0) {
            redS[w][ksub * 4 + r] = s;
            redQ[w][ksub * 4 + r] = qq;
        }
    }
    __syncthreads();

    #pragma unroll
    for (int r = 0; r < 4; ++r) {
        int rl = ksub * 4 + r;
        float sum  = redS[0][rl] + redS[1][rl] + redS[2][rl] + redS[3][rl];
        float sumq = redQ[0][rl] + redQ[1][rl] + redQ[2][rl] + redQ[3][rl];
        float mean = sum * (1.f / 256.f);
        float var  = sumq * (1.f / 256.f) - mean * mean;
        float rstd = rsqrtf(var + 1e-5f);
        int row = m0 + rl;
        #pragma unroll
        for (int ni = 0; ni < 4; ++ni) {
            int col = w * 64 + ni * 16 + fr;
            xout[(long)row * DMODEL + col] =
                (vres[ni][r] - mean) * rstd * g[col] + beta[col];
        }
    }
}

// ===========================================================================
// Fallback (fp32) path kernels — used only if ws is too small.
// ===========================================================================
__global__ __launch_bounds__(256) void embed_kernel(
    const int* __restrict__ word_idx,
    const int* __restrict__ ngram_idx,
    const float* __restrict__ fc1_w,
    const float* __restrict__ fc1_b,
    const float* __restrict__ fc2_w,
    const float* __restrict__ fc2_b,
    float* __restrict__ x)
{
    __shared__ int   feats[8][8];
    __shared__ int   nf[8];
    __shared__ float x1[8][FFDIM];

    const int t0  = blockIdx.x * 8;
    const int tid = threadIdx.x;

    if (tid < 8) {
        int t = t0 + tid;
        int cnt = 0;
        feats[tid][cnt++] = word_idx[t];
        for (int k = 0; k < 6; ++k) {
            int f = WORDC + ngram_idx[t * 6 + k];
            bool dup = false;
            for (int s = 1; s < cnt; ++s)
                if (feats[tid][s] == f) dup = true;
            if (!dup) feats[tid][cnt++] = f;
        }
        nf[tid] = cnt;
    }
    __syncthreads();

    for (int it = 0; it < 16; ++it) {
        int item = it * 256 + tid;
        int tt = item >> 9;
        int j  = item & 511;
        float acc = fc1_b[j];
        int n = nf[tt];
        const float* rowbase = fc1_w + (long)j * F_TOT;
        for (int s = 0; s < n; ++s)
            acc += rowbase[feats[tt][s]];
        x1[tt][j] = fmaxf(acc, 0.f);
    }
    __syncthreads();

    const int d = tid;
    float acc[8];
    float bb = fc2_b[d];
    #pragma unroll
    for (int tt = 0; tt < 8; ++tt) acc[tt] = bb;
    const float* wrow = fc2_w + d * FFDIM;
    for (int k = 0; k < FFDIM; ++k) {
        float wv = wrow[k];
        #pragma unroll
        for (int tt = 0; tt < 8; ++tt) acc[tt] += wv * x1[tt][k];
    }
    #pragma unroll
    for (int tt = 0; tt < 8; ++tt)
        x[(t0 + tt) * DMODEL + d] = acc[tt];
}

template<bool RELU>
__global__ __launch_bounds__(256) void gemm_bias(
    const float* __restrict__ A,
    const float* __restrict__ W,
    const float* __restrict__ bias,
    float* __restrict__ C,
    int M, int N, int K)
{
    __shared__ float sA[16][64];
    __shared__ float sW[16][64];

    const int tid = threadIdx.x;
    const int tx = tid & 15;
    const int ty = tid >> 4;
    const int m0 = blockIdx.y * 64;
    const int n0 = blockIdx.x * 64;

    const int lr = tid >> 2;
    const int lc = tid & 3;

    float acc[4][4] = {};

    for (int k0 = 0; k0 < K; k0 += 16) {
        float4 av = *(const float4*)&A[(long)(m0 + lr) * K + k0 + lc * 4];
        float4 wv = *(const float4*)&W[(long)(n0 + lr) * K + k0 + lc * 4];
        __syncthreads();
        sA[lc * 4 + 0][lr] = av.x; sA[lc * 4 + 1][lr] = av.y;
        sA[lc * 4 + 2][lr] = av.z; sA[lc * 4 + 3][lr] = av.w;
        sW[lc * 4 + 0][lr] = wv.x; sW[lc * 4 + 1][lr] = wv.y;
        sW[lc * 4 + 2][lr] = wv.z; sW[lc * 4 + 3][lr] = wv.w;
        __syncthreads();
        #pragma unroll
        for (int k = 0; k < 16; ++k) {
            float4 a4 = *(const float4*)&sA[k][ty * 4];
            float4 b4 = *(const float4*)&sW[k][tx * 4];
            float am[4] = {a4.x, a4.y, a4.z, a4.w};
            float bn[4] = {b4.x, b4.y, b4.z, b4.w};
            #pragma unroll
            for (int i = 0; i < 4; ++i)
                #pragma unroll
                for (int j = 0; j < 4; ++j)
                    acc[i][j] += am[i] * bn[j];
        }
    }

    float4 bv = *(const float4*)&bias[n0 + tx * 4];
    #pragma unroll
    for (int i = 0; i < 4; ++i) {
        int m = m0 + ty * 4 + i;
        float4 o;
        o.x = acc[i][0] + bv.x;
        o.y = acc[i][1] + bv.y;
        o.z = acc[i][2] + bv.z;
        o.w = acc[i][3] + bv.w;
        if (RELU) {
            o.x = fmaxf(o.x, 0.f); o.y = fmaxf(o.y, 0.f);
            o.z = fmaxf(o.z, 0.f); o.w = fmaxf(o.w, 0.f);
        }
        *(float4*)&C[(long)m * N + n0 + tx * 4] = o;
    }
}

__global__ __launch_bounds__(256) void attn_kernel(
    const float* __restrict__ qkv,
    float* __restrict__ o)
{
    const int b = blockIdx.x >> 3;
    const int h = blockIdx.x & 7;
    const int tid = threadIdx.x;
    const int q = tid >> 2;
    const int p = tid & 3;

    __shared__ float Kt[SEQL][HDIM + 1];
    __shared__ float Vt[SEQL][HDIM + 1];
    __shared__ float S[SEQL][SEQL + 1];

    const float scale = 0.17677669529663687f;

    {
        int fidx = tid * 2;
        int row  = fidx >> 3;
        int c    = (fidx & 7) * 4;
        const float* kb = qkv + (long)(b * SEQL + row) * 768 + 256 + h * HDIM + c;
        float4 k0 = *(const float4*)kb;
        float4 k1 = *(const float4*)(kb + 4);
        float4 v0 = *(const float4*)(kb + 256);
        float4 v1 = *(const float4*)(kb + 260);
        *(float4*)&Kt[row][c]     = k0;
        *(float4*)&Kt[row][c + 4] = k1;
        *(float4*)&Vt[row][c]     = v0;
        *(float4*)&Vt[row][c + 4] = v1;
    }

    float qreg[HDIM];
    {
        const float* qb = qkv + (long)(b * SEQL + q) * 768 + h * HDIM;
        #pragma unroll
        for (int c = 0; c < HDIM / 4; ++c) {
            float4 v = *(const float4*)(qb + c * 4);
            qreg[c * 4 + 0] = v.x * scale;
            qreg[c * 4 + 1] = v.y * scale;
            qreg[c * 4 + 2] = v.z * scale;
            qreg[c * 4 + 3] = v.w * scale;
        }
    }
    __syncthreads();

    float sc[16];
    float mx = -1e30f;
    #pragma unroll
    for (int i = 0; i < 16; ++i) {
        int jj = p * 16 + i;
        float s = 0.f;
        #pragma unroll
        for (int d = 0; d < HDIM; ++d) s += qreg[d] * Kt[jj][d];
        sc[i] = s;
        mx = fmaxf(mx, s);
    }
    mx = fmaxf(mx, __shfl_xor(mx, 1));
    mx = fmaxf(mx, __shfl_xor(mx, 2));

    float sum = 0.f;
    #pragma unroll
    for (int i = 0; i < 16; ++i) {
        float e = __expf(sc[i] - mx);
        S[q][p * 16 + i] = e;
        sum += e;
    }
    sum += __shfl_xor(sum, 1);
    sum += __shfl_xor(sum, 2);
    const float inv = 1.f / sum;
    __syncthreads();

    float acc[8] = {};
    for (int jj = 0; jj < SEQL; ++jj) {
        float pv = S[q][jj];
        #pragma unroll
        for (int d = 0; d < 8; ++d) acc[d] += pv * Vt[jj][p * 8 + d];
    }
    float* orow = o + (long)(b * SEQL + q) * DMODEL + h * HDIM + p * 8;
    float4 o0, o1;
    o0.x = acc[0] * inv; o0.y = acc[1] * inv; o0.z = acc[2] * inv; o0.w = acc[3] * inv;
    o1.x = acc[4] * inv; o1.y = acc[5] * inv; o1.z = acc[6] * inv; o1.w = acc[7] * inv;
    *(float4*)orow = o0;
    *(float4*)(orow + 4) = o1;
}

__global__ __launch_bounds__(256) void add_ln_kernel(
    const float* __restrict__ xin,
    const float* __restrict__ f,
    const float* __restrict__ g,
    const float* __restrict__ bta,
    float* __restrict__ xout)
{
    const int w = threadIdx.x >> 6;
    const int lane = threadIdx.x & 63;
    const int t = blockIdx.x * 4 + w;

    float4 xv = *(const float4*)&xin[(long)t * DMODEL + lane * 4];
    float4 fv = *(const float4*)&f[(long)t * DMODEL + lane * 4];
    float v0 = xv.x + fv.x, v1 = xv.y + fv.y, v2 = xv.z + fv.z, v3 = xv.w + fv.w;

    float s  = v0 + v1 + v2 + v3;
    float sq = v0 * v0 + v1 * v1 + v2 * v2 + v3 * v3;
    #pragma unroll
    for (int off = 1; off < 64; off <<= 1) {
        s  += __shfl_xor(s, off);
        sq += __shfl_xor(sq, off);
    }
    float mean = s * (1.f / 256.f);
    float var  = sq * (1.f / 256.f) - mean * mean;
    float rs   = rsqrtf(var + 1e-5f);

    float4 gv = *(const float4*)&g[lane * 4];
    float4 bv = *(const float4*)&bta[lane * 4];
    float4 o;
    o.x = (v0 - mean) * rs * gv.x + bv.x;
    o.y = (v1 - mean) * rs * gv.y + bv.y;
    o.z = (v2 - mean) * rs * gv.z + bv.z;
    o.w = (v3 - mean) * rs * gv.w + bv.w;
    *(float4*)&xout[(long)t * DMODEL + lane * 4] = o;
}

// ---------------------------------------------------------------------------
extern "C" void kernel_launch(void* const* d_in, const int* in_sizes, int n_in,
                              void* d_out, int out_size, void* d_ws, size_t ws_size,
                              hipStream_t stream) {
    const int*   word_idx  = (const int*)d_in[0];
    const int*   ngram_idx = (const int*)d_in[1];
    const float* fc1_w = (const float*)d_in[2];
    const float* fc1_b = (const float*)d_in[3];
    const float* fc2_w = (const float*)d_in[4];
    const float* fc2_b = (const float*)d_in[5];
    const float* qkv_w = (const float*)d_in[6];
    const float* qkv_b = (const float*)d_in[7];
    const float* out_w = (const float*)d_in[8];
    const float* out_b = (const float*)d_in[9];
    const float* ln1_g = (const float*)d_in[10];
    const float* ln1_b = (const float*)d_in[11];
    const float* ff1_w = (const float*)d_in[12];
    const float* ff1_b = (const float*)d_in[13];
    const float* ff2_w = (const float*)d_in[14];
    const float* ff2_b = (const float*)d_in[15];
    const float* ln2_g = (const float*)d_in[16];
    const float* ln2_b = (const float*)d_in[17];

    float* x = (float*)d_out;  // [2048][256]

    // fast-path ws layout (bytes)
    const size_t BM_OFF   = 0;                         // bitmap: 2500 u32
    const size_t FC1T_OFF = 10240;
    const size_t FC1T_BYTES = (size_t)F_TOT * FFDIM * 2;              // 81,920,000
    const size_t QKVT_OFF = FC1T_OFF + FC1T_BYTES;
    const size_t QKVT_BYTES = (size_t)2 * 768 * 256 * 2;
    const size_t OUTT_OFF = QKVT_OFF + QKVT_BYTES;
    const size_t OUTT_BYTES = (size_t)2 * 256 * 256 * 2;
    const size_t FF1T_OFF = OUTT_OFF + OUTT_BYTES;
    const size_t FF1T_BYTES = (size_t)2 * 1024 * 256 * 2;
    const size_t FF2T_OFF = FF1T_OFF + FF1T_BYTES;
    const size_t FF2T_BYTES = (size_t)2 * 256 * 1024 * 2;
    const size_t ATTN_OFF = FF2T_OFF + FF2T_BYTES;
    const size_t ATTN_BYTES = (size_t)NTOK * DMODEL * 4;
    const size_t FAST_BYTES = ATTN_OFF + ATTN_BYTES;

    if (ws_size >= FAST_BYTES) {
        unsigned int*   bm   = (unsigned int*)((char*)d_ws + BM_OFF);
        unsigned short* fc1T = (unsigned short*)((char*)d_ws + FC1T_OFF);
        unsigned short* qkvT = (unsigned short*)((char*)d_ws + QKVT_OFF);
        unsigned short* outT = (unsigned short*)((char*)d_ws + OUTT_OFF);
        unsigned short* ff1T = (unsigned short*)((char*)d_ws + FF1T_OFF);
        unsigned short* ff2T = (unsigned short*)((char*)d_ws + FF2T_OFF);
        float* attn_raw = (float*)((char*)d_ws + ATTN_OFF);

        mark_feats<<<1, 256, 0, stream>>>(word_idx, ngram_idx, bm);
        transpose_cvt<<<10192, 256, 0, stream>>>(
            fc1_w, fc1T, bm, qkv_w, out_w, ff1_w, ff2_w, qkvT, outT, ff1T, ff2T);
        embed_gather<<<NTOK / 8, 256, 0, stream>>>(word_idx, ngram_idx, fc1T,
                                                   fc1_b, fc2_w, fc2_b, x);

        for (int i = 0; i < 2; ++i) {
            fused_qkv_attn<<<32 * NHEAD, 256, 0, stream>>>(
                x, qkvT + (long)i * 768 * 256, qkv_b + i * 768, attn_raw);

            gemm_ln<<<NTOK / 16, 256, 0, stream>>>(
                attn_raw, outT + (long)i * 256 * 256, out_b + i * 256,
                x, ln1_g + i * 256, ln1_b + i * 256, x);

            fused_ffn<<<NTOK / 16, 256, 0, stream>>>(
                x, ff1T + (long)i * 1024 * 256, ff1_b + i * 1024,
                ff2T + (long)i * 256 * 1024, ff2_b + i * 256,
                ln2_g + i * 256, ln2_b + i * 256, x);
        }
    } else {
        float* wsf      = (float*)d_ws;
        float* qkvbuf   = wsf;
        float* attn_raw = qkvbuf + 2048 * 768;
        float* obuf     = attn_raw + 2048 * 256;
        float* ffbuf    = obuf + 2048 * 256;

        embed_kernel<<<NTOK / 8, 256, 0, stream>>>(word_idx, ngram_idx, fc1_w,
                                                   fc1_b, fc2_w, fc2_b, x);
        for (int i = 0; i < 2; ++i) {
            gemm_bias<false><<<dim3(768 / 64, NTOK / 64), 256, 0, stream>>>(
                x, qkv_w + (long)i * 768 * 256, qkv_b + i * 768, qkvbuf,
                NTOK, 768, 256);
            attn_kernel<<<32 * NHEAD, 256, 0, stream>>>(qkvbuf, attn_raw);
            gemm_bias<false><<<dim3(256 / 64, NTOK / 64), 256, 0, stream>>>(
                attn_raw, out_w + (long)i * 256 * 256, out_b + i * 256, obuf,
                NTOK, 256, 256);
            add_ln_kernel<<<NTOK / 4, 256, 0, stream>>>(x, obuf, ln1_g + i * 256,
                                                        ln1_b + i * 256, x);
            gemm_bias<true><<<dim3(1024 / 64, NTOK / 64), 256, 0, stream>>>(
                x, ff1_w + (long)i * 1024 * 256, ff1_b + i * 1024, ffbuf,
                NTOK, 1024, 256);
            gemm_bias<false><<<dim3(256 / 64, NTOK / 64), 256, 0, stream>>>(
                ffbuf, ff2_w + (long)i * 256 * 1024, ff2_b + i * 256, obuf,
                NTOK, 256, 1024);
            add_ln_kernel<<<NTOK / 4, 256, 0, stream>>>(x, obuf, ln2_g + i * 256,
                                                        ln2_b + i * 256, x);
        }
    }
}

// Round 6
// 166.795 us; speedup vs baseline: 2.4873x; 1.1925x over previous
//
#include <hip/hip_runtime.h>
#include <hip/hip_bf16.h>
#include <math.h>

#define WORDC 30000
#define F_TOT 80000
#define NTOK  2048
#define DMODEL 256
#define FFDIM 512
#define NHEAD 8
#define HDIM  32
#define SEQL  64

typedef __attribute__((ext_vector_type(8))) short bf16x8;
typedef __attribute__((ext_vector_type(8))) unsigned short u16x8;
typedef __attribute__((ext_vector_type(4))) float f32x4;

__device__ __forceinline__ unsigned short f32_to_bf16_rne(float x) {
    unsigned int u = __float_as_uint(x);
    unsigned int r = (u + 0x7FFFu + ((u >> 16) & 1u)) >> 16;
    return (unsigned short)r;
}

__device__ __forceinline__ u16x8 cvt8(float4 a, float4 b) {
    u16x8 v;
    v[0] = f32_to_bf16_rne(a.x); v[1] = f32_to_bf16_rne(a.y);
    v[2] = f32_to_bf16_rne(a.z); v[3] = f32_to_bf16_rne(a.w);
    v[4] = f32_to_bf16_rne(b.x); v[5] = f32_to_bf16_rne(b.y);
    v[6] = f32_to_bf16_rne(b.z); v[7] = f32_to_bf16_rne(b.w);
    return v;
}

// ---------------------------------------------------------------------------
// Build bitmap of used features (word + ngram), one block.
// ---------------------------------------------------------------------------
__global__ __launch_bounds__(256) void mark_feats(
    const int* __restrict__ word_idx,
    const int* __restrict__ ngram_idx,
    unsigned int* __restrict__ bm)
{
    __shared__ unsigned int lbm[2500];
    const int tid = threadIdx.x;
    for (int i = tid; i < 2500; i += 256) lbm[i] = 0u;
    __syncthreads();
    for (int j = tid; j < NTOK; j += 256) {
        int f = word_idx[j];
        atomicOr(&lbm[f >> 5], 1u << (f & 31));
    }
    for (int j = tid; j < NTOK * 6; j += 256) {
        int f = WORDC + ngram_idx[j];
        atomicOr(&lbm[f >> 5], 1u << (f & 31));
    }
    __syncthreads();
    for (int i = tid; i < 2500; i += 256) bm[i] = lbm[i];
}

// ---------------------------------------------------------------------------
// Transpose fc1_w (store-pruned by bitmap) + cvt transformer weights.
// ---------------------------------------------------------------------------
__global__ __launch_bounds__(256) void transpose_cvt(
    const float* __restrict__ fc1_w,
    unsigned short* __restrict__ fc1T,
    const unsigned int* __restrict__ bm,
    const float* __restrict__ s0, const float* __restrict__ s1,
    const float* __restrict__ s2, const float* __restrict__ s3,
    unsigned short* __restrict__ d0, unsigned short* __restrict__ d1,
    unsigned short* __restrict__ d2, unsigned short* __restrict__ d3)
{
    __shared__ float tile[64][65];
    const int bid = blockIdx.x;
    const int tid = threadIdx.x;

    if (bid < 10000) {
        const int f0 = (bid % 1250) * 64;
        const int j0 = (bid / 1250) * 64;

        const int fr = (tid & 15) * 4;
        const int jr = tid >> 4;
        #pragma unroll
        for (int p = 0; p < 4; ++p) {
            int j = j0 + p * 16 + jr;
            float4 v = *(const float4*)&fc1_w[(long)j * F_TOT + f0 + fr];
            tile[fr + 0][p * 16 + jr] = v.x;
            tile[fr + 1][p * 16 + jr] = v.y;
            tile[fr + 2][p * 16 + jr] = v.z;
            tile[fr + 3][p * 16 + jr] = v.w;
        }
        __syncthreads();

        const int jc  = (tid & 15) * 4;
        const int fr2 = tid >> 4;
        #pragma unroll
        for (int p = 0; p < 4; ++p) {
            int fi = p * 16 + fr2;
            int f  = f0 + fi;
            if ((bm[f >> 5] >> (f & 31)) & 1u) {
                ushort4 o;
                o.x = f32_to_bf16_rne(tile[fi][jc + 0]);
                o.y = f32_to_bf16_rne(tile[fi][jc + 1]);
                o.z = f32_to_bf16_rne(tile[fi][jc + 2]);
                o.w = f32_to_bf16_rne(tile[fi][jc + 3]);
                *(ushort4*)&fc1T[(long)f * FFDIM + j0 + jc] = o;
            }
        }
    } else {
        int s = bid - 10000;
        int ten = s / 48, b48 = s % 48;
        const float* src; unsigned short* dst; int n4;
        switch (ten) {
            case 0:  src = s0; dst = d0; n4 = 2 * 768 * 256 / 4;  break;
            case 1:  src = s1; dst = d1; n4 = 2 * 256 * 256 / 4;  break;
            case 2:  src = s2; dst = d2; n4 = 2 * 1024 * 256 / 4; break;
            default: src = s3; dst = d3; n4 = 2 * 256 * 1024 / 4; break;
        }
        for (int i = b48 * 256 + tid; i < n4; i += 48 * 256) {
            float4 v = ((const float4*)src)[i];
            ushort4 o;
            o.x = f32_to_bf16_rne(v.x);
            o.y = f32_to_bf16_rne(v.y);
            o.z = f32_to_bf16_rne(v.z);
            o.w = f32_to_bf16_rne(v.w);
            ((ushort4*)dst)[i] = o;
        }
    }
}

// ---------------------------------------------------------------------------
// Gather path: dedupe -> sum bf16 rows of fc1T -> relu -> fc2
// ---------------------------------------------------------------------------
__global__ __launch_bounds__(256) void embed_gather(
    const int* __restrict__ word_idx,
    const int* __restrict__ ngram_idx,
    const unsigned short* __restrict__ fc1_wT,
    const float* __restrict__ fc1_b,
    const float* __restrict__ fc2_w,
    const float* __restrict__ fc2_b,
    float* __restrict__ x)
{
    __shared__ int   feats[8][8];
    __shared__ int   nf[8];
    __shared__ float x1[8][FFDIM];

    const int t0  = blockIdx.x * 8;
    const int tid = threadIdx.x;

    if (tid < 8) {
        int t = t0 + tid;
        int cnt = 0;
        feats[tid][cnt++] = word_idx[t];
        for (int k = 0; k < 6; ++k) {
            int f = WORDC + ngram_idx[t * 6 + k];
            bool dup = false;
            for (int s = 1; s < cnt; ++s)
                if (feats[tid][s] == f) dup = true;
            if (!dup) feats[tid][cnt++] = f;
        }
        nf[tid] = cnt;
    }
    __syncthreads();

    const float2 bb = *(const float2*)&fc1_b[tid * 2];
    #pragma unroll
    for (int tt = 0; tt < 8; ++tt) {
        float a0 = bb.x, a1 = bb.y;
        int n = nf[tt];
        for (int s = 0; s < n; ++s) {
            unsigned int wrd = *(const unsigned int*)
                &fc1_wT[(long)feats[tt][s] * FFDIM + tid * 2];
            a0 += __uint_as_float((wrd & 0xFFFFu) << 16);
            a1 += __uint_as_float(wrd & 0xFFFF0000u);
        }
        x1[tt][tid * 2 + 0] = fmaxf(a0, 0.f);
        x1[tt][tid * 2 + 1] = fmaxf(a1, 0.f);
    }
    __syncthreads();

    const int d = tid;
    float acc[8];
    float cb = fc2_b[d];
    #pragma unroll
    for (int tt = 0; tt < 8; ++tt) acc[tt] = cb;
    const float* wrow = fc2_w + d * FFDIM;
    for (int k = 0; k < FFDIM; ++k) {
        float wv = wrow[k];
        #pragma unroll
        for (int tt = 0; tt < 8; ++tt) acc[tt] += wv * x1[tt][k];
    }
    #pragma unroll
    for (int tt = 0; tt < 8; ++tt)
        x[(t0 + tt) * DMODEL + d] = acc[tt];
}

// ---------------------------------------------------------------------------
// Fused per-(b,h) QKV GEMM (dbuf, BK=64) + MFMA attention.
// grid 256 = (b,h); 256 threads = 4 waves; wave owns 16 query rows.
// ---------------------------------------------------------------------------
__global__ __launch_bounds__(256) void fused_qkv_attn(
    const float* __restrict__ x,            // [2048][256]
    const unsigned short* __restrict__ Wq,  // layer qkvT [768][256]
    const float* __restrict__ bq,           // layer qkv_b [768]
    float* __restrict__ o)                  // attn_raw [2048][256]
{
    __shared__ unsigned short sA[2][64 * 72];
    __shared__ unsigned short sW[2][96 * 72];
    __shared__ unsigned short sQ[64 * 40];
    __shared__ unsigned short sK[64 * 40];
    __shared__ unsigned short sVt[32 * 72];
    __shared__ unsigned short sP[64 * 72];

    const int b = blockIdx.x >> 3;
    const int h = blockIdx.x & 7;
    const int tid  = threadIdx.x;
    const int lane = tid & 63;
    const int w    = tid >> 6;
    const int fr   = lane & 15;
    const int ksub = lane >> 4;
    const int row0 = b * SEQL;

    const int ar = tid >> 3;   // 0..31
    const int ac = tid & 7;    // 8-elem chunk

    f32x4 acc[6] = {};
    float4 af32[2][2];
    u16x8  wreg[3];

    // ---- phase 1: QKV GEMM, 4 iters BK=64, double-buffered ----
    {
        // prologue stage t=0
        {
            const float* ap0 = &x[(long)(row0 + ar) * DMODEL + ac * 8];
            af32[0][0] = *(const float4*)ap0;
            af32[0][1] = *(const float4*)(ap0 + 4);
            const float* ap1 = ap0 + 32 * DMODEL;
            af32[1][0] = *(const float4*)ap1;
            af32[1][1] = *(const float4*)(ap1 + 4);
            #pragma unroll
            for (int j = 0; j < 3; ++j) {
                int rr = ar + j * 32;
                int grow = (rr >> 5) * 256 + h * HDIM + (rr & 31);
                wreg[j] = *(const u16x8*)&Wq[(long)grow * DMODEL + ac * 8];
            }
        }
        #pragma unroll
        for (int it = 0; it < 2; ++it)
            *(u16x8*)&sA[0][(ar + it * 32) * 72 + ac * 8] = cvt8(af32[it][0], af32[it][1]);
        #pragma unroll
        for (int j = 0; j < 3; ++j)
            *(u16x8*)&sW[0][(ar + j * 32) * 72 + ac * 8] = wreg[j];
        __syncthreads();

        for (int t = 0; t < 4; ++t) {
            if (t < 3) {
                int k0 = (t + 1) * 64;
                const float* ap0 = &x[(long)(row0 + ar) * DMODEL + k0 + ac * 8];
                af32[0][0] = *(const float4*)ap0;
                af32[0][1] = *(const float4*)(ap0 + 4);
                const float* ap1 = ap0 + 32 * DMODEL;
                af32[1][0] = *(const float4*)ap1;
                af32[1][1] = *(const float4*)(ap1 + 4);
                #pragma unroll
                for (int j = 0; j < 3; ++j) {
                    int rr = ar + j * 32;
                    int grow = (rr >> 5) * 256 + h * HDIM + (rr & 31);
                    wreg[j] = *(const u16x8*)&Wq[(long)grow * DMODEL + k0 + ac * 8];
                }
            }
            const int buf = t & 1;
            #pragma unroll
            for (int kk = 0; kk < 2; ++kk) {
                bf16x8 af = *(bf16x8*)&sA[buf][(w * 16 + fr) * 72 + kk * 32 + ksub * 8];
                #pragma unroll
                for (int ni = 0; ni < 6; ++ni) {
                    bf16x8 bf = *(bf16x8*)&sW[buf][(ni * 16 + fr) * 72 + kk * 32 + ksub * 8];
                    acc[ni] = __builtin_amdgcn_mfma_f32_16x16x32_bf16(af, bf, acc[ni], 0, 0, 0);
                }
            }
            __syncthreads();
            if (t < 3) {
                const int nb = (t + 1) & 1;
                #pragma unroll
                for (int it = 0; it < 2; ++it)
                    *(u16x8*)&sA[nb][(ar + it * 32) * 72 + ac * 8] = cvt8(af32[it][0], af32[it][1]);
                #pragma unroll
                for (int j = 0; j < 3; ++j)
                    *(u16x8*)&sW[nb][(ar + j * 32) * 72 + ac * 8] = wreg[j];
                __syncthreads();
            }
        }
    }

    // ---- phase 1 epilogue: scatter Q,K,V^T to bf16 LDS tiles ----
    const float scale = 0.17677669529663687f;  // 1/sqrt(32)
    #pragma unroll
    for (int ni = 0; ni < 6; ++ni) {
        const int part = ni >> 1;               // 0=Q 1=K 2=V (fr<16)
        const int pc   = ((ni & 1) << 4) + fr;  // col within 32
        float bv = bq[(part << 8) + h * HDIM + pc];
        #pragma unroll
        for (int r = 0; r < 4; ++r) {
            int row = w * 16 + ksub * 4 + r;
            float v = acc[ni][r] + bv;
            if (part == 0)      sQ[row * 40 + pc] = f32_to_bf16_rne(v * scale);
            else if (part == 1) sK[row * 40 + pc] = f32_to_bf16_rne(v);
            else                sVt[pc * 72 + row] = f32_to_bf16_rne(v);
        }
    }
    __syncthreads();

    // ---- S = Q K^T (MFMA), wave w owns query rows w*16..w*16+15 ----
    f32x4 s4[4];
    {
        bf16x8 afq = *(bf16x8*)&sQ[(w * 16 + fr) * 40 + ksub * 8];
        #pragma unroll
        for (int ni = 0; ni < 4; ++ni) {
            bf16x8 bfk = *(bf16x8*)&sK[(ni * 16 + fr) * 40 + ksub * 8];
            f32x4 z = {};
            s4[ni] = __builtin_amdgcn_mfma_f32_16x16x32_bf16(afq, bfk, z, 0, 0, 0);
        }
    }

    // ---- softmax: rows live in 16-lane fr groups ----
    float minv[4];
    #pragma unroll
    for (int r = 0; r < 4; ++r) {
        float m = fmaxf(fmaxf(s4[0][r], s4[1][r]), fmaxf(s4[2][r], s4[3][r]));
        m = fmaxf(m, __shfl_xor(m, 1));
        m = fmaxf(m, __shfl_xor(m, 2));
        m = fmaxf(m, __shfl_xor(m, 4));
        m = fmaxf(m, __shfl_xor(m, 8));
        float p0 = __expf(s4[0][r] - m);
        float p1 = __expf(s4[1][r] - m);
        float p2 = __expf(s4[2][r] - m);
        float p3 = __expf(s4[3][r] - m);
        float sum = p0 + p1 + p2 + p3;
        sum += __shfl_xor(sum, 1);
        sum += __shfl_xor(sum, 2);
        sum += __shfl_xor(sum, 4);
        sum += __shfl_xor(sum, 8);
        minv[r] = 1.f / sum;
        int prow = w * 16 + ksub * 4 + r;
        sP[prow * 72 +  0 + fr] = f32_to_bf16_rne(p0);
        sP[prow * 72 + 16 + fr] = f32_to_bf16_rne(p1);
        sP[prow * 72 + 32 + fr] = f32_to_bf16_rne(p2);
        sP[prow * 72 + 48 + fr] = f32_to_bf16_rne(p3);
    }
    __syncthreads();

    // ---- O = P V (MFMA) ----
    f32x4 o4[2] = {};
    #pragma unroll
    for (int kc = 0; kc < 2; ++kc) {
        bf16x8 afp = *(bf16x8*)&sP[(w * 16 + fr) * 72 + kc * 32 + ksub * 8];
        #pragma unroll
        for (int n2 = 0; n2 < 2; ++n2) {
            bf16x8 bfv = *(bf16x8*)&sVt[(n2 * 16 + fr) * 72 + kc * 32 + ksub * 8];
            o4[n2] = __builtin_amdgcn_mfma_f32_16x16x32_bf16(afp, bfv, o4[n2], 0, 0, 0);
        }
    }
    #pragma unroll
    for (int n2 = 0; n2 < 2; ++n2) {
        #pragma unroll
        for (int r = 0; r < 4; ++r) {
            int row = row0 + w * 16 + ksub * 4 + r;
            o[(long)row * DMODEL + h * HDIM + n2 * 16 + fr] = o4[n2][r] * minv[r];
        }
    }
}

// ---------------------------------------------------------------------------
// Fused GEMM + residual + LayerNorm (out-proj): BK=64, dbuf, 4 iters.
//   xout = LN(xres + A@W^T + bias) * g + beta ; K=256, A fp32
// ---------------------------------------------------------------------------
__global__ __launch_bounds__(256) void gemm_ln(
    const float* __restrict__ A,
    const unsigned short* __restrict__ Wb,
    const float* __restrict__ bias,
    const float* __restrict__ xres,
    const float* __restrict__ g,
    const float* __restrict__ beta,
    float* __restrict__ xout)
{
    __shared__ unsigned short sA[2][16 * 72];
    __shared__ unsigned short sW[2][256 * 72];
    __shared__ float redS[4][16];
    __shared__ float redQ[4][16];

    const int tid  = threadIdx.x;
    const int lane = tid & 63;
    const int w    = tid >> 6;
    const int fr   = lane & 15;
    const int ksub = lane >> 4;
    const int m0   = blockIdx.x * 16;

    const int ar = tid >> 3;   // 0..31 (A uses 0..15)
    const int ac = tid & 7;

    f32x4 acc[4] = {};
    float4 af32[2];
    u16x8  wreg[8];

    // prologue stage t=0
    if (tid < 128) {
        const float* ap = &A[(long)(m0 + ar) * DMODEL + ac * 8];
        af32[0] = *(const float4*)ap;
        af32[1] = *(const float4*)(ap + 4);
    }
    #pragma unroll
    for (int j = 0; j < 8; ++j)
        wreg[j] = *(const u16x8*)&Wb[(long)(ar + j * 32) * DMODEL + ac * 8];

    if (tid < 128)
        *(u16x8*)&sA[0][ar * 72 + ac * 8] = cvt8(af32[0], af32[1]);
    #pragma unroll
    for (int j = 0; j < 8; ++j)
        *(u16x8*)&sW[0][(ar + j * 32) * 72 + ac * 8] = wreg[j];
    __syncthreads();

    for (int t = 0; t < 4; ++t) {
        if (t < 3) {
            int k0 = (t + 1) * 64;
            if (tid < 128) {
                const float* ap = &A[(long)(m0 + ar) * DMODEL + k0 + ac * 8];
                af32[0] = *(const float4*)ap;
                af32[1] = *(const float4*)(ap + 4);
            }
            #pragma unroll
            for (int j = 0; j < 8; ++j)
                wreg[j] = *(const u16x8*)&Wb[(long)(ar + j * 32) * DMODEL + k0 + ac * 8];
        }
        const int buf = t & 1;
        #pragma unroll
        for (int kk = 0; kk < 2; ++kk) {
            bf16x8 af = *(bf16x8*)&sA[buf][fr * 72 + kk * 32 + ksub * 8];
            #pragma unroll
            for (int ni = 0; ni < 4; ++ni) {
                bf16x8 bf = *(bf16x8*)&sW[buf][(w * 64 + ni * 16 + fr) * 72 + kk * 32 + ksub * 8];
                acc[ni] = __builtin_amdgcn_mfma_f32_16x16x32_bf16(af, bf, acc[ni], 0, 0, 0);
            }
        }
        __syncthreads();
        if (t < 3) {
            const int nb = (t + 1) & 1;
            if (tid < 128)
                *(u16x8*)&sA[nb][ar * 72 + ac * 8] = cvt8(af32[0], af32[1]);
            #pragma unroll
            for (int j = 0; j < 8; ++j)
                *(u16x8*)&sW[nb][(ar + j * 32) * 72 + ac * 8] = wreg[j];
            __syncthreads();
        }
    }

    float vres[4][4];
    #pragma unroll
    for (int ni = 0; ni < 4; ++ni) {
        int col = w * 64 + ni * 16 + fr;
        float bv = bias[col];
        #pragma unroll
        for (int r = 0; r < 4; ++r) {
            int row = m0 + ksub * 4 + r;
            vres[ni][r] = acc[ni][r] + bv + xres[(long)row * DMODEL + col];
        }
    }

    #pragma unroll
    for (int r = 0; r < 4; ++r) {
        float s = 0.f, qq = 0.f;
        #pragma unroll
        for (int ni = 0; ni < 4; ++ni) {
            s  += vres[ni][r];
            qq += vres[ni][r] * vres[ni][r];
        }
        #pragma unroll
        for (int mask = 1; mask < 16; mask <<= 1) {
            s  += __shfl_xor(s, mask);
            qq += __shfl_xor(qq, mask);
        }
        if (fr == 0) {
            redS[w][ksub * 4 + r] = s;
            redQ[w][ksub * 4 + r] = qq;
        }
    }
    __syncthreads();

    #pragma unroll
    for (int r = 0; r < 4; ++r) {
        int rl = ksub * 4 + r;
        float sum  = redS[0][rl] + redS[1][rl] + redS[2][rl] + redS[3][rl];
        float sumq = redQ[0][rl] + redQ[1][rl] + redQ[2][rl] + redQ[3][rl];
        float mean = sum * (1.f / 256.f);
        float var  = sumq * (1.f / 256.f) - mean * mean;
        float rstd = rsqrtf(var + 1e-5f);
        int row = m0 + rl;
        #pragma unroll
        for (int ni = 0; ni < 4; ++ni) {
            int col = w * 64 + ni * 16 + fr;
            xout[(long)row * DMODEL + col] =
                (vres[ni][r] - mean) * rstd * g[col] + beta[col];
        }
    }
}

// ---------------------------------------------------------------------------
// Fused FFN: x = LN(x + relu(x@W1^T+b1)@W2^T + b2) * g + beta
// BM=16, BK=64, unified 32-iter double-buffered W staging; x1 stays in LDS.
// ---------------------------------------------------------------------------
__global__ __launch_bounds__(256) void fused_ffn(
    const float* __restrict__ x,
    const unsigned short* __restrict__ W1,   // [1024][256] bf16
    const float* __restrict__ b1,
    const unsigned short* __restrict__ W2,   // [256][1024] bf16
    const float* __restrict__ b2,
    const float* __restrict__ g,
    const float* __restrict__ beta,
    float* __restrict__ xout)
{
    __shared__ unsigned short sX[16 * 264];
    __shared__ unsigned short x1s[16 * 1032];
    __shared__ unsigned short sW[2][256 * 72];
    __shared__ float redS[4][16];
    __shared__ float redQ[4][16];

    const int tid  = threadIdx.x;
    const int lane = tid & 63;
    const int w    = tid >> 6;
    const int fr   = lane & 15;
    const int ksub = lane >> 4;
    const int m0   = blockIdx.x * 16;

    const int ar = tid >> 3;   // 0..31
    const int ac = tid & 7;

    // stage x tile (16x256) as bf16 once
    #pragma unroll
    for (int j = 0; j < 2; ++j) {
        int s = tid + j * 256;
        int row = s >> 5, c8 = s & 31;
        const float* xp = &x[(long)(m0 + row) * DMODEL + c8 * 8];
        float4 a0 = *(const float4*)xp;
        float4 a1 = *(const float4*)(xp + 4);
        *(u16x8*)&sX[row * 264 + c8 * 8] = cvt8(a0, a1);
    }

    u16x8 wreg[8];
    f32x4 acc[4] = {};

    // prologue stage t=0 (W1 chunk nc=0, kq=0)
    #pragma unroll
    for (int j = 0; j < 8; ++j)
        wreg[j] = *(const u16x8*)&W1[(long)(ar + j * 32) * DMODEL + ac * 8];
    #pragma unroll
    for (int j = 0; j < 8; ++j)
        *(u16x8*)&sW[0][(ar + j * 32) * 72 + ac * 8] = wreg[j];
    __syncthreads();

    for (int t = 0; t < 32; ++t) {
        if (t < 31) {
            int tn = t + 1;
            #pragma unroll
            for (int j = 0; j < 8; ++j) {
                int row = ar + j * 32;
                const unsigned short* src;
                if (tn < 16) {
                    int nc = tn >> 2, kq = tn & 3;
                    src = &W1[(long)(nc * 256 + row) * DMODEL + kq * 64 + ac * 8];
                } else {
                    int tt = tn - 16;
                    src = &W2[(long)row * 1024 + tt * 64 + ac * 8];
                }
                wreg[j] = *(const u16x8*)src;
            }
        }
        const int buf = t & 1;
        #pragma unroll
        for (int kk = 0; kk < 2; ++kk) {
            bf16x8 af;
            if (t < 16) {
                int kq = t & 3;
                af = *(bf16x8*)&sX[fr * 264 + kq * 64 + kk * 32 + ksub * 8];
            } else {
                int tt = t - 16;
                af = *(bf16x8*)&x1s[fr * 1032 + tt * 64 + kk * 32 + ksub * 8];
            }
            #pragma unroll
            for (int ni = 0; ni < 4; ++ni) {
                bf16x8 bf = *(bf16x8*)&sW[buf][(w * 64 + ni * 16 + fr) * 72 + kk * 32 + ksub * 8];
                acc[ni] = __builtin_amdgcn_mfma_f32_16x16x32_bf16(af, bf, acc[ni], 0, 0, 0);
            }
        }
        if (t < 16 && (t & 3) == 3) {
            // finish ff1 chunk: bias + relu -> x1s (bf16)
            int nc = t >> 2;
            #pragma unroll
            for (int ni = 0; ni < 4; ++ni) {
                int col = nc * 256 + w * 64 + ni * 16 + fr;
                float bv = b1[col];
                #pragma unroll
                for (int r = 0; r < 4; ++r)
                    x1s[(ksub * 4 + r) * 1032 + col] =
                        f32_to_bf16_rne(fmaxf(acc[ni][r] + bv, 0.f));
                acc[ni] = (f32x4){};
            }
        }
        __syncthreads();
        if (t < 31) {
            const int nb = (t + 1) & 1;
            #pragma unroll
            for (int j = 0; j < 8; ++j)
                *(u16x8*)&sW[nb][(ar + j * 32) * 72 + ac * 8] = wreg[j];
            __syncthreads();
        }
    }

    // ---- epilogue: + b2 + residual, LN ----
    float vres[4][4];
    #pragma unroll
    for (int ni = 0; ni < 4; ++ni) {
        int col = w * 64 + ni * 16 + fr;
        float bv = b2[col];
        #pragma unroll
        for (int r = 0; r < 4; ++r) {
            int row = m0 + ksub * 4 + r;
            vres[ni][r] = acc[ni][r] + bv + x[(long)row * DMODEL + col];
        }
    }

    #pragma unroll
    for (int r = 0; r < 4; ++r) {
        float s = 0.f, qq = 0.f;
        #pragma unroll
        for (int ni = 0; ni < 4; ++ni) {
            s  += vres[ni][r];
            qq += vres[ni][r] * vres[ni][r];
        }
        #pragma unroll
        for (int mask = 1; mask < 16; mask <<= 1) {
            s  += __shfl_xor(s, mask);
            qq += __shfl_xor(qq, mask);
        }
        if (fr == 0) {
            redS[w][ksub * 4 + r] = s;
            redQ[w][ksub * 4 + r] = qq;
        }
    }
    __syncthreads();

    #pragma unroll
    for (int r = 0; r < 4; ++r) {
        int rl = ksub * 4 + r;
        float sum  = redS[0][rl] + redS[1][rl] + redS[2][rl] + redS[3][rl];
        float sumq = redQ[0][rl] + redQ[1][rl] + redQ[2][rl] + redQ[3][rl];
        float mean = sum * (1.f / 256.f);
        float var  = sumq * (1.f / 256.f) - mean * mean;
        float rstd = rsqrtf(var + 1e-5f);
        int row = m0 + rl;
        #pragma unroll
        for (int ni = 0; ni < 4; ++ni) {
            int col = w * 64 + ni * 16 + fr;
            xout[(long)row * DMODEL + col] =
                (vres[ni][r] - mean) * rstd * g[col] + beta[col];
        }
    }
}

// ===========================================================================
// Fallback (fp32) path kernels — used only if ws is too small.
// ===========================================================================
__global__ __launch_bounds__(256) void embed_kernel(
    const int* __restrict__ word_idx,
    const int* __restrict__ ngram_idx,
    const float* __restrict__ fc1_w,
    const float* __restrict__ fc1_b,
    const float* __restrict__ fc2_w,
    const float* __restrict__ fc2_b,
    float* __restrict__ x)
{
    __shared__ int   feats[8][8];
    __shared__ int   nf[8];
    __shared__ float x1[8][FFDIM];

    const int t0  = blockIdx.x * 8;
    const int tid = threadIdx.x;

    if (tid < 8) {
        int t = t0 + tid;
        int cnt = 0;
        feats[tid][cnt++] = word_idx[t];
        for (int k = 0; k < 6; ++k) {
            int f = WORDC + ngram_idx[t * 6 + k];
            bool dup = false;
            for (int s = 1; s < cnt; ++s)
                if (feats[tid][s] == f) dup = true;
            if (!dup) feats[tid][cnt++] = f;
        }
        nf[tid] = cnt;
    }
    __syncthreads();

    for (int it = 0; it < 16; ++it) {
        int item = it * 256 + tid;
        int tt = item >> 9;
        int j  = item & 511;
        float acc = fc1_b[j];
        int n = nf[tt];
        const float* rowbase = fc1_w + (long)j * F_TOT;
        for (int s = 0; s < n; ++s)
            acc += rowbase[feats[tt][s]];
        x1[tt][j] = fmaxf(acc, 0.f);
    }
    __syncthreads();

    const int d = tid;
    float acc[8];
    float bb = fc2_b[d];
    #pragma unroll
    for (int tt = 0; tt < 8; ++tt) acc[tt] = bb;
    const float* wrow = fc2_w + d * FFDIM;
    for (int k = 0; k < FFDIM; ++k) {
        float wv = wrow[k];
        #pragma unroll
        for (int tt = 0; tt < 8; ++tt) acc[tt] += wv * x1[tt][k];
    }
    #pragma unroll
    for (int tt = 0; tt < 8; ++tt)
        x[(t0 + tt) * DMODEL + d] = acc[tt];
}

template<bool RELU>
__global__ __launch_bounds__(256) void gemm_bias(
    const float* __restrict__ A,
    const float* __restrict__ W,
    const float* __restrict__ bias,
    float* __restrict__ C,
    int M, int N, int K)
{
    __shared__ float sA[16][64];
    __shared__ float sW[16][64];

    const int tid = threadIdx.x;
    const int tx = tid & 15;
    const int ty = tid >> 4;
    const int m0 = blockIdx.y * 64;
    const int n0 = blockIdx.x * 64;

    const int lr = tid >> 2;
    const int lc = tid & 3;

    float acc[4][4] = {};

    for (int k0 = 0; k0 < K; k0 += 16) {
        float4 av = *(const float4*)&A[(long)(m0 + lr) * K + k0 + lc * 4];
        float4 wv = *(const float4*)&W[(long)(n0 + lr) * K + k0 + lc * 4];
        __syncthreads();
        sA[lc * 4 + 0][lr] = av.x; sA[lc * 4 + 1][lr] = av.y;
        sA[lc * 4 + 2][lr] = av.z; sA[lc * 4 + 3][lr] = av.w;
        sW[lc * 4 + 0][lr] = wv.x; sW[lc * 4 + 1][lr] = wv.y;
        sW[lc * 4 + 2][lr] = wv.z; sW[lc * 4 + 3][lr] = wv.w;
        __syncthreads();
        #pragma unroll
        for (int k = 0; k < 16; ++k) {
            float4 a4 = *(const float4*)&sA[k][ty * 4];
            float4 b4 = *(const float4*)&sW[k][tx * 4];
            float am[4] = {a4.x, a4.y, a4.z, a4.w};
            float bn[4] = {b4.x, b4.y, b4.z, b4.w};
            #pragma unroll
            for (int i = 0; i < 4; ++i)
                #pragma unroll
                for (int j = 0; j < 4; ++j)
                    acc[i][j] += am[i] * bn[j];
        }
    }

    float4 bv = *(const float4*)&bias[n0 + tx * 4];
    #pragma unroll
    for (int i = 0; i < 4; ++i) {
        int m = m0 + ty * 4 + i;
        float4 o;
        o.x = acc[i][0] + bv.x;
        o.y = acc[i][1] + bv.y;
        o.z = acc[i][2] + bv.z;
        o.w = acc[i][3] + bv.w;
        if (RELU) {
            o.x = fmaxf(o.x, 0.f); o.y = fmaxf(o.y, 0.f);
            o.z = fmaxf(o.z, 0.f); o.w = fmaxf(o.w, 0.f);
        }
        *(float4*)&C[(long)m * N + n0 + tx * 4] = o;
    }
}

__global__ __launch_bounds__(256) void attn_kernel(
    const float* __restrict__ qkv,
    float* __restrict__ o)
{
    const int b = blockIdx.x >> 3;
    const int h = blockIdx.x & 7;
    const int tid = threadIdx.x;
    const int q = tid >> 2;
    const int p = tid & 3;

    __shared__ float Kt[SEQL][HDIM + 1];
    __shared__ float Vt[SEQL][HDIM + 1];
    __shared__ float S[SEQL][SEQL + 1];

    const float scale = 0.17677669529663687f;

    {
        int fidx = tid * 2;
        int row  = fidx >> 3;
        int c    = (fidx & 7) * 4;
        const float* kb = qkv + (long)(b * SEQL + row) * 768 + 256 + h * HDIM + c;
        float4 k0 = *(const float4*)kb;
        float4 k1 = *(const float4*)(kb + 4);
        float4 v0 = *(const float4*)(kb + 256);
        float4 v1 = *(const float4*)(kb + 260);
        *(float4*)&Kt[row][c]     = k0;
        *(float4*)&Kt[row][c + 4] = k1;
        *(float4*)&Vt[row][c]     = v0;
        *(float4*)&Vt[row][c + 4] = v1;
    }

    float qreg[HDIM];
    {
        const float* qb = qkv + (long)(b * SEQL + q) * 768 + h * HDIM;
        #pragma unroll
        for (int c = 0; c < HDIM / 4; ++c) {
            float4 v = *(const float4*)(qb + c * 4);
            qreg[c * 4 + 0] = v.x * scale;
            qreg[c * 4 + 1] = v.y * scale;
            qreg[c * 4 + 2] = v.z * scale;
            qreg[c * 4 + 3] = v.w * scale;
        }
    }
    __syncthreads();

    float sc[16];
    float mx = -1e30f;
    #pragma unroll
    for (int i = 0; i < 16; ++i) {
        int jj = p * 16 + i;
        float s = 0.f;
        #pragma unroll
        for (int d = 0; d < HDIM; ++d) s += qreg[d] * Kt[jj][d];
        sc[i] = s;
        mx = fmaxf(mx, s);
    }
    mx = fmaxf(mx, __shfl_xor(mx, 1));
    mx = fmaxf(mx, __shfl_xor(mx, 2));

    float sum = 0.f;
    #pragma unroll
    for (int i = 0; i < 16; ++i) {
        float e = __expf(sc[i] - mx);
        S[q][p * 16 + i] = e;
        sum += e;
    }
    sum += __shfl_xor(sum, 1);
    sum += __shfl_xor(sum, 2);
    const float inv = 1.f / sum;
    __syncthreads();

    float acc[8] = {};
    for (int jj = 0; jj < SEQL; ++jj) {
        float pv = S[q][jj];
        #pragma unroll
        for (int d = 0; d < 8; ++d) acc[d] += pv * Vt[jj][p * 8 + d];
    }
    float* orow = o + (long)(b * SEQL + q) * DMODEL + h * HDIM + p * 8;
    float4 o0, o1;
    o0.x = acc[0] * inv; o0.y = acc[1] * inv; o0.z = acc[2] * inv; o0.w = acc[3] * inv;
    o1.x = acc[4] * inv; o1.y = acc[5] * inv; o1.z = acc[6] * inv; o1.w = acc[7] * inv;
    *(float4*)orow = o0;
    *(float4*)(orow + 4) = o1;
}

__global__ __launch_bounds__(256) void add_ln_kernel(
    const float* __restrict__ xin,
    const float* __restrict__ f,
    const float* __restrict__ g,
    const float* __restrict__ bta,
    float* __restrict__ xout)
{
    const int w = threadIdx.x >> 6;
    const int lane = threadIdx.x & 63;
    const int t = blockIdx.x * 4 + w;

    float4 xv = *(const float4*)&xin[(long)t * DMODEL + lane * 4];
    float4 fv = *(const float4*)&f[(long)t * DMODEL + lane * 4];
    float v0 = xv.x + fv.x, v1 = xv.y + fv.y, v2 = xv.z + fv.z, v3 = xv.w + fv.w;

    float s  = v0 + v1 + v2 + v3;
    float sq = v0 * v0 + v1 * v1 + v2 * v2 + v3 * v3;
    #pragma unroll
    for (int off = 1; off < 64; off <<= 1) {
        s  += __shfl_xor(s, off);
        sq += __shfl_xor(sq, off);
    }
    float mean = s * (1.f / 256.f);
    float var  = sq * (1.f / 256.f) - mean * mean;
    float rs   = rsqrtf(var + 1e-5f);

    float4 gv = *(const float4*)&g[lane * 4];
    float4 bv = *(const float4*)&bta[lane * 4];
    float4 o;
    o.x = (v0 - mean) * rs * gv.x + bv.x;
    o.y = (v1 - mean) * rs * gv.y + bv.y;
    o.z = (v2 - mean) * rs * gv.z + bv.z;
    o.w = (v3 - mean) * rs * gv.w + bv.w;
    *(float4*)&xout[(long)t * DMODEL + lane * 4] = o;
}

// ---------------------------------------------------------------------------
extern "C" void kernel_launch(void* const* d_in, const int* in_sizes, int n_in,
                              void* d_out, int out_size, void* d_ws, size_t ws_size,
                              hipStream_t stream) {
    const int*   word_idx  = (const int*)d_in[0];
    const int*   ngram_idx = (const int*)d_in[1];
    const float* fc1_w = (const float*)d_in[2];
    const float* fc1_b = (const float*)d_in[3];
    const float* fc2_w = (const float*)d_in[4];
    const float* fc2_b = (const float*)d_in[5];
    const float* qkv_w = (const float*)d_in[6];
    const float* qkv_b = (const float*)d_in[7];
    const float* out_w = (const float*)d_in[8];
    const float* out_b = (const float*)d_in[9];
    const float* ln1_g = (const float*)d_in[10];
    const float* ln1_b = (const float*)d_in[11];
    const float* ff1_w = (const float*)d_in[12];
    const float* ff1_b = (const float*)d_in[13];
    const float* ff2_w = (const float*)d_in[14];
    const float* ff2_b = (const float*)d_in[15];
    const float* ln2_g = (const float*)d_in[16];
    const float* ln2_b = (const float*)d_in[17];

    float* x = (float*)d_out;  // [2048][256]

    const size_t BM_OFF   = 0;
    const size_t FC1T_OFF = 10240;
    const size_t FC1T_BYTES = (size_t)F_TOT * FFDIM * 2;
    const size_t QKVT_OFF = FC1T_OFF + FC1T_BYTES;
    const size_t QKVT_BYTES = (size_t)2 * 768 * 256 * 2;
    const size_t OUTT_OFF = QKVT_OFF + QKVT_BYTES;
    const size_t OUTT_BYTES = (size_t)2 * 256 * 256 * 2;
    const size_t FF1T_OFF = OUTT_OFF + OUTT_BYTES;
    const size_t FF1T_BYTES = (size_t)2 * 1024 * 256 * 2;
    const size_t FF2T_OFF = FF1T_OFF + FF1T_BYTES;
    const size_t FF2T_BYTES = (size_t)2 * 256 * 1024 * 2;
    const size_t ATTN_OFF = FF2T_OFF + FF2T_BYTES;
    const size_t ATTN_BYTES = (size_t)NTOK * DMODEL * 4;
    const size_t FAST_BYTES = ATTN_OFF + ATTN_BYTES;

    if (ws_size >= FAST_BYTES) {
        unsigned int*   bm   = (unsigned int*)((char*)d_ws + BM_OFF);
        unsigned short* fc1T = (unsigned short*)((char*)d_ws + FC1T_OFF);
        unsigned short* qkvT = (unsigned short*)((char*)d_ws + QKVT_OFF);
        unsigned short* outT = (unsigned short*)((char*)d_ws + OUTT_OFF);
        unsigned short* ff1T = (unsigned short*)((char*)d_ws + FF1T_OFF);
        unsigned short* ff2T = (unsigned short*)((char*)d_ws + FF2T_OFF);
        float* attn_raw = (float*)((char*)d_ws + ATTN_OFF);

        mark_feats<<<1, 256, 0, stream>>>(word_idx, ngram_idx, bm);
        transpose_cvt<<<10192, 256, 0, stream>>>(
            fc1_w, fc1T, bm, qkv_w, out_w, ff1_w, ff2_w, qkvT, outT, ff1T, ff2T);
        embed_gather<<<NTOK / 8, 256, 0, stream>>>(word_idx, ngram_idx, fc1T,
                                                   fc1_b, fc2_w, fc2_b, x);

        for (int i = 0; i < 2; ++i) {
            fused_qkv_attn<<<32 * NHEAD, 256, 0, stream>>>(
                x, qkvT + (long)i * 768 * 256, qkv_b + i * 768, attn_raw);

            gemm_ln<<<NTOK / 16, 256, 0, stream>>>(
                attn_raw, outT + (long)i * 256 * 256, out_b + i * 256,
                x, ln1_g + i * 256, ln1_b + i * 256, x);

            fused_ffn<<<NTOK / 16, 256, 0, stream>>>(
                x, ff1T + (long)i * 1024 * 256, ff1_b + i * 1024,
                ff2T + (long)i * 256 * 1024, ff2_b + i * 256,
                ln2_g + i * 256, ln2_b + i * 256, x);
        }
    } else {
        float* wsf      = (float*)d_ws;
        float* qkvbuf   = wsf;
        float* attn_raw = qkvbuf + 2048 * 768;
        float* obuf     = attn_raw + 2048 * 256;
        float* ffbuf    = obuf + 2048 * 256;

        embed_kernel<<<NTOK / 8, 256, 0, stream>>>(word_idx, ngram_idx, fc1_w,
                                                   fc1_b, fc2_w, fc2_b, x);
        for (int i = 0; i < 2; ++i) {
            gemm_bias<false><<<dim3(768 / 64, NTOK / 64), 256, 0, stream>>>(
                x, qkv_w + (long)i * 768 * 256, qkv_b + i * 768, qkvbuf,
                NTOK, 768, 256);
            attn_kernel<<<32 * NHEAD, 256, 0, stream>>>(qkvbuf, attn_raw);
            gemm_bias<false><<<dim3(256 / 64, NTOK / 64), 256, 0, stream>>>(
                attn_raw, out_w + (long)i * 256 * 256, out_b + i * 256, obuf,
                NTOK, 256, 256);
            add_ln_kernel<<<NTOK / 4, 256, 0, stream>>>(x, obuf, ln1_g + i * 256,
                                                        ln1_b + i * 256, x);
            gemm_bias<true><<<dim3(1024 / 64, NTOK / 64), 256, 0, stream>>>(
                x, ff1_w + (long)i * 1024 * 256, ff1_b + i * 1024, ffbuf,
                NTOK, 1024, 256);
            gemm_bias<false><<<dim3(256 / 64, NTOK / 64), 256, 0, stream>>>(
                ffbuf, ff2_w + (long)i * 256 * 1024, ff2_b + i * 256, obuf,
                NTOK, 256, 1024);
            add_ln_kernel<<<NTOK / 4, 256, 0, stream>>>(x, obuf, ln2_g + i * 256,
                                                        ln2_b + i * 256, x);
        }
    }
}

// Round 7
// 157.628 us; speedup vs baseline: 2.6319x; 1.0582x over previous
//
#include <hip/hip_runtime.h>
#include <hip/hip_bf16.h>
#include <math.h>

#define WORDC 30000
#define F_TOT 80000
#define NTOK  2048
#define DMODEL 256
#define FFDIM 512
#define NHEAD 8
#define HDIM  32
#define SEQL  64

typedef __attribute__((ext_vector_type(8))) short bf16x8;
typedef __attribute__((ext_vector_type(8))) unsigned short u16x8;
typedef __attribute__((ext_vector_type(4))) float f32x4;

__device__ __forceinline__ unsigned short f32_to_bf16_rne(float x) {
    unsigned int u = __float_as_uint(x);
    unsigned int r = (u + 0x7FFFu + ((u >> 16) & 1u)) >> 16;
    return (unsigned short)r;
}

__device__ __forceinline__ u16x8 cvt8(float4 a, float4 b) {
    u16x8 v;
    v[0] = f32_to_bf16_rne(a.x); v[1] = f32_to_bf16_rne(a.y);
    v[2] = f32_to_bf16_rne(a.z); v[3] = f32_to_bf16_rne(a.w);
    v[4] = f32_to_bf16_rne(b.x); v[5] = f32_to_bf16_rne(b.y);
    v[6] = f32_to_bf16_rne(b.z); v[7] = f32_to_bf16_rne(b.w);
    return v;
}

// ---------------------------------------------------------------------------
// Build bitmap of used features (word + ngram), one block.
// ---------------------------------------------------------------------------
__global__ __launch_bounds__(256) void mark_feats(
    const int* __restrict__ word_idx,
    const int* __restrict__ ngram_idx,
    unsigned int* __restrict__ bm)
{
    __shared__ unsigned int lbm[2500];
    const int tid = threadIdx.x;
    for (int i = tid; i < 2500; i += 256) lbm[i] = 0u;
    __syncthreads();
    for (int j = tid; j < NTOK; j += 256) {
        int f = word_idx[j];
        atomicOr(&lbm[f >> 5], 1u << (f & 31));
    }
    for (int j = tid; j < NTOK * 6; j += 256) {
        int f = WORDC + ngram_idx[j];
        atomicOr(&lbm[f >> 5], 1u << (f & 31));
    }
    __syncthreads();
    for (int i = tid; i < 2500; i += 256) bm[i] = lbm[i];
}

// ---------------------------------------------------------------------------
// Transpose fc1_w (store-pruned by bitmap) + cvt transformer weights.
// ---------------------------------------------------------------------------
__global__ __launch_bounds__(256) void transpose_cvt(
    const float* __restrict__ fc1_w,
    unsigned short* __restrict__ fc1T,
    const unsigned int* __restrict__ bm,
    const float* __restrict__ s0, const float* __restrict__ s1,
    const float* __restrict__ s2, const float* __restrict__ s3,
    unsigned short* __restrict__ d0, unsigned short* __restrict__ d1,
    unsigned short* __restrict__ d2, unsigned short* __restrict__ d3)
{
    __shared__ float tile[64][65];
    const int bid = blockIdx.x;
    const int tid = threadIdx.x;

    if (bid < 10000) {
        const int f0 = (bid % 1250) * 64;
        const int j0 = (bid / 1250) * 64;

        const int fr = (tid & 15) * 4;
        const int jr = tid >> 4;
        #pragma unroll
        for (int p = 0; p < 4; ++p) {
            int j = j0 + p * 16 + jr;
            float4 v = *(const float4*)&fc1_w[(long)j * F_TOT + f0 + fr];
            tile[fr + 0][p * 16 + jr] = v.x;
            tile[fr + 1][p * 16 + jr] = v.y;
            tile[fr + 2][p * 16 + jr] = v.z;
            tile[fr + 3][p * 16 + jr] = v.w;
        }
        __syncthreads();

        const int jc  = (tid & 15) * 4;
        const int fr2 = tid >> 4;
        #pragma unroll
        for (int p = 0; p < 4; ++p) {
            int fi = p * 16 + fr2;
            int f  = f0 + fi;
            if ((bm[f >> 5] >> (f & 31)) & 1u) {
                ushort4 o;
                o.x = f32_to_bf16_rne(tile[fi][jc + 0]);
                o.y = f32_to_bf16_rne(tile[fi][jc + 1]);
                o.z = f32_to_bf16_rne(tile[fi][jc + 2]);
                o.w = f32_to_bf16_rne(tile[fi][jc + 3]);
                *(ushort4*)&fc1T[(long)f * FFDIM + j0 + jc] = o;
            }
        }
    } else {
        int s = bid - 10000;
        int ten = s / 48, b48 = s % 48;
        const float* src; unsigned short* dst; int n4;
        switch (ten) {
            case 0:  src = s0; dst = d0; n4 = 2 * 768 * 256 / 4;  break;
            case 1:  src = s1; dst = d1; n4 = 2 * 256 * 256 / 4;  break;
            case 2:  src = s2; dst = d2; n4 = 2 * 1024 * 256 / 4; break;
            default: src = s3; dst = d3; n4 = 2 * 256 * 1024 / 4; break;
        }
        for (int i = b48 * 256 + tid; i < n4; i += 48 * 256) {
            float4 v = ((const float4*)src)[i];
            ushort4 o;
            o.x = f32_to_bf16_rne(v.x);
            o.y = f32_to_bf16_rne(v.y);
            o.z = f32_to_bf16_rne(v.z);
            o.w = f32_to_bf16_rne(v.w);
            ((ushort4*)dst)[i] = o;
        }
    }
}

// ---------------------------------------------------------------------------
// Gather path: dedupe -> sum bf16 rows of fc1T -> relu -> fc2
// ---------------------------------------------------------------------------
__global__ __launch_bounds__(256) void embed_gather(
    const int* __restrict__ word_idx,
    const int* __restrict__ ngram_idx,
    const unsigned short* __restrict__ fc1_wT,
    const float* __restrict__ fc1_b,
    const float* __restrict__ fc2_w,
    const float* __restrict__ fc2_b,
    float* __restrict__ x)
{
    __shared__ int   feats[8][8];
    __shared__ int   nf[8];
    __shared__ float x1[8][FFDIM];

    const int t0  = blockIdx.x * 8;
    const int tid = threadIdx.x;

    if (tid < 8) {
        int t = t0 + tid;
        int cnt = 0;
        feats[tid][cnt++] = word_idx[t];
        for (int k = 0; k < 6; ++k) {
            int f = WORDC + ngram_idx[t * 6 + k];
            bool dup = false;
            for (int s = 1; s < cnt; ++s)
                if (feats[tid][s] == f) dup = true;
            if (!dup) feats[tid][cnt++] = f;
        }
        nf[tid] = cnt;
    }
    __syncthreads();

    const float2 bb = *(const float2*)&fc1_b[tid * 2];
    #pragma unroll
    for (int tt = 0; tt < 8; ++tt) {
        float a0 = bb.x, a1 = bb.y;
        int n = nf[tt];
        for (int s = 0; s < n; ++s) {
            unsigned int wrd = *(const unsigned int*)
                &fc1_wT[(long)feats[tt][s] * FFDIM + tid * 2];
            a0 += __uint_as_float((wrd & 0xFFFFu) << 16);
            a1 += __uint_as_float(wrd & 0xFFFF0000u);
        }
        x1[tt][tid * 2 + 0] = fmaxf(a0, 0.f);
        x1[tt][tid * 2 + 1] = fmaxf(a1, 0.f);
    }
    __syncthreads();

    const int d = tid;
    float acc[8];
    float cb = fc2_b[d];
    #pragma unroll
    for (int tt = 0; tt < 8; ++tt) acc[tt] = cb;
    const float* wrow = fc2_w + d * FFDIM;
    for (int k = 0; k < FFDIM; ++k) {
        float wv = wrow[k];
        #pragma unroll
        for (int tt = 0; tt < 8; ++tt) acc[tt] += wv * x1[tt][k];
    }
    #pragma unroll
    for (int tt = 0; tt < 8; ++tt)
        x[(t0 + tt) * DMODEL + d] = acc[tt];
}

// ---------------------------------------------------------------------------
// Fused per-(b,h) QKV GEMM + MFMA attention. 512 threads / 8 waves.
// A staged once (64x256 bf16); W staged wave-private (no barriers in k-loop).
// Wave (rg,ch): rg = 16-row group, ch = 48-col half of the 96 QKV cols.
// ---------------------------------------------------------------------------
__global__ __launch_bounds__(512) void fused_qkv_attn(
    const float* __restrict__ x,
    const unsigned short* __restrict__ Wq,  // layer qkvT [768][256]
    const float* __restrict__ bq,
    float* __restrict__ o)
{
    __shared__ unsigned short sA[64 * 264];
    __shared__ unsigned short sWp[8][48 * 72];
    __shared__ unsigned short sQ[64 * 40];
    __shared__ unsigned short sK[64 * 40];
    __shared__ unsigned short sVt[32 * 72];
    __shared__ unsigned short sP[64 * 72];
    __shared__ float sfmx[2][64];
    __shared__ float sfsm[2][64];

    const int b = blockIdx.x >> 3;
    const int h = blockIdx.x & 7;
    const int tid  = threadIdx.x;
    const int lane = tid & 63;
    const int w    = tid >> 6;          // 0..7
    const int rg   = w & 3;             // query-row group
    const int ch   = w >> 2;            // col half
    const int fr   = lane & 15;
    const int ksub = lane >> 4;
    const int row0 = b * SEQL;

    // ---- stage whole A tile (64x256) as bf16, 4 chunks/thread ----
    #pragma unroll
    for (int j = 0; j < 4; ++j) {
        int c = j * 512 + tid;
        int row = c >> 5, c8 = c & 31;
        const float* ap = &x[(long)(row0 + row) * DMODEL + c8 * 8];
        float4 a0 = *(const float4*)ap;
        float4 a1 = *(const float4*)(ap + 4);
        *(u16x8*)&sA[row * 264 + c8 * 8] = cvt8(a0, a1);
    }

    // wave-private W chunk mapping: 48 rows x 8 chunks = 384 -> 6/lane
    int lr6[6], grow6[6];
    const int wcc = (lane & 7) * 8;
    #pragma unroll
    for (int j = 0; j < 6; ++j) {
        int lr = j * 8 + (lane >> 3);
        lr6[j] = lr;
        int c = ch * 48 + lr;
        grow6[j] = (c >> 5) * 256 + h * HDIM + (c & 31);
    }
    u16x8 wc[6], wn[6];
    #pragma unroll
    for (int j = 0; j < 6; ++j)
        wc[j] = *(const u16x8*)&Wq[(long)grow6[j] * DMODEL + wcc];

    __syncthreads();   // sA ready

    f32x4 acc[3] = {};
    for (int t = 0; t < 4; ++t) {
        #pragma unroll
        for (int j = 0; j < 6; ++j)
            *(u16x8*)&sWp[w][lr6[j] * 72 + wcc] = wc[j];
        if (t < 3) {
            int k0 = (t + 1) * 64;
            #pragma unroll
            for (int j = 0; j < 6; ++j)
                wn[j] = *(const u16x8*)&Wq[(long)grow6[j] * DMODEL + k0 + wcc];
        }
        #pragma unroll
        for (int kk = 0; kk < 2; ++kk) {
            bf16x8 af = *(bf16x8*)&sA[(rg * 16 + fr) * 264 + t * 64 + kk * 32 + ksub * 8];
            #pragma unroll
            for (int ni = 0; ni < 3; ++ni) {
                bf16x8 bf = *(bf16x8*)&sWp[w][(ni * 16 + fr) * 72 + kk * 32 + ksub * 8];
                acc[ni] = __builtin_amdgcn_mfma_f32_16x16x32_bf16(af, bf, acc[ni], 0, 0, 0);
            }
        }
        if (t < 3) {
            #pragma unroll
            for (int j = 0; j < 6; ++j) wc[j] = wn[j];
        }
    }

    // ---- scatter Q, K, V^T into bf16 LDS tiles ----
    const float scale = 0.17677669529663687f;   // 1/sqrt(32)
    #pragma unroll
    for (int ni = 0; ni < 3; ++ni) {
        int c = ch * 48 + ni * 16 + fr;
        int part = c >> 5, pc = c & 31;
        float bv = bq[part * 256 + h * HDIM + pc];
        #pragma unroll
        for (int r = 0; r < 4; ++r) {
            int row = rg * 16 + ksub * 4 + r;
            float v = acc[ni][r] + bv;
            if (part == 0)      sQ[row * 40 + pc] = f32_to_bf16_rne(v * scale);
            else if (part == 1) sK[row * 40 + pc] = f32_to_bf16_rne(v);
            else                sVt[pc * 72 + row] = f32_to_bf16_rne(v);
        }
    }
    __syncthreads();

    // ---- S = Q K^T: wave (rg,ch) -> rows rg*16, k-cols ch*32 (2 ni) ----
    f32x4 s4[2];
    {
        bf16x8 afq = *(bf16x8*)&sQ[(rg * 16 + fr) * 40 + ksub * 8];
        #pragma unroll
        for (int ni = 0; ni < 2; ++ni) {
            bf16x8 bfk = *(bf16x8*)&sK[(ch * 32 + ni * 16 + fr) * 40 + ksub * 8];
            f32x4 z = {};
            s4[ni] = __builtin_amdgcn_mfma_f32_16x16x32_bf16(afq, bfk, z, 0, 0, 0);
        }
    }

    // ---- softmax with 2-way cross-wave (col-half) reduce ----
    #pragma unroll
    for (int r = 0; r < 4; ++r) {
        float m = fmaxf(s4[0][r], s4[1][r]);
        m = fmaxf(m, __shfl_xor(m, 1));
        m = fmaxf(m, __shfl_xor(m, 2));
        m = fmaxf(m, __shfl_xor(m, 4));
        m = fmaxf(m, __shfl_xor(m, 8));
        if (fr == 0) sfmx[ch][rg * 16 + ksub * 4 + r] = m;
    }
    __syncthreads();
    float minv[4];
    #pragma unroll
    for (int r = 0; r < 4; ++r) {
        int row = rg * 16 + ksub * 4 + r;
        float m = fmaxf(sfmx[0][row], sfmx[1][row]);
        float p0 = __expf(s4[0][r] - m);
        float p1 = __expf(s4[1][r] - m);
        sP[row * 72 + ch * 32 + fr]      = f32_to_bf16_rne(p0);
        sP[row * 72 + ch * 32 + 16 + fr] = f32_to_bf16_rne(p1);
        float s = p0 + p1;
        s += __shfl_xor(s, 1);
        s += __shfl_xor(s, 2);
        s += __shfl_xor(s, 4);
        s += __shfl_xor(s, 8);
        if (fr == 0) sfsm[ch][row] = s;
    }
    __syncthreads();
    #pragma unroll
    for (int r = 0; r < 4; ++r) {
        int row = rg * 16 + ksub * 4 + r;
        minv[r] = 1.f / (sfsm[0][row] + sfsm[1][row]);
    }

    // ---- O = P V: wave -> rows rg*16, out-cols ch*16 ----
    f32x4 o4 = {};
    #pragma unroll
    for (int kc = 0; kc < 2; ++kc) {
        bf16x8 afp = *(bf16x8*)&sP[(rg * 16 + fr) * 72 + kc * 32 + ksub * 8];
        bf16x8 bfv = *(bf16x8*)&sVt[(ch * 16 + fr) * 72 + kc * 32 + ksub * 8];
        o4 = __builtin_amdgcn_mfma_f32_16x16x32_bf16(afp, bfv, o4, 0, 0, 0);
    }
    #pragma unroll
    for (int r = 0; r < 4; ++r) {
        int row = row0 + rg * 16 + ksub * 4 + r;
        o[(long)row * DMODEL + h * HDIM + ch * 16 + fr] = o4[r] * minv[r];
    }
}

// ---------------------------------------------------------------------------
// Fused GEMM + residual + LayerNorm (out-proj). BM=8, grid 256, 512 thr.
// A staged once (zero-padded to 16 rows); W wave-private, barrier-free k-loop.
// ---------------------------------------------------------------------------
__global__ __launch_bounds__(512) void gemm_ln(
    const float* __restrict__ A,
    const unsigned short* __restrict__ Wb,
    const float* __restrict__ bias,
    const float* __restrict__ xres,
    const float* __restrict__ g,
    const float* __restrict__ beta,
    float* __restrict__ xout)
{
    __shared__ unsigned short sA[16 * 264];
    __shared__ unsigned short sWp[8][32 * 72];
    __shared__ float redS[8][8];
    __shared__ float redQ[8][8];

    const int tid  = threadIdx.x;
    const int lane = tid & 63;
    const int w    = tid >> 6;
    const int fr   = lane & 15;
    const int ksub = lane >> 4;
    const int m0   = blockIdx.x * 8;

    // stage A rows 0..7 (bf16), zero rows 8..15
    {
        int row = tid >> 5, c8 = tid & 31;
        if (tid < 256) {
            const float* ap = &A[(long)(m0 + row) * DMODEL + c8 * 8];
            float4 a0 = *(const float4*)ap;
            float4 a1 = *(const float4*)(ap + 4);
            *(u16x8*)&sA[row * 264 + c8 * 8] = cvt8(a0, a1);
        } else {
            u16x8 z = {};
            *(u16x8*)&sA[row * 264 + c8 * 8] = z;
        }
    }

    const int lrb = lane >> 3;
    const int wcc = (lane & 7) * 8;
    u16x8 wc[4], wn[4];
    #pragma unroll
    for (int j = 0; j < 4; ++j)
        wc[j] = *(const u16x8*)&Wb[(long)(w * 32 + j * 8 + lrb) * DMODEL + wcc];

    __syncthreads();

    f32x4 acc[2] = {};
    for (int t = 0; t < 4; ++t) {
        #pragma unroll
        for (int j = 0; j < 4; ++j)
            *(u16x8*)&sWp[w][(j * 8 + lrb) * 72 + wcc] = wc[j];
        if (t < 3) {
            int k0 = (t + 1) * 64;
            #pragma unroll
            for (int j = 0; j < 4; ++j)
                wn[j] = *(const u16x8*)&Wb[(long)(w * 32 + j * 8 + lrb) * DMODEL + k0 + wcc];
        }
        #pragma unroll
        for (int kk = 0; kk < 2; ++kk) {
            bf16x8 af = *(bf16x8*)&sA[fr * 264 + t * 64 + kk * 32 + ksub * 8];
            #pragma unroll
            for (int ni = 0; ni < 2; ++ni) {
                bf16x8 bf = *(bf16x8*)&sWp[w][(ni * 16 + fr) * 72 + kk * 32 + ksub * 8];
                acc[ni] = __builtin_amdgcn_mfma_f32_16x16x32_bf16(af, bf, acc[ni], 0, 0, 0);
            }
        }
        if (t < 3) {
            #pragma unroll
            for (int j = 0; j < 4; ++j) wc[j] = wn[j];
        }
    }

    float vres[2][4];
    #pragma unroll
    for (int ni = 0; ni < 2; ++ni) {
        int col = w * 32 + ni * 16 + fr;
        float bv = bias[col];
        #pragma unroll
        for (int r = 0; r < 4; ++r) {
            int rl = ksub * 4 + r;
            if (rl < 8)
                vres[ni][r] = acc[ni][r] + bv + xres[(long)(m0 + rl) * DMODEL + col];
            else
                vres[ni][r] = 0.f;
        }
    }

    #pragma unroll
    for (int r = 0; r < 4; ++r) {
        float s  = vres[0][r] + vres[1][r];
        float qq = vres[0][r] * vres[0][r] + vres[1][r] * vres[1][r];
        #pragma unroll
        for (int mask = 1; mask < 16; mask <<= 1) {
            s  += __shfl_xor(s, mask);
            qq += __shfl_xor(qq, mask);
        }
        if (fr == 0 && ksub < 2) {
            redS[w][ksub * 4 + r] = s;
            redQ[w][ksub * 4 + r] = qq;
        }
    }
    __syncthreads();

    #pragma unroll
    for (int r = 0; r < 4; ++r) {
        int rl = ksub * 4 + r;
        if (rl < 8) {
            float sum = 0.f, sumq = 0.f;
            #pragma unroll
            for (int ww = 0; ww < 8; ++ww) {
                sum  += redS[ww][rl];
                sumq += redQ[ww][rl];
            }
            float mean = sum * (1.f / 256.f);
            float var  = sumq * (1.f / 256.f) - mean * mean;
            float rstd = rsqrtf(var + 1e-5f);
            #pragma unroll
            for (int ni = 0; ni < 2; ++ni) {
                int col = w * 32 + ni * 16 + fr;
                xout[(long)(m0 + rl) * DMODEL + col] =
                    (vres[ni][r] - mean) * rstd * g[col] + beta[col];
            }
        }
    }
}

// ---------------------------------------------------------------------------
// Fused FFN: x = LN(x + relu(x@W1^T+b1)@W2^T + b2)*g + beta
// BM=16, grid 128, 512 thr / 8 waves; W wave-private; 3 barriers total.
// ---------------------------------------------------------------------------
__global__ __launch_bounds__(512) void fused_ffn(
    const float* __restrict__ x,
    const unsigned short* __restrict__ W1,   // [1024][256] bf16
    const float* __restrict__ b1,
    const unsigned short* __restrict__ W2,   // [256][1024] bf16
    const float* __restrict__ b2,
    const float* __restrict__ g,
    const float* __restrict__ beta,
    float* __restrict__ xout)
{
    __shared__ unsigned short sX[16 * 264];
    __shared__ unsigned short x1s[16 * 1032];
    __shared__ unsigned short sWp[8][32 * 72];
    __shared__ float redS[8][16];
    __shared__ float redQ[8][16];

    const int tid  = threadIdx.x;
    const int lane = tid & 63;
    const int w    = tid >> 6;
    const int fr   = lane & 15;
    const int ksub = lane >> 4;
    const int m0   = blockIdx.x * 16;

    // stage x tile (16x256) bf16, 1 chunk/thread
    {
        int row = tid >> 5, c8 = tid & 31;
        const float* xp = &x[(long)(m0 + row) * DMODEL + c8 * 8];
        float4 a0 = *(const float4*)xp;
        float4 a1 = *(const float4*)(xp + 4);
        *(u16x8*)&sX[row * 264 + c8 * 8] = cvt8(a0, a1);
    }

    const int lrb = lane >> 3;
    const int wcc = (lane & 7) * 8;
    u16x8 wc[4], wn[4];
    #pragma unroll
    for (int j = 0; j < 4; ++j)
        wc[j] = *(const u16x8*)&W1[(long)(w * 32 + j * 8 + lrb) * DMODEL + wcc];

    __syncthreads();

    f32x4 acc[2] = {};
    for (int t = 0; t < 32; ++t) {
        #pragma unroll
        for (int j = 0; j < 4; ++j)
            *(u16x8*)&sWp[w][(j * 8 + lrb) * 72 + wcc] = wc[j];
        if (t < 31) {
            int tn = t + 1;
            if (tn < 16) {
                int nc = tn >> 2, kq = tn & 3;
                #pragma unroll
                for (int j = 0; j < 4; ++j)
                    wn[j] = *(const u16x8*)&W1[(long)(nc * 256 + w * 32 + j * 8 + lrb) * DMODEL
                                               + kq * 64 + wcc];
            } else {
                int tt = tn - 16;
                #pragma unroll
                for (int j = 0; j < 4; ++j)
                    wn[j] = *(const u16x8*)&W2[(long)(w * 32 + j * 8 + lrb) * 1024
                                               + tt * 64 + wcc];
            }
        }
        #pragma unroll
        for (int kk = 0; kk < 2; ++kk) {
            bf16x8 af;
            if (t < 16)
                af = *(bf16x8*)&sX[fr * 264 + (t & 3) * 64 + kk * 32 + ksub * 8];
            else
                af = *(bf16x8*)&x1s[fr * 1032 + (t - 16) * 64 + kk * 32 + ksub * 8];
            #pragma unroll
            for (int ni = 0; ni < 2; ++ni) {
                bf16x8 bf = *(bf16x8*)&sWp[w][(ni * 16 + fr) * 72 + kk * 32 + ksub * 8];
                acc[ni] = __builtin_amdgcn_mfma_f32_16x16x32_bf16(af, bf, acc[ni], 0, 0, 0);
            }
        }
        if (t < 16 && (t & 3) == 3) {
            int nc = t >> 2;
            #pragma unroll
            for (int ni = 0; ni < 2; ++ni) {
                int col = nc * 256 + w * 32 + ni * 16 + fr;
                float bv = b1[col];
                #pragma unroll
                for (int r = 0; r < 4; ++r)
                    x1s[(ksub * 4 + r) * 1032 + col] =
                        f32_to_bf16_rne(fmaxf(acc[ni][r] + bv, 0.f));
                acc[ni] = (f32x4){};
            }
        }
        if (t == 15) __syncthreads();    // x1s complete before ff2 reads
        if (t < 31) {
            #pragma unroll
            for (int j = 0; j < 4; ++j) wc[j] = wn[j];
        }
    }

    // ---- epilogue: + b2 + residual, LN ----
    float vres[2][4];
    #pragma unroll
    for (int ni = 0; ni < 2; ++ni) {
        int col = w * 32 + ni * 16 + fr;
        float bv = b2[col];
        #pragma unroll
        for (int r = 0; r < 4; ++r) {
            int row = m0 + ksub * 4 + r;
            vres[ni][r] = acc[ni][r] + bv + x[(long)row * DMODEL + col];
        }
    }

    #pragma unroll
    for (int r = 0; r < 4; ++r) {
        float s  = vres[0][r] + vres[1][r];
        float qq = vres[0][r] * vres[0][r] + vres[1][r] * vres[1][r];
        #pragma unroll
        for (int mask = 1; mask < 16; mask <<= 1) {
            s  += __shfl_xor(s, mask);
            qq += __shfl_xor(qq, mask);
        }
        if (fr == 0) {
            redS[w][ksub * 4 + r] = s;
            redQ[w][ksub * 4 + r] = qq;
        }
    }
    __syncthreads();

    #pragma unroll
    for (int r = 0; r < 4; ++r) {
        int rl = ksub * 4 + r;
        float sum = 0.f, sumq = 0.f;
        #pragma unroll
        for (int ww = 0; ww < 8; ++ww) {
            sum  += redS[ww][rl];
            sumq += redQ[ww][rl];
        }
        float mean = sum * (1.f / 256.f);
        float var  = sumq * (1.f / 256.f) - mean * mean;
        float rstd = rsqrtf(var + 1e-5f);
        #pragma unroll
        for (int ni = 0; ni < 2; ++ni) {
            int col = w * 32 + ni * 16 + fr;
            xout[(long)(m0 + rl) * DMODEL + col] =
                (vres[ni][r] - mean) * rstd * g[col] + beta[col];
        }
    }
}

// ===========================================================================
// Fallback (fp32) path kernels — used only if ws is too small.
// ===========================================================================
__global__ __launch_bounds__(256) void embed_kernel(
    const int* __restrict__ word_idx,
    const int* __restrict__ ngram_idx,
    const float* __restrict__ fc1_w,
    const float* __restrict__ fc1_b,
    const float* __restrict__ fc2_w,
    const float* __restrict__ fc2_b,
    float* __restrict__ x)
{
    __shared__ int   feats[8][8];
    __shared__ int   nf[8];
    __shared__ float x1[8][FFDIM];

    const int t0  = blockIdx.x * 8;
    const int tid = threadIdx.x;

    if (tid < 8) {
        int t = t0 + tid;
        int cnt = 0;
        feats[tid][cnt++] = word_idx[t];
        for (int k = 0; k < 6; ++k) {
            int f = WORDC + ngram_idx[t * 6 + k];
            bool dup = false;
            for (int s = 1; s < cnt; ++s)
                if (feats[tid][s] == f) dup = true;
            if (!dup) feats[tid][cnt++] = f;
        }
        nf[tid] = cnt;
    }
    __syncthreads();

    for (int it = 0; it < 16; ++it) {
        int item = it * 256 + tid;
        int tt = item >> 9;
        int j  = item & 511;
        float acc = fc1_b[j];
        int n = nf[tt];
        const float* rowbase = fc1_w + (long)j * F_TOT;
        for (int s = 0; s < n; ++s)
            acc += rowbase[feats[tt][s]];
        x1[tt][j] = fmaxf(acc, 0.f);
    }
    __syncthreads();

    const int d = tid;
    float acc[8];
    float bb = fc2_b[d];
    #pragma unroll
    for (int tt = 0; tt < 8; ++tt) acc[tt] = bb;
    const float* wrow = fc2_w + d * FFDIM;
    for (int k = 0; k < FFDIM; ++k) {
        float wv = wrow[k];
        #pragma unroll
        for (int tt = 0; tt < 8; ++tt) acc[tt] += wv * x1[tt][k];
    }
    #pragma unroll
    for (int tt = 0; tt < 8; ++tt)
        x[(t0 + tt) * DMODEL + d] = acc[tt];
}

template<bool RELU>
__global__ __launch_bounds__(256) void gemm_bias(
    const float* __restrict__ A,
    const float* __restrict__ W,
    const float* __restrict__ bias,
    float* __restrict__ C,
    int M, int N, int K)
{
    __shared__ float sA[16][64];
    __shared__ float sW[16][64];

    const int tid = threadIdx.x;
    const int tx = tid & 15;
    const int ty = tid >> 4;
    const int m0 = blockIdx.y * 64;
    const int n0 = blockIdx.x * 64;

    const int lr = tid >> 2;
    const int lc = tid & 3;

    float acc[4][4] = {};

    for (int k0 = 0; k0 < K; k0 += 16) {
        float4 av = *(const float4*)&A[(long)(m0 + lr) * K + k0 + lc * 4];
        float4 wv = *(const float4*)&W[(long)(n0 + lr) * K + k0 + lc * 4];
        __syncthreads();
        sA[lc * 4 + 0][lr] = av.x; sA[lc * 4 + 1][lr] = av.y;
        sA[lc * 4 + 2][lr] = av.z; sA[lc * 4 + 3][lr] = av.w;
        sW[lc * 4 + 0][lr] = wv.x; sW[lc * 4 + 1][lr] = wv.y;
        sW[lc * 4 + 2][lr] = wv.z; sW[lc * 4 + 3][lr] = wv.w;
        __syncthreads();
        #pragma unroll
        for (int k = 0; k < 16; ++k) {
            float4 a4 = *(const float4*)&sA[k][ty * 4];
            float4 b4 = *(const float4*)&sW[k][tx * 4];
            float am[4] = {a4.x, a4.y, a4.z, a4.w};
            float bn[4] = {b4.x, b4.y, b4.z, b4.w};
            #pragma unroll
            for (int i = 0; i < 4; ++i)
                #pragma unroll
                for (int j = 0; j < 4; ++j)
                    acc[i][j] += am[i] * bn[j];
        }
    }

    float4 bv = *(const float4*)&bias[n0 + tx * 4];
    #pragma unroll
    for (int i = 0; i < 4; ++i) {
        int m = m0 + ty * 4 + i;
        float4 o;
        o.x = acc[i][0] + bv.x;
        o.y = acc[i][1] + bv.y;
        o.z = acc[i][2] + bv.z;
        o.w = acc[i][3] + bv.w;
        if (RELU) {
            o.x = fmaxf(o.x, 0.f); o.y = fmaxf(o.y, 0.f);
            o.z = fmaxf(o.z, 0.f); o.w = fmaxf(o.w, 0.f);
        }
        *(float4*)&C[(long)m * N + n0 + tx * 4] = o;
    }
}

__global__ __launch_bounds__(256) void attn_kernel(
    const float* __restrict__ qkv,
    float* __restrict__ o)
{
    const int b = blockIdx.x >> 3;
    const int h = blockIdx.x & 7;
    const int tid = threadIdx.x;
    const int q = tid >> 2;
    const int p = tid & 3;

    __shared__ float Kt[SEQL][HDIM + 1];
    __shared__ float Vt[SEQL][HDIM + 1];
    __shared__ float S[SEQL][SEQL + 1];

    const float scale = 0.17677669529663687f;

    {
        int fidx = tid * 2;
        int row  = fidx >> 3;
        int c    = (fidx & 7) * 4;
        const float* kb = qkv + (long)(b * SEQL + row) * 768 + 256 + h * HDIM + c;
        float4 k0 = *(const float4*)kb;
        float4 k1 = *(const float4*)(kb + 4);
        float4 v0 = *(const float4*)(kb + 256);
        float4 v1 = *(const float4*)(kb + 260);
        *(float4*)&Kt[row][c]     = k0;
        *(float4*)&Kt[row][c + 4] = k1;
        *(float4*)&Vt[row][c]     = v0;
        *(float4*)&Vt[row][c + 4] = v1;
    }

    float qreg[HDIM];
    {
        const float* qb = qkv + (long)(b * SEQL + q) * 768 + h * HDIM;
        #pragma unroll
        for (int c = 0; c < HDIM / 4; ++c) {
            float4 v = *(const float4*)(qb + c * 4);
            qreg[c * 4 + 0] = v.x * scale;
            qreg[c * 4 + 1] = v.y * scale;
            qreg[c * 4 + 2] = v.z * scale;
            qreg[c * 4 + 3] = v.w * scale;
        }
    }
    __syncthreads();

    float sc[16];
    float mx = -1e30f;
    #pragma unroll
    for (int i = 0; i < 16; ++i) {
        int jj = p * 16 + i;
        float s = 0.f;
        #pragma unroll
        for (int d = 0; d < HDIM; ++d) s += qreg[d] * Kt[jj][d];
        sc[i] = s;
        mx = fmaxf(mx, s);
    }
    mx = fmaxf(mx, __shfl_xor(mx, 1));
    mx = fmaxf(mx, __shfl_xor(mx, 2));

    float sum = 0.f;
    #pragma unroll
    for (int i = 0; i < 16; ++i) {
        float e = __expf(sc[i] - mx);
        S[q][p * 16 + i] = e;
        sum += e;
    }
    sum += __shfl_xor(sum, 1);
    sum += __shfl_xor(sum, 2);
    const float inv = 1.f / sum;
    __syncthreads();

    float acc[8] = {};
    for (int jj = 0; jj < SEQL; ++jj) {
        float pv = S[q][jj];
        #pragma unroll
        for (int d = 0; d < 8; ++d) acc[d] += pv * Vt[jj][p * 8 + d];
    }
    float* orow = o + (long)(b * SEQL + q) * DMODEL + h * HDIM + p * 8;
    float4 o0, o1;
    o0.x = acc[0] * inv; o0.y = acc[1] * inv; o0.z = acc[2] * inv; o0.w = acc[3] * inv;
    o1.x = acc[4] * inv; o1.y = acc[5] * inv; o1.z = acc[6] * inv; o1.w = acc[7] * inv;
    *(float4*)orow = o0;
    *(float4*)(orow + 4) = o1;
}

__global__ __launch_bounds__(256) void add_ln_kernel(
    const float* __restrict__ xin,
    const float* __restrict__ f,
    const float* __restrict__ g,
    const float* __restrict__ bta,
    float* __restrict__ xout)
{
    const int w = threadIdx.x >> 6;
    const int lane = threadIdx.x & 63;
    const int t = blockIdx.x * 4 + w;

    float4 xv = *(const float4*)&xin[(long)t * DMODEL + lane * 4];
    float4 fv = *(const float4*)&f[(long)t * DMODEL + lane * 4];
    float v0 = xv.x + fv.x, v1 = xv.y + fv.y, v2 = xv.z + fv.z, v3 = xv.w + fv.w;

    float s  = v0 + v1 + v2 + v3;
    float sq = v0 * v0 + v1 * v1 + v2 * v2 + v3 * v3;
    #pragma unroll
    for (int off = 1; off < 64; off <<= 1) {
        s  += __shfl_xor(s, off);
        sq += __shfl_xor(sq, off);
    }
    float mean = s * (1.f / 256.f);
    float var  = sq * (1.f / 256.f) - mean * mean;
    float rs   = rsqrtf(var + 1e-5f);

    float4 gv = *(const float4*)&g[lane * 4];
    float4 bv = *(const float4*)&bta[lane * 4];
    float4 o;
    o.x = (v0 - mean) * rs * gv.x + bv.x;
    o.y = (v1 - mean) * rs * gv.y + bv.y;
    o.z = (v2 - mean) * rs * gv.z + bv.z;
    o.w = (v3 - mean) * rs * gv.w + bv.w;
    *(float4*)&xout[(long)t * DMODEL + lane * 4] = o;
}

// ---------------------------------------------------------------------------
extern "C" void kernel_launch(void* const* d_in, const int* in_sizes, int n_in,
                              void* d_out, int out_size, void* d_ws, size_t ws_size,
                              hipStream_t stream) {
    const int*   word_idx  = (const int*)d_in[0];
    const int*   ngram_idx = (const int*)d_in[1];
    const float* fc1_w = (const float*)d_in[2];
    const float* fc1_b = (const float*)d_in[3];
    const float* fc2_w = (const float*)d_in[4];
    const float* fc2_b = (const float*)d_in[5];
    const float* qkv_w = (const float*)d_in[6];
    const float* qkv_b = (const float*)d_in[7];
    const float* out_w = (const float*)d_in[8];
    const float* out_b = (const float*)d_in[9];
    const float* ln1_g = (const float*)d_in[10];
    const float* ln1_b = (const float*)d_in[11];
    const float* ff1_w = (const float*)d_in[12];
    const float* ff1_b = (const float*)d_in[13];
    const float* ff2_w = (const float*)d_in[14];
    const float* ff2_b = (const float*)d_in[15];
    const float* ln2_g = (const float*)d_in[16];
    const float* ln2_b = (const float*)d_in[17];

    float* x = (float*)d_out;  // [2048][256]

    const size_t BM_OFF   = 0;
    const size_t FC1T_OFF = 10240;
    const size_t FC1T_BYTES = (size_t)F_TOT * FFDIM * 2;
    const size_t QKVT_OFF = FC1T_OFF + FC1T_BYTES;
    const size_t QKVT_BYTES = (size_t)2 * 768 * 256 * 2;
    const size_t OUTT_OFF = QKVT_OFF + QKVT_BYTES;
    const size_t OUTT_BYTES = (size_t)2 * 256 * 256 * 2;
    const size_t FF1T_OFF = OUTT_OFF + OUTT_BYTES;
    const size_t FF1T_BYTES = (size_t)2 * 1024 * 256 * 2;
    const size_t FF2T_OFF = FF1T_OFF + FF1T_BYTES;
    const size_t FF2T_BYTES = (size_t)2 * 256 * 1024 * 2;
    const size_t ATTN_OFF = FF2T_OFF + FF2T_BYTES;
    const size_t ATTN_BYTES = (size_t)NTOK * DMODEL * 4;
    const size_t FAST_BYTES = ATTN_OFF + ATTN_BYTES;

    if (ws_size >= FAST_BYTES) {
        unsigned int*   bm   = (unsigned int*)((char*)d_ws + BM_OFF);
        unsigned short* fc1T = (unsigned short*)((char*)d_ws + FC1T_OFF);
        unsigned short* qkvT = (unsigned short*)((char*)d_ws + QKVT_OFF);
        unsigned short* outT = (unsigned short*)((char*)d_ws + OUTT_OFF);
        unsigned short* ff1T = (unsigned short*)((char*)d_ws + FF1T_OFF);
        unsigned short* ff2T = (unsigned short*)((char*)d_ws + FF2T_OFF);
        float* attn_raw = (float*)((char*)d_ws + ATTN_OFF);

        mark_feats<<<1, 256, 0, stream>>>(word_idx, ngram_idx, bm);
        transpose_cvt<<<10192, 256, 0, stream>>>(
            fc1_w, fc1T, bm, qkv_w, out_w, ff1_w, ff2_w, qkvT, outT, ff1T, ff2T);
        embed_gather<<<NTOK / 8, 256, 0, stream>>>(word_idx, ngram_idx, fc1T,
                                                   fc1_b, fc2_w, fc2_b, x);

        for (int i = 0; i < 2; ++i) {
            fused_qkv_attn<<<32 * NHEAD, 512, 0, stream>>>(
                x, qkvT + (long)i * 768 * 256, qkv_b + i * 768, attn_raw);

            gemm_ln<<<NTOK / 8, 512, 0, stream>>>(
                attn_raw, outT + (long)i * 256 * 256, out_b + i * 256,
                x, ln1_g + i * 256, ln1_b + i * 256, x);

            fused_ffn<<<NTOK / 16, 512, 0, stream>>>(
                x, ff1T + (long)i * 1024 * 256, ff1_b + i * 1024,
                ff2T + (long)i * 256 * 1024, ff2_b + i * 256,
                ln2_g + i * 256, ln2_b + i * 256, x);
        }
    } else {
        float* wsf      = (float*)d_ws;
        float* qkvbuf   = wsf;
        float* attn_raw = qkvbuf + 2048 * 768;
        float* obuf     = attn_raw + 2048 * 256;
        float* ffbuf    = obuf + 2048 * 256;

        embed_kernel<<<NTOK / 8, 256, 0, stream>>>(word_idx, ngram_idx, fc1_w,
                                                   fc1_b, fc2_w, fc2_b, x);
        for (int i = 0; i < 2; ++i) {
            gemm_bias<false><<<dim3(768 / 64, NTOK / 64), 256, 0, stream>>>(
                x, qkv_w + (long)i * 768 * 256, qkv_b + i * 768, qkvbuf,
                NTOK, 768, 256);
            attn_kernel<<<32 * NHEAD, 256, 0, stream>>>(qkvbuf, attn_raw);
            gemm_bias<false><<<dim3(256 / 64, NTOK / 64), 256, 0, stream>>>(
                attn_raw, out_w + (long)i * 256 * 256, out_b + i * 256, obuf,
                NTOK, 256, 256);
            add_ln_kernel<<<NTOK / 4, 256, 0, stream>>>(x, obuf, ln1_g + i * 256,
                                                        ln1_b + i * 256, x);
            gemm_bias<true><<<dim3(1024 / 64, NTOK / 64), 256, 0, stream>>>(
                x, ff1_w + (long)i * 1024 * 256, ff1_b + i * 1024, ffbuf,
                NTOK, 1024, 256);
            gemm_bias<false><<<dim3(256 / 64, NTOK / 64), 256, 0, stream>>>(
                ffbuf, ff2_w + (long)i * 256 * 1024, ff2_b + i * 256, obuf,
                NTOK, 256, 1024);
            add_ln_kernel<<<NTOK / 4, 256, 0, stream>>>(x, obuf, ln2_g + i * 256,
                                                        ln2_b + i * 256, x);
        }
    }
}